// Round 2
// baseline (782.872 us; speedup 1.0000x reference)
//
#include <hip/hip_runtime.h>
#include <math.h>

#define EPSB 1e-5f

constexpr int B_ = 4;
constexpr int C_ = 64;
constexpr int H_ = 160;
constexpr int W_ = 160;
constexpr int HW_ = H_ * W_;

// workspace layout (float offsets)
constexpr size_t X_OFF   = 0;                                   // relu(x1+x2+x3+x4): B*C*HW
constexpr size_t Y1_OFF  = X_OFF  + (size_t)B_ * C_ * HW_;      // conv(f1)+bn @80x80
constexpr size_t Y2_OFF  = Y1_OFF + (size_t)B_ * C_ * 80 * 80;  // conv(f2)+bn @40x40
constexpr size_t Y3_OFF  = Y2_OFF + (size_t)B_ * C_ * 40 * 40;  // conv(f3)+bn @20x20
constexpr size_t OM_OFF  = Y3_OFF + (size_t)B_ * C_ * 20 * 20;  // (sy,sx,mask) per tap: B*27*HW
constexpr size_t WR0_OFF = OM_OFF + (size_t)B_ * 27 * HW_;      // w0 reordered ci-major: 64*64
constexpr size_t WTB_OFF = WR0_OFF + 64 * 64;                   // dcn_w bf16 [k][o][c pad 72]: 9*64*72 ushort = 20736 floats
constexpr size_t RW_OFF  = WTB_OFF + (9 * 64 * 72) / 2;         // off_w reordered [(ci,dy,dx)][k]: 576*27
constexpr size_t SB_OFF  = RW_OFF + 576 * 27;                   // 5 BNs x (scale[64], bias[64])

typedef short bf16x8 __attribute__((ext_vector_type(8)));
typedef float f32x4 __attribute__((ext_vector_type(4)));

static __device__ __forceinline__ unsigned short f2bf(float f) {
    unsigned int u = __float_as_uint(f);
    u += 0x7fff + ((u >> 16) & 1);   // RNE
    return (unsigned short)(u >> 16);
}

__global__ __launch_bounds__(256) void prep_kernel(
    const float* __restrict__ g0, const float* __restrict__ b0, const float* __restrict__ m0, const float* __restrict__ v0,
    const float* __restrict__ g1, const float* __restrict__ b1, const float* __restrict__ m1, const float* __restrict__ v1,
    const float* __restrict__ g2, const float* __restrict__ b2, const float* __restrict__ m2, const float* __restrict__ v2,
    const float* __restrict__ g3, const float* __restrict__ b3, const float* __restrict__ m3, const float* __restrict__ v3,
    const float* __restrict__ gf, const float* __restrict__ bf, const float* __restrict__ mf, const float* __restrict__ vf,
    const float* __restrict__ w0, const float* __restrict__ dcn_w, const float* __restrict__ off_w,
    float* __restrict__ ws)
{
    int tid = blockIdx.x * 256 + threadIdx.x;
    if (tid < 320) {  // BN scale/bias fold
        int j = tid >> 6, c = tid & 63;
        const float *g, *b, *m, *v;
        switch (j) {
            case 0: g = g0; b = b0; m = m0; v = v0; break;
            case 1: g = g1; b = b1; m = m1; v = v1; break;
            case 2: g = g2; b = b2; m = m2; v = v2; break;
            case 3: g = g3; b = b3; m = m3; v = v3; break;
            default: g = gf; b = bf; m = mf; v = vf; break;
        }
        float sc = g[c] * rsqrtf(v[c] + EPSB);
        ws[SB_OFF + j * 128 + c]      = sc;
        ws[SB_OFF + j * 128 + 64 + c] = b[c] - m[c] * sc;
        return;
    }
    int t = tid - 320;
    if (t < 4096) {  // wr0[ci*64+o] = w0[o*64+ci]
        int ci = t >> 6, o = t & 63;
        ws[WR0_OFF + t] = w0[o * 64 + ci];
        return;
    }
    t -= 4096;
    if (t < 9 * 64 * 72) {  // wtb[k][o][c pad72] bf16 = dcn_w[(o*64+c)*9+k]
        int k = t / 4608, r = t % 4608, o = r / 72, c = r % 72;
        float v = (c < 64) ? dcn_w[(o * 64 + c) * 9 + k] : 0.f;
        ((unsigned short*)(ws + WTB_OFF))[t] = f2bf(v);
        return;
    }
    t -= 9 * 64 * 72;
    if (t < 15552) {  // rw[rest*27 + k] = off_w[k*576 + rest], rest = ci*9+dy*3+dx
        int k = t % 27, rest = t / 27;
        ws[RW_OFF + rest * 27 + k] = off_w[k * 576 + rest];
        return;
    }
}

// thread = one output element (b, o, p); loop over Cin
__global__ __launch_bounds__(256) void conv1x1_bn_kernel(
    const float* __restrict__ f, const float* __restrict__ wmat,
    const float* __restrict__ sb, float* __restrict__ out, int Cin, int hw)
{
    int tid = blockIdx.x * 256 + threadIdx.x;
    int p = tid % hw;
    int o = (tid / hw) & 63;
    int b = tid / (hw * 64);
    const float* fb = f + (size_t)b * Cin * hw + p;
    const float* wr = wmat + o * Cin;
    float acc = 0.f;
#pragma unroll 4
    for (int ci = 0; ci < Cin; ++ci) acc = fmaf(fb[(size_t)ci * hw], wr[ci], acc);
    out[tid] = fmaf(acc, sb[o], sb[64 + o]);
}

// block = 64 px x 4 channel-groups; thread: 16 channels of one pixel
__global__ __launch_bounds__(256) void fuse_kernel(const float* __restrict__ f0, float* __restrict__ ws)
{
    int tid = threadIdx.x;
    int blk = blockIdx.x;
    int b = blk / 400, t = blk % 400;
    int p0 = t * 64;
    int lane = tid & 63, cb = tid >> 6;
    int p = p0 + lane;
    int h = p / W_, w = p % W_;
    const float* wr0 = ws + WR0_OFF + cb * 16;
    const float* sb  = ws + SB_OFF;  // bn0

    float acc[16];
#pragma unroll
    for (int i = 0; i < 16; i++) acc[i] = 0.f;

    const float* f0b = f0 + (size_t)b * 64 * HW_ + p;
    for (int ci = 0; ci < 64; ++ci) {
        float fv = f0b[(size_t)ci * HW_];
        const float* wrow = wr0 + ci * 64;
#pragma unroll
        for (int i = 0; i < 16; i++) acc[i] = fmaf(fv, wrow[i], acc[i]);
    }
#pragma unroll
    for (int i = 0; i < 16; i++) {
        int o = cb * 16 + i;
        acc[i] = fmaf(acc[i], sb[o], sb[64 + o]);
    }

    {   // +upsample x2 from 80x80 (align_corners)
        float fy = h * (79.f / 159.f); int i0 = (int)fy; if (i0 > 78) i0 = 78; float ty = fy - i0;
        float fx = w * (79.f / 159.f); int j0 = (int)fx; if (j0 > 78) j0 = 78; float tx = fx - j0;
        float w00 = (1.f - ty) * (1.f - tx), w01 = (1.f - ty) * tx, w10 = ty * (1.f - tx), w11 = ty * tx;
        const float* y = ws + Y1_OFF + (size_t)b * 64 * 6400 + (size_t)cb * 16 * 6400 + i0 * 80 + j0;
#pragma unroll
        for (int i = 0; i < 16; i++) {
            const float* yc = y + (size_t)i * 6400;
            acc[i] += yc[0] * w00 + yc[1] * w01 + yc[80] * w10 + yc[81] * w11;
        }
    }
    {   // +upsample x4 from 40x40
        float fy = h * (39.f / 159.f); int i0 = (int)fy; if (i0 > 38) i0 = 38; float ty = fy - i0;
        float fx = w * (39.f / 159.f); int j0 = (int)fx; if (j0 > 38) j0 = 38; float tx = fx - j0;
        float w00 = (1.f - ty) * (1.f - tx), w01 = (1.f - ty) * tx, w10 = ty * (1.f - tx), w11 = ty * tx;
        const float* y = ws + Y2_OFF + (size_t)b * 64 * 1600 + (size_t)cb * 16 * 1600 + i0 * 40 + j0;
#pragma unroll
        for (int i = 0; i < 16; i++) {
            const float* yc = y + (size_t)i * 1600;
            acc[i] += yc[0] * w00 + yc[1] * w01 + yc[40] * w10 + yc[41] * w11;
        }
    }
    {   // +upsample x8 from 20x20
        float fy = h * (19.f / 159.f); int i0 = (int)fy; if (i0 > 18) i0 = 18; float ty = fy - i0;
        float fx = w * (19.f / 159.f); int j0 = (int)fx; if (j0 > 18) j0 = 18; float tx = fx - j0;
        float w00 = (1.f - ty) * (1.f - tx), w01 = (1.f - ty) * tx, w10 = ty * (1.f - tx), w11 = ty * tx;
        const float* y = ws + Y3_OFF + (size_t)b * 64 * 400 + (size_t)cb * 16 * 400 + i0 * 20 + j0;
#pragma unroll
        for (int i = 0; i < 16; i++) {
            const float* yc = y + (size_t)i * 400;
            acc[i] += yc[0] * w00 + yc[1] * w01 + yc[20] * w10 + yc[21] * w11;
        }
    }

    float* x = ws + X_OFF + (size_t)b * 64 * HW_ + (size_t)cb * 16 * HW_ + p;
#pragma unroll
    for (int i = 0; i < 16; i++) x[(size_t)i * HW_] = fmaxf(acc[i], 0.f);
}

// block = 64 px x 4 ci-groups of 16; LDS-reduce 27 accs; write (sy,sx,mask)
__global__ __launch_bounds__(256) void offconv_kernel(const float* __restrict__ off_b, float* __restrict__ ws)
{
    __shared__ float buf[64 * 113];
    int tid = threadIdx.x;
    int blk = blockIdx.x;
    int b = blk / 400, t = blk % 400;
    int p0 = t * 64;
    int lane = tid & 63, cs = tid >> 6;
    int p = p0 + lane;
    int h = p / W_, w = p % W_;
    const float* x  = ws + X_OFF + (size_t)b * 64 * HW_ + (size_t)cs * 16 * HW_;
    const float* rw = ws + RW_OFF + (size_t)cs * 16 * 9 * 27;

    float acc[27];
#pragma unroll
    for (int j = 0; j < 27; j++) acc[j] = 0.f;

    for (int ci = 0; ci < 16; ++ci) {
        const float* xc = x + (size_t)ci * HW_;
#pragma unroll
        for (int dy = 0; dy < 3; dy++) {
            int yy = h + dy - 1;
            if (yy < 0 || yy >= H_) continue;
#pragma unroll
            for (int dx = 0; dx < 3; dx++) {
                int xx = w + dx - 1;
                if (xx < 0 || xx >= W_) continue;
                float xv = xc[yy * W_ + xx];
                const float* rr = rw + (ci * 9 + dy * 3 + dx) * 27;
#pragma unroll
                for (int j = 0; j < 27; j++) acc[j] = fmaf(xv, rr[j], acc[j]);
            }
        }
    }

    float* bp = buf + lane * 113 + cs * 28;
#pragma unroll
    for (int j = 0; j < 27; j++) bp[j] = acc[j];
    __syncthreads();

    for (int i = tid; i < 576; i += 256) {
        int k = i >> 6, px = i & 63;
        const float* rb = buf + px * 113;
        float ady = rb[2 * k] + rb[28 + 2 * k] + rb[56 + 2 * k] + rb[84 + 2 * k] + off_b[2 * k];
        float adx = rb[2 * k + 1] + rb[29 + 2 * k] + rb[57 + 2 * k] + rb[85 + 2 * k] + off_b[2 * k + 1];
        float am  = rb[18 + k] + rb[46 + k] + rb[74 + k] + rb[102 + k] + off_b[18 + k];
        int pp = p0 + px;
        int hh = pp / W_, ww = pp % W_;
        float sy = (float)(hh + k / 3 - 1) + ady;
        float sx = (float)(ww + k % 3 - 1) + adx;
        float mk = 1.f / (1.f + __expf(-am));
        float* om = ws + OM_OFF + (size_t)b * 27 * HW_ + pp;
        om[(size_t)(k * 3 + 0) * HW_] = sy;
        om[(size_t)(k * 3 + 1) * HW_] = sx;
        om[(size_t)(k * 3 + 2) * HW_] = mk;
    }
}

// block = 64-pixel tile; 4 waves each compute a 16x64 slab of C via MFMA over K=9 taps x 64 ch
__global__ __launch_bounds__(256) void dcn_mfma_kernel(const float* __restrict__ ws, float* __restrict__ out)
{
    __shared__ __align__(16) unsigned short smem[2 * 64 * 72];  // A tile | B tile; reused as C (f32 64x65)
    unsigned short* A_lds = smem;
    unsigned short* B_lds = smem + 64 * 72;

    int tid = threadIdx.x;
    int blk = blockIdx.x;
    int b = blk / 400, t = blk % 400;
    int p0 = t * 64;
    int lane = tid & 63;
    int cb = tid >> 6;            // wave id == channel-group for gather == m-tile for MFMA
    int p = p0 + lane;

    const float* x   = ws + X_OFF + (size_t)b * 64 * HW_;
    const unsigned short* wtb = (const unsigned short*)(ws + WTB_OFF);
    const float* om  = ws + OM_OFF + (size_t)b * 27 * HW_ + p;
    const float* sb  = ws + SB_OFF + 4 * 128;  // final bn

    int mrow = lane & 15;
    int half = lane >> 4;

    f32x4 acc[4];
#pragma unroll
    for (int nt = 0; nt < 4; nt++) acc[nt] = (f32x4){0.f, 0.f, 0.f, 0.f};

    for (int k = 0; k < 9; ++k) {
        __syncthreads();  // previous iteration's LDS reads done
        // cooperative B-tile load: wtb[k][o][c pad72] bf16, 4608 entries
        for (int i = tid; i < 4608; i += 256) B_lds[i] = wtb[k * 4608 + i];

        // gather: this thread fills A[px=lane][ch = cb*16 .. +15]
        float sy = om[(size_t)(k * 3 + 0) * HW_];
        float sx = om[(size_t)(k * 3 + 1) * HW_];
        float mk = om[(size_t)(k * 3 + 2) * HW_];
        float y0f = floorf(sy), x0f = floorf(sx);
        int y0 = (int)y0f, x0 = (int)x0f;
        float ty = sy - y0f, tx = sx - x0f;

        int   idx[4];
        float wv[4];
#pragma unroll
        for (int cr = 0; cr < 4; cr++) {
            int dy = cr >> 1, dx = cr & 1;
            int yy = y0 + dy, xx = x0 + dx;
            float wy = dy ? ty : 1.f - ty;
            float wx = dx ? tx : 1.f - tx;
            bool valid = (yy >= 0) && (yy < H_) && (xx >= 0) && (xx < W_);
            int yc = min(max(yy, 0), H_ - 1);
            int xc = min(max(xx, 0), W_ - 1);
            idx[cr] = yc * W_ + xc;
            wv[cr]  = valid ? wy * wx * mk : 0.f;
        }

        unsigned short loc[16];
        const float* xg = x + (size_t)cb * 16 * HW_;
#pragma unroll
        for (int i = 0; i < 16; i++) {
            const float* xp = xg + (size_t)i * HW_;
            float v = xp[idx[0]] * wv[0] + xp[idx[1]] * wv[1] + xp[idx[2]] * wv[2] + xp[idx[3]] * wv[3];
            loc[i] = f2bf(v);
        }
        {
            unsigned short* dst = A_lds + lane * 72 + cb * 16;
#pragma unroll
            for (int i = 0; i < 16; i++) dst[i] = loc[i];
        }
        __syncthreads();

        // MFMA: A[m=cb*16+mrow][k=half*8+j(+32)], B[n][k] from row-major [n][k] tile
        const unsigned short* Ap = A_lds + (cb * 16 + mrow) * 72 + half * 8;
        bf16x8 a0 = *(const bf16x8*)(Ap);
        bf16x8 a1 = *(const bf16x8*)(Ap + 32);
#pragma unroll
        for (int nt = 0; nt < 4; nt++) {
            const unsigned short* Bp = B_lds + (nt * 16 + mrow) * 72 + half * 8;
            bf16x8 b0 = *(const bf16x8*)(Bp);
            bf16x8 b1 = *(const bf16x8*)(Bp + 32);
            acc[nt] = __builtin_amdgcn_mfma_f32_16x16x32_bf16(a0, b0, acc[nt], 0, 0, 0);
            acc[nt] = __builtin_amdgcn_mfma_f32_16x16x32_bf16(a1, b1, acc[nt], 0, 0, 0);
        }
    }

    // epilogue: C frag (col n = lane&15, row m = half*4+reg) -> LDS [o][px pad65] -> coalesced store
    __syncthreads();
    float* C_lds = (float*)smem;
#pragma unroll
    for (int nt = 0; nt < 4; nt++) {
        int o = nt * 16 + mrow;
        int pxb = cb * 16 + half * 4;
#pragma unroll
        for (int r = 0; r < 4; r++) C_lds[o * 65 + pxb + r] = acc[nt][r];
    }
    __syncthreads();
    {
#pragma unroll
        for (int i = 0; i < 16; i++) {
            int o = cb * 16 + i;
            float v = C_lds[o * 65 + lane];
            v = fmaf(v, sb[o], sb[64 + o]);
            out[((size_t)b * 64 + o) * HW_ + p0 + lane] = fmaxf(v, 0.f);
        }
    }
}

extern "C" void kernel_launch(void* const* d_in, const int* in_sizes, int n_in,
                              void* d_out, int out_size, void* d_ws, size_t ws_size,
                              hipStream_t stream)
{
    const float* f0 = (const float*)d_in[0];
    const float* f1 = (const float*)d_in[1];
    const float* f2 = (const float*)d_in[2];
    const float* f3 = (const float*)d_in[3];
    const float* w0 = (const float*)d_in[4];
    const float* g0 = (const float*)d_in[5];
    const float* b0 = (const float*)d_in[6];
    const float* m0 = (const float*)d_in[7];
    const float* v0 = (const float*)d_in[8];
    const float* w1 = (const float*)d_in[9];
    const float* g1 = (const float*)d_in[10];
    const float* b1 = (const float*)d_in[11];
    const float* m1 = (const float*)d_in[12];
    const float* v1 = (const float*)d_in[13];
    const float* w2 = (const float*)d_in[14];
    const float* g2 = (const float*)d_in[15];
    const float* b2 = (const float*)d_in[16];
    const float* m2 = (const float*)d_in[17];
    const float* v2 = (const float*)d_in[18];
    const float* w3 = (const float*)d_in[19];
    const float* g3 = (const float*)d_in[20];
    const float* b3 = (const float*)d_in[21];
    const float* m3 = (const float*)d_in[22];
    const float* v3 = (const float*)d_in[23];
    const float* off_w = (const float*)d_in[24];
    const float* off_b = (const float*)d_in[25];
    const float* dcn_w = (const float*)d_in[26];
    const float* gf = (const float*)d_in[27];
    const float* bf = (const float*)d_in[28];
    const float* mf = (const float*)d_in[29];
    const float* vf = (const float*)d_in[30];

    float* ws  = (float*)d_ws;
    float* out = (float*)d_out;

    // prep: 320 + 4096 + 41472 + 15552 = 61440 threads = 240 * 256
    prep_kernel<<<dim3(240), dim3(256), 0, stream>>>(
        g0, b0, m0, v0, g1, b1, m1, v1, g2, b2, m2, v2, g3, b3, m3, v3,
        gf, bf, mf, vf, w0, dcn_w, off_w, ws);

    // small-scale 1x1 convs + bn
    conv1x1_bn_kernel<<<dim3(6400), dim3(256), 0, stream>>>(f1, w1, ws + SB_OFF + 128, ws + Y1_OFF, 128, 6400);
    conv1x1_bn_kernel<<<dim3(1600), dim3(256), 0, stream>>>(f2, w2, ws + SB_OFF + 256, ws + Y2_OFF, 256, 1600);
    conv1x1_bn_kernel<<<dim3(400),  dim3(256), 0, stream>>>(f3, w3, ws + SB_OFF + 384, ws + Y3_OFF, 512, 400);

    // fuse: conv1x1(f0)+bn + upsample adds + relu -> x   (1600 blocks)
    fuse_kernel<<<dim3(1600), dim3(256), 0, stream>>>(f0, ws);

    // offset conv -> (sy, sx, mask)   (1600 blocks, ci-split + LDS reduce)
    offconv_kernel<<<dim3(1600), dim3(256), 0, stream>>>(off_b, ws);

    // deformable conv via MFMA + final bn + relu   (1600 blocks)
    dcn_mfma_kernel<<<dim3(1600), dim3(256), 0, stream>>>(ws, out);
}

// Round 3
// 589.001 us; speedup vs baseline: 1.3292x; 1.3292x over previous
//
#include <hip/hip_runtime.h>
#include <math.h>

#define EPSB 1e-5f

constexpr int B_ = 4;
constexpr int C_ = 64;
constexpr int H_ = 160;
constexpr int W_ = 160;
constexpr int HW_ = H_ * W_;

// workspace layout (float offsets) — total 11,503,488 floats = 46.01 MB
constexpr size_t X_OFF   = 0;                                    // x NHWC: [b][p][64]
constexpr size_t Y1_OFF  = X_OFF  + (size_t)B_ * HW_ * 64;       // y1 NHWC @80x80
constexpr size_t Y2_OFF  = Y1_OFF + (size_t)B_ * 6400 * 64;      // y2 NHWC @40x40
constexpr size_t Y3_OFF  = Y2_OFF + (size_t)B_ * 1600 * 64;      // y3 NHWC @20x20
constexpr size_t OM_OFF  = Y3_OFF + (size_t)B_ * 400 * 64;       // om: [b][p][27] (sy,sx,mk)*9
constexpr size_t WR0_OFF = OM_OFF + (size_t)B_ * HW_ * 27;       // w0 fp32 [ci][o]: 4096
constexpr size_t WTB_OFF = WR0_OFF + 4096;                       // dcn_w bf16 [k][o][c pad72]: 41472 ush = 20736 f
constexpr size_t RWB_OFF = WTB_OFF + (9 * 64 * 72) / 2;          // off_w bf16 [tap][o pad32][ci 64]: 18432 ush = 9216 f
constexpr size_t SB_OFF  = RWB_OFF + (9 * 32 * 64) / 2;          // 5 BNs x (scale[64], bias[64])

typedef short bf16x8 __attribute__((ext_vector_type(8)));
typedef float f32x4 __attribute__((ext_vector_type(4)));

static __device__ __forceinline__ unsigned short f2bf(float f) {
    unsigned int u = __float_as_uint(f);
    u += 0x7fff + ((u >> 16) & 1);   // RNE
    return (unsigned short)(u >> 16);
}

__global__ __launch_bounds__(256) void prep_kernel(
    const float* __restrict__ g0, const float* __restrict__ b0, const float* __restrict__ m0, const float* __restrict__ v0,
    const float* __restrict__ g1, const float* __restrict__ b1, const float* __restrict__ m1, const float* __restrict__ v1,
    const float* __restrict__ g2, const float* __restrict__ b2, const float* __restrict__ m2, const float* __restrict__ v2,
    const float* __restrict__ g3, const float* __restrict__ b3, const float* __restrict__ m3, const float* __restrict__ v3,
    const float* __restrict__ gf, const float* __restrict__ bf, const float* __restrict__ mf, const float* __restrict__ vf,
    const float* __restrict__ w0, const float* __restrict__ dcn_w, const float* __restrict__ off_w,
    float* __restrict__ ws)
{
    int tid = blockIdx.x * 256 + threadIdx.x;
    if (tid < 320) {  // BN scale/bias fold
        int j = tid >> 6, c = tid & 63;
        const float *g, *b, *m, *v;
        switch (j) {
            case 0: g = g0; b = b0; m = m0; v = v0; break;
            case 1: g = g1; b = b1; m = m1; v = v1; break;
            case 2: g = g2; b = b2; m = m2; v = v2; break;
            case 3: g = g3; b = b3; m = m3; v = v3; break;
            default: g = gf; b = bf; m = mf; v = vf; break;
        }
        float sc = g[c] * rsqrtf(v[c] + EPSB);
        ws[SB_OFF + j * 128 + c]      = sc;
        ws[SB_OFF + j * 128 + 64 + c] = b[c] - m[c] * sc;
        return;
    }
    int t = tid - 320;
    if (t < 4096) {  // wr0[ci*64+o] = w0[o*64+ci]
        int ci = t >> 6, o = t & 63;
        ws[WR0_OFF + t] = w0[o * 64 + ci];
        return;
    }
    t -= 4096;
    if (t < 9 * 64 * 72) {  // wtb[k][o][c pad72] bf16 = dcn_w[o][c][k]
        int k = t / 4608, r = t % 4608, o = r / 72, c = r % 72;
        float v = (c < 64) ? dcn_w[o * 576 + c * 9 + k] : 0.f;
        ((unsigned short*)(ws + WTB_OFF))[t] = f2bf(v);
        return;
    }
    t -= 9 * 64 * 72;
    if (t < 9 * 32 * 64) {  // rwb[tap][o pad32][ci] bf16 = off_w[o][ci][tap]
        int tap = t / 2048, r = t % 2048, o = r / 64, ci = r % 64;
        float v = (o < 27) ? off_w[o * 576 + ci * 9 + tap] : 0.f;
        ((unsigned short*)(ws + RWB_OFF))[t] = f2bf(v);
        return;
    }
}

// wave = one (b,p); lanes = 64 output channels. NHWC output.
__global__ __launch_bounds__(256) void conv1x1_bn_kernel(
    const float* __restrict__ f, const float* __restrict__ wmat,
    const float* __restrict__ sb, float* __restrict__ out, int Cin, int hw)
{
    int tid = blockIdx.x * 256 + threadIdx.x;
    int o = tid & 63;
    int rest = tid >> 6;
    int p = rest % hw;
    int b = rest / hw;
    p = __builtin_amdgcn_readfirstlane(p);
    b = __builtin_amdgcn_readfirstlane(b);
    const float* fb = f + (size_t)b * Cin * hw + p;
    const float* wr = wmat + o * Cin;
    float acc = 0.f;
#pragma unroll 4
    for (int ci = 0; ci < Cin; ++ci) acc = fmaf(fb[(size_t)ci * hw], wr[ci], acc);
    out[((size_t)b * hw + p) * 64 + o] = fmaf(acc, sb[o], sb[64 + o]);
}

// block = 64 px x 4 ch-groups; NHWC y-reads (float4) and NHWC x-write
__global__ __launch_bounds__(256) void fuse_kernel(const float* __restrict__ f0, float* __restrict__ ws)
{
    int tid = threadIdx.x;
    int blk = blockIdx.x;
    int b = blk / 400, t = blk % 400;
    int p0 = t * 64;
    int lane = tid & 63, cb = tid >> 6;
    int p = p0 + lane;
    int h = p / W_, w = p % W_;
    const float* wr0 = ws + WR0_OFF + cb * 16;
    const float* sb  = ws + SB_OFF;  // bn0

    float acc[16];
#pragma unroll
    for (int i = 0; i < 16; i++) acc[i] = 0.f;

    const float* f0b = f0 + (size_t)b * 64 * HW_ + p;
    for (int ci = 0; ci < 64; ++ci) {
        float fv = f0b[(size_t)ci * HW_];
        const float* wrow = wr0 + ci * 64;
#pragma unroll
        for (int i = 0; i < 16; i++) acc[i] = fmaf(fv, wrow[i], acc[i]);
    }
#pragma unroll
    for (int i = 0; i < 16; i++) {
        int o = cb * 16 + i;
        acc[i] = fmaf(acc[i], sb[o], sb[64 + o]);
    }

    {   // +upsample x2 from 80x80 (align_corners), NHWC
        float fy = h * (79.f / 159.f); int i0 = (int)fy; if (i0 > 78) i0 = 78; float ty = fy - i0;
        float fx = w * (79.f / 159.f); int j0 = (int)fx; if (j0 > 78) j0 = 78; float tx = fx - j0;
        float w00 = (1.f - ty) * (1.f - tx), w01 = (1.f - ty) * tx, w10 = ty * (1.f - tx), w11 = ty * tx;
        const float* y = ws + Y1_OFF + ((size_t)b * 6400 + (size_t)(i0 * 80 + j0)) * 64 + cb * 16;
#pragma unroll
        for (int c4 = 0; c4 < 4; c4++) {
            f32x4 a00 = *(const f32x4*)(y + c4 * 4);
            f32x4 a01 = *(const f32x4*)(y + 64 + c4 * 4);
            f32x4 a10 = *(const f32x4*)(y + 80 * 64 + c4 * 4);
            f32x4 a11 = *(const f32x4*)(y + 81 * 64 + c4 * 4);
#pragma unroll
            for (int j = 0; j < 4; j++)
                acc[c4 * 4 + j] += a00[j] * w00 + a01[j] * w01 + a10[j] * w10 + a11[j] * w11;
        }
    }
    {   // +upsample x4 from 40x40
        float fy = h * (39.f / 159.f); int i0 = (int)fy; if (i0 > 38) i0 = 38; float ty = fy - i0;
        float fx = w * (39.f / 159.f); int j0 = (int)fx; if (j0 > 38) j0 = 38; float tx = fx - j0;
        float w00 = (1.f - ty) * (1.f - tx), w01 = (1.f - ty) * tx, w10 = ty * (1.f - tx), w11 = ty * tx;
        const float* y = ws + Y2_OFF + ((size_t)b * 1600 + (size_t)(i0 * 40 + j0)) * 64 + cb * 16;
#pragma unroll
        for (int c4 = 0; c4 < 4; c4++) {
            f32x4 a00 = *(const f32x4*)(y + c4 * 4);
            f32x4 a01 = *(const f32x4*)(y + 64 + c4 * 4);
            f32x4 a10 = *(const f32x4*)(y + 40 * 64 + c4 * 4);
            f32x4 a11 = *(const f32x4*)(y + 41 * 64 + c4 * 4);
#pragma unroll
            for (int j = 0; j < 4; j++)
                acc[c4 * 4 + j] += a00[j] * w00 + a01[j] * w01 + a10[j] * w10 + a11[j] * w11;
        }
    }
    {   // +upsample x8 from 20x20
        float fy = h * (19.f / 159.f); int i0 = (int)fy; if (i0 > 18) i0 = 18; float ty = fy - i0;
        float fx = w * (19.f / 159.f); int j0 = (int)fx; if (j0 > 18) j0 = 18; float tx = fx - j0;
        float w00 = (1.f - ty) * (1.f - tx), w01 = (1.f - ty) * tx, w10 = ty * (1.f - tx), w11 = ty * tx;
        const float* y = ws + Y3_OFF + ((size_t)b * 400 + (size_t)(i0 * 20 + j0)) * 64 + cb * 16;
#pragma unroll
        for (int c4 = 0; c4 < 4; c4++) {
            f32x4 a00 = *(const f32x4*)(y + c4 * 4);
            f32x4 a01 = *(const f32x4*)(y + 64 + c4 * 4);
            f32x4 a10 = *(const f32x4*)(y + 20 * 64 + c4 * 4);
            f32x4 a11 = *(const f32x4*)(y + 21 * 64 + c4 * 4);
#pragma unroll
            for (int j = 0; j < 4; j++)
                acc[c4 * 4 + j] += a00[j] * w00 + a01[j] * w01 + a10[j] * w10 + a11[j] * w11;
        }
    }

    float* x = ws + X_OFF + ((size_t)b * HW_ + p) * 64 + cb * 16;
#pragma unroll
    for (int i = 0; i < 16; i++) x[i] = fmaxf(acc[i], 0.f);
}

// offconv as MFMA GEMM: M=64 px, K=9*64, N=27(pad32). Writes om[b][p][27].
__global__ __launch_bounds__(256) void offconv_mfma_kernel(const float* __restrict__ off_b, float* __restrict__ ws)
{
    __shared__ __align__(16) unsigned short Bt[9 * 32 * 72];   // all-tap B, rows pad72
    __shared__ __align__(16) unsigned short Asm[64 * 72];      // A tile; reused as C float[64][28]

    int tid = threadIdx.x;
    int blk = blockIdx.x;
    int b = blk / 400, t = blk % 400;
    int p0 = t * 64;
    int lane = tid & 63, cb = tid >> 6;
    int px = lane;
    int p = p0 + px;
    int h = p / W_, w = p % W_;
    int mrow = lane & 15, quad = lane >> 4;

    const unsigned short* rwb = (const unsigned short*)(ws + RWB_OFF);
    const float* xb = ws + X_OFF + (size_t)b * HW_ * 64;

    // stage all 9 B tiles once (rows 64 -> pad 72)
    for (int i = tid; i < 2592; i += 256) {
        int row = i / 9, cj = i % 9;
        bf16x8 v = {0, 0, 0, 0, 0, 0, 0, 0};
        if (cj < 8) v = *(const bf16x8*)(rwb + row * 64 + cj * 8);
        *(bf16x8*)(Bt + row * 72 + cj * 8) = v;
    }

    f32x4 acc[2];
    acc[0] = (f32x4){0.f, 0.f, 0.f, 0.f};
    acc[1] = (f32x4){0.f, 0.f, 0.f, 0.f};

    for (int tap = 0; tap < 9; ++tap) {
        __syncthreads();  // prev A reads done; first iter: Bt staged
        int yy = h + tap / 3 - 1;
        int xx = w + tap % 3 - 1;
        bool valid = (yy >= 0) && (yy < H_) && (xx >= 0) && (xx < W_);
        bf16x8 pk0 = {0, 0, 0, 0, 0, 0, 0, 0}, pk1 = pk0;
        if (valid) {
            const float* src = xb + ((size_t)(yy * W_ + xx)) * 64 + cb * 16;
#pragma unroll
            for (int c4 = 0; c4 < 2; c4++) {
                f32x4 g0 = *(const f32x4*)(src + c4 * 8);
                f32x4 g1 = *(const f32x4*)(src + c4 * 8 + 4);
#pragma unroll
                for (int j = 0; j < 4; j++) {
                    pk0[c4 * 8 + j]     = (short)f2bf(g0[j]);
                    pk0[c4 * 8 + j + 4] = (short)f2bf(g1[j]);
                }
            }
            // pk0 holds ch 0..7 of group? fix: fill both halves properly
        }
        // rebuild cleanly (compiler folds): 16 channels -> two bf16x8
        if (valid) {
            const float* src = xb + ((size_t)(yy * W_ + xx)) * 64 + cb * 16;
            f32x4 g0 = *(const f32x4*)(src);
            f32x4 g1 = *(const f32x4*)(src + 4);
            f32x4 g2 = *(const f32x4*)(src + 8);
            f32x4 g3 = *(const f32x4*)(src + 12);
#pragma unroll
            for (int j = 0; j < 4; j++) {
                pk0[j]     = (short)f2bf(g0[j]);
                pk0[j + 4] = (short)f2bf(g1[j]);
                pk1[j]     = (short)f2bf(g2[j]);
                pk1[j + 4] = (short)f2bf(g3[j]);
            }
        }
        unsigned short* dst = Asm + px * 72 + cb * 16;
        *(bf16x8*)(dst)     = pk0;
        *(bf16x8*)(dst + 8) = pk1;
        __syncthreads();

        const unsigned short* Ab = Asm + (cb * 16 + mrow) * 72;
#pragma unroll
        for (int ks = 0; ks < 2; ks++) {
            bf16x8 af = *(const bf16x8*)(Ab + ks * 32 + quad * 8);
#pragma unroll
            for (int nt = 0; nt < 2; nt++) {
                bf16x8 bf_ = *(const bf16x8*)(Bt + (tap * 32 + nt * 16 + mrow) * 72 + ks * 32 + quad * 8);
                acc[nt] = __builtin_amdgcn_mfma_f32_16x16x32_bf16(af, bf_, acc[nt], 0, 0, 0);
            }
        }
    }

    __syncthreads();
    float* Cl = (float*)Asm;  // [64 px][28]
#pragma unroll
    for (int nt = 0; nt < 2; nt++) {
        int o = nt * 16 + mrow;
        if (o < 27) {
            int pr = cb * 16 + quad * 4;
#pragma unroll
            for (int r = 0; r < 4; r++) Cl[(pr + r) * 28 + o] = acc[nt][r];
        }
    }
    __syncthreads();

    int j = tid >> 6;
    for (int k = j; k < 9; k += 4) {
        float ady = Cl[px * 28 + 2 * k]     + off_b[2 * k];
        float adx = Cl[px * 28 + 2 * k + 1] + off_b[2 * k + 1];
        float am  = Cl[px * 28 + 18 + k]    + off_b[18 + k];
        float sy = (float)(h + k / 3 - 1) + ady;
        float sx = (float)(w + k % 3 - 1) + adx;
        float mk = 1.f / (1.f + __expf(-am));
        float* om = ws + OM_OFF + ((size_t)b * HW_ + p) * 27 + 3 * k;
        om[0] = sy; om[1] = sx; om[2] = mk;
    }
}

// dcn: MFMA GEMM with NHWC float4 gathers; om staged in LDS
__global__ __launch_bounds__(256) void dcn_mfma_kernel(const float* __restrict__ ws, float* __restrict__ out)
{
    __shared__ __align__(16) unsigned short smem[2 * 64 * 72];  // A | B; reused as C float[64][65]
    __shared__ float OMs[64 * 27];
    unsigned short* A_lds = smem;
    unsigned short* B_lds = smem + 64 * 72;

    int tid = threadIdx.x;
    int blk = blockIdx.x;
    int b = blk / 400, t = blk % 400;
    int p0 = t * 64;
    int lane = tid & 63, cb = tid >> 6;
    int px = lane;
    int mrow = lane & 15, quad = lane >> 4;

    const float* xb  = ws + X_OFF + (size_t)b * HW_ * 64;
    const unsigned short* wtb = (const unsigned short*)(ws + WTB_OFF);
    const float* sb  = ws + SB_OFF + 4 * 128;  // final bn

    // stage om for this block's 64 px
    {
        const float* omg = ws + OM_OFF + ((size_t)b * HW_ + p0) * 27;
        for (int i = tid; i < 64 * 27; i += 256) OMs[i] = omg[i];
    }

    f32x4 acc[4];
#pragma unroll
    for (int nt = 0; nt < 4; nt++) acc[nt] = (f32x4){0.f, 0.f, 0.f, 0.f};

    for (int k = 0; k < 9; ++k) {
        __syncthreads();  // prev LDS reads done; first iter: OMs staged
        // stage B tile (bf16x8 chunks, contiguous)
        {
            const bf16x8* src = (const bf16x8*)(wtb + k * 4608);
            bf16x8* dst = (bf16x8*)B_lds;
            for (int i = tid; i < 576; i += 256) dst[i] = src[i];
        }
        // gather: A[px][cb*16 .. +15]
        float sy = OMs[px * 27 + 3 * k];
        float sx = OMs[px * 27 + 3 * k + 1];
        float mk = OMs[px * 27 + 3 * k + 2];
        float y0f = floorf(sy), x0f = floorf(sx);
        int y0 = (int)y0f, x0 = (int)x0f;
        float ty = sy - y0f, tx = sx - x0f;

        float val[16];
#pragma unroll
        for (int i = 0; i < 16; i++) val[i] = 0.f;
#pragma unroll
        for (int cr = 0; cr < 4; cr++) {
            int dy = cr >> 1, dx = cr & 1;
            int yy = y0 + dy, xx = x0 + dx;
            float wy = dy ? ty : 1.f - ty;
            float wx = dx ? tx : 1.f - tx;
            bool vld = (yy >= 0) && (yy < H_) && (xx >= 0) && (xx < W_);
            int yc = min(max(yy, 0), H_ - 1);
            int xc = min(max(xx, 0), W_ - 1);
            float wv = vld ? wy * wx * mk : 0.f;
            const float* src = xb + ((size_t)(yc * W_ + xc)) * 64 + cb * 16;
#pragma unroll
            for (int c4 = 0; c4 < 4; c4++) {
                f32x4 g = *(const f32x4*)(src + c4 * 4);
#pragma unroll
                for (int jj = 0; jj < 4; jj++) val[c4 * 4 + jj] = fmaf(g[jj], wv, val[c4 * 4 + jj]);
            }
        }
        bf16x8 pk0, pk1;
#pragma unroll
        for (int jj = 0; jj < 8; jj++) {
            pk0[jj] = (short)f2bf(val[jj]);
            pk1[jj] = (short)f2bf(val[8 + jj]);
        }
        unsigned short* dst = A_lds + px * 72 + cb * 16;
        *(bf16x8*)(dst)     = pk0;
        *(bf16x8*)(dst + 8) = pk1;
        __syncthreads();

        // MFMA: wave cb -> C rows cb*16..+15 (pixels), cols 0..63 (out ch)
        const unsigned short* Ab = A_lds + (cb * 16 + mrow) * 72;
#pragma unroll
        for (int ks = 0; ks < 2; ks++) {
            bf16x8 af = *(const bf16x8*)(Ab + ks * 32 + quad * 8);
#pragma unroll
            for (int nt = 0; nt < 4; nt++) {
                bf16x8 bf_ = *(const bf16x8*)(B_lds + (nt * 16 + mrow) * 72 + ks * 32 + quad * 8);
                acc[nt] = __builtin_amdgcn_mfma_f32_16x16x32_bf16(af, bf_, acc[nt], 0, 0, 0);
            }
        }
    }

    // epilogue: C frag (col o = mrow(+nt*16), row px = quad*4+r (+cb*16)) -> LDS [o][px pad65] -> NCHW store
    __syncthreads();
    float* C_lds = (float*)smem;
#pragma unroll
    for (int nt = 0; nt < 4; nt++) {
        int o = nt * 16 + mrow;
        int pxb = cb * 16 + quad * 4;
#pragma unroll
        for (int r = 0; r < 4; r++) C_lds[o * 65 + pxb + r] = acc[nt][r];
    }
    __syncthreads();
#pragma unroll
    for (int i = 0; i < 16; i++) {
        int o = cb * 16 + i;
        float v = C_lds[o * 65 + lane];
        v = fmaf(v, sb[o], sb[64 + o]);
        out[((size_t)b * 64 + o) * HW_ + p0 + lane] = fmaxf(v, 0.f);
    }
}

extern "C" void kernel_launch(void* const* d_in, const int* in_sizes, int n_in,
                              void* d_out, int out_size, void* d_ws, size_t ws_size,
                              hipStream_t stream)
{
    const float* f0 = (const float*)d_in[0];
    const float* f1 = (const float*)d_in[1];
    const float* f2 = (const float*)d_in[2];
    const float* f3 = (const float*)d_in[3];
    const float* w0 = (const float*)d_in[4];
    const float* g0 = (const float*)d_in[5];
    const float* b0 = (const float*)d_in[6];
    const float* m0 = (const float*)d_in[7];
    const float* v0 = (const float*)d_in[8];
    const float* w1 = (const float*)d_in[9];
    const float* g1 = (const float*)d_in[10];
    const float* b1 = (const float*)d_in[11];
    const float* m1 = (const float*)d_in[12];
    const float* v1 = (const float*)d_in[13];
    const float* w2 = (const float*)d_in[14];
    const float* g2 = (const float*)d_in[15];
    const float* b2 = (const float*)d_in[16];
    const float* m2 = (const float*)d_in[17];
    const float* v2 = (const float*)d_in[18];
    const float* w3 = (const float*)d_in[19];
    const float* g3 = (const float*)d_in[20];
    const float* b3 = (const float*)d_in[21];
    const float* m3 = (const float*)d_in[22];
    const float* v3 = (const float*)d_in[23];
    const float* off_w = (const float*)d_in[24];
    const float* off_b = (const float*)d_in[25];
    const float* dcn_w = (const float*)d_in[26];
    const float* gf = (const float*)d_in[27];
    const float* bf = (const float*)d_in[28];
    const float* mf = (const float*)d_in[29];
    const float* vf = (const float*)d_in[30];

    float* ws  = (float*)d_ws;
    float* out = (float*)d_out;

    // prep: 320 + 4096 + 41472 + 18432 = 64320 threads -> 252 blocks
    prep_kernel<<<dim3(252), dim3(256), 0, stream>>>(
        g0, b0, m0, v0, g1, b1, m1, v1, g2, b2, m2, v2, g3, b3, m3, v3,
        gf, bf, mf, vf, w0, dcn_w, off_w, ws);

    // 1x1 convs + bn -> NHWC y
    conv1x1_bn_kernel<<<dim3(6400), dim3(256), 0, stream>>>(f1, w1, ws + SB_OFF + 128, ws + Y1_OFF, 128, 6400);
    conv1x1_bn_kernel<<<dim3(1600), dim3(256), 0, stream>>>(f2, w2, ws + SB_OFF + 256, ws + Y2_OFF, 256, 1600);
    conv1x1_bn_kernel<<<dim3(400),  dim3(256), 0, stream>>>(f3, w3, ws + SB_OFF + 384, ws + Y3_OFF, 512, 400);

    // fuse -> x (NHWC)
    fuse_kernel<<<dim3(1600), dim3(256), 0, stream>>>(f0, ws);

    // offset conv via MFMA -> om [b][p][27]
    offconv_mfma_kernel<<<dim3(1600), dim3(256), 0, stream>>>(off_b, ws);

    // deformable conv via MFMA + final bn + relu
    dcn_mfma_kernel<<<dim3(1600), dim3(256), 0, stream>>>(ws, out);
}

// Round 6
// 548.230 us; speedup vs baseline: 1.4280x; 1.0744x over previous
//
#include <hip/hip_runtime.h>
#include <math.h>

#define EPSB 1e-5f

constexpr int B_ = 4;
constexpr int C_ = 64;
constexpr int H_ = 160;
constexpr int W_ = 160;
constexpr int HW_ = H_ * W_;

// workspace layout (float offsets) — round-3 layout, total 11,503,488 floats = 46.01 MB
constexpr size_t X_OFF   = 0;                                    // x NHWC: [b][p][64]
constexpr size_t Y1_OFF  = X_OFF  + (size_t)B_ * HW_ * 64;       // y1 NHWC @80x80
constexpr size_t Y2_OFF  = Y1_OFF + (size_t)B_ * 6400 * 64;      // y2 NHWC @40x40
constexpr size_t Y3_OFF  = Y2_OFF + (size_t)B_ * 1600 * 64;      // y3 NHWC @20x20
constexpr size_t OM_OFF  = Y3_OFF + (size_t)B_ * 400 * 64;       // om: [b][p][27] (sy,sx,mk)*9
constexpr size_t WR0_OFF = OM_OFF + (size_t)B_ * HW_ * 27;       // w0 fp32 [ci][o]: 4096
constexpr size_t WTB_OFF = WR0_OFF + 4096;                       // dcn_w bf16 [k][o][c pad72]: 41472 ush
constexpr size_t RWB_OFF = WTB_OFF + (9 * 64 * 72) / 2;          // off_w bf16 [tap][o pad32][ci]: 18432 ush
constexpr size_t SB_OFF  = RWB_OFF + (9 * 32 * 64) / 2;          // 5 BNs x (scale[64], bias[64])
// transposed conv1x1 weights OVERLAID at head of X region:
// written by prep, read by conv1x1 kernels, clobbered afterwards by fuse (stream-ordered).
constexpr size_t WR1_OFF = X_OFF + 0;       // w1 fp32 [ci][o]: 128*64 = 8192
constexpr size_t WR2_OFF = X_OFF + 8192;    // w2 fp32 [ci][o]: 256*64 = 16384
constexpr size_t WR3_OFF = X_OFF + 24576;   // w3 fp32 [ci][o]: 512*64 = 32768 (ends 57344 << X size)

typedef short bf16x8 __attribute__((ext_vector_type(8)));
typedef float f32x4 __attribute__((ext_vector_type(4)));

static __device__ __forceinline__ unsigned short f2bf(float f) {
    unsigned int u = __float_as_uint(f);
    u += 0x7fff + ((u >> 16) & 1);   // RNE
    return (unsigned short)(u >> 16);
}

__global__ __launch_bounds__(256) void prep_kernel(
    const float* __restrict__ g0, const float* __restrict__ b0, const float* __restrict__ m0, const float* __restrict__ v0,
    const float* __restrict__ g1, const float* __restrict__ b1, const float* __restrict__ m1, const float* __restrict__ v1,
    const float* __restrict__ g2, const float* __restrict__ b2, const float* __restrict__ m2, const float* __restrict__ v2,
    const float* __restrict__ g3, const float* __restrict__ b3, const float* __restrict__ m3, const float* __restrict__ v3,
    const float* __restrict__ gf, const float* __restrict__ bf, const float* __restrict__ mf, const float* __restrict__ vf,
    const float* __restrict__ w0, const float* __restrict__ w1, const float* __restrict__ w2, const float* __restrict__ w3,
    const float* __restrict__ dcn_w, const float* __restrict__ off_w,
    float* __restrict__ ws)
{
    int tid = blockIdx.x * 256 + threadIdx.x;
    if (tid < 320) {  // BN scale/bias fold
        int j = tid >> 6, c = tid & 63;
        const float *g, *b, *m, *v;
        switch (j) {
            case 0: g = g0; b = b0; m = m0; v = v0; break;
            case 1: g = g1; b = b1; m = m1; v = v1; break;
            case 2: g = g2; b = b2; m = m2; v = v2; break;
            case 3: g = g3; b = b3; m = m3; v = v3; break;
            default: g = gf; b = bf; m = mf; v = vf; break;
        }
        float sc = g[c] * rsqrtf(v[c] + EPSB);
        ws[SB_OFF + j * 128 + c]      = sc;
        ws[SB_OFF + j * 128 + 64 + c] = b[c] - m[c] * sc;
        return;
    }
    int t = tid - 320;
    if (t < 4096) {  // wr0[ci*64+o] = w0[o*64+ci]
        int ci = t >> 6, o = t & 63;
        ws[WR0_OFF + t] = w0[o * 64 + ci];
        return;
    }
    t -= 4096;
    if (t < 9 * 64 * 72) {  // wtb[k][o][c pad72] bf16 = dcn_w[o][c][k]   (round-3 exact)
        int k = t / 4608, r = t % 4608, o = r / 72, c = r % 72;
        float v = (c < 64) ? dcn_w[o * 576 + c * 9 + k] : 0.f;
        ((unsigned short*)(ws + WTB_OFF))[t] = f2bf(v);
        return;
    }
    t -= 9 * 64 * 72;
    if (t < 9 * 32 * 64) {  // rwb[tap][o pad32][ci] bf16 = off_w[o][ci][tap]   (round-3 exact)
        int tap = t >> 11, r = t & 2047, o = r >> 6, ci = r & 63;
        float v = (o < 27) ? off_w[o * 576 + ci * 9 + tap] : 0.f;
        ((unsigned short*)(ws + RWB_OFF))[t] = f2bf(v);
        return;
    }
    t -= 9 * 32 * 64;
    if (t < 8192) {  // wr1[ci*64+o] = w1[o*128+ci]
        int ci = t >> 6, o = t & 63;
        ws[WR1_OFF + t] = w1[o * 128 + ci];
        return;
    }
    t -= 8192;
    if (t < 16384) {  // wr2[ci*64+o] = w2[o*256+ci]
        int ci = t >> 6, o = t & 63;
        ws[WR2_OFF + t] = w2[o * 256 + ci];
        return;
    }
    t -= 16384;
    if (t < 32768) {  // wr3[ci*64+o] = w3[o*512+ci]
        int ci = t >> 6, o = t & 63;
        ws[WR3_OFF + t] = w3[o * 512 + ci];
        return;
    }
}

// wave = one (b,p); lanes = 64 output channels; weights [ci][o] -> coalesced. NHWC out.
__global__ __launch_bounds__(256) void conv1x1_bn_kernel(
    const float* __restrict__ f, const float* __restrict__ wr,
    const float* __restrict__ sb, float* __restrict__ out, int Cin, int hw)
{
    int tid = blockIdx.x * 256 + threadIdx.x;
    int o = tid & 63;
    int rest = tid >> 6;
    int p = rest % hw;
    int b = rest / hw;
    p = __builtin_amdgcn_readfirstlane(p);
    b = __builtin_amdgcn_readfirstlane(b);
    const float* fb = f + (size_t)b * Cin * hw + p;
    float acc = 0.f;
#pragma unroll 8
    for (int ci = 0; ci < Cin; ++ci) acc = fmaf(fb[(size_t)ci * hw], wr[ci * 64 + o], acc);
    out[((size_t)b * hw + p) * 64 + o] = fmaf(acc, sb[o], sb[64 + o]);
}

// block = 64 px x 4 ch-groups; NHWC y-reads (float4) and NHWC x-write   (round-3 verbatim)
__global__ __launch_bounds__(256) void fuse_kernel(const float* __restrict__ f0, float* __restrict__ ws)
{
    int tid = threadIdx.x;
    int blk = blockIdx.x;
    int b = blk / 400, t = blk % 400;
    int p0 = t * 64;
    int lane = tid & 63, cb = tid >> 6;
    int p = p0 + lane;
    int h = p / W_, w = p % W_;
    const float* wr0 = ws + WR0_OFF + cb * 16;
    const float* sb  = ws + SB_OFF;  // bn0

    float acc[16];
#pragma unroll
    for (int i = 0; i < 16; i++) acc[i] = 0.f;

    const float* f0b = f0 + (size_t)b * 64 * HW_ + p;
    for (int ci = 0; ci < 64; ++ci) {
        float fv = f0b[(size_t)ci * HW_];
        const float* wrow = wr0 + ci * 64;
#pragma unroll
        for (int i = 0; i < 16; i++) acc[i] = fmaf(fv, wrow[i], acc[i]);
    }
#pragma unroll
    for (int i = 0; i < 16; i++) {
        int o = cb * 16 + i;
        acc[i] = fmaf(acc[i], sb[o], sb[64 + o]);
    }

    {   // +upsample x2 from 80x80 (align_corners), NHWC
        float fy = h * (79.f / 159.f); int i0 = (int)fy; if (i0 > 78) i0 = 78; float ty = fy - i0;
        float fx = w * (79.f / 159.f); int j0 = (int)fx; if (j0 > 78) j0 = 78; float tx = fx - j0;
        float w00 = (1.f - ty) * (1.f - tx), w01 = (1.f - ty) * tx, w10 = ty * (1.f - tx), w11 = ty * tx;
        const float* y = ws + Y1_OFF + ((size_t)b * 6400 + (size_t)(i0 * 80 + j0)) * 64 + cb * 16;
#pragma unroll
        for (int c4 = 0; c4 < 4; c4++) {
            f32x4 a00 = *(const f32x4*)(y + c4 * 4);
            f32x4 a01 = *(const f32x4*)(y + 64 + c4 * 4);
            f32x4 a10 = *(const f32x4*)(y + 80 * 64 + c4 * 4);
            f32x4 a11 = *(const f32x4*)(y + 81 * 64 + c4 * 4);
#pragma unroll
            for (int j = 0; j < 4; j++)
                acc[c4 * 4 + j] += a00[j] * w00 + a01[j] * w01 + a10[j] * w10 + a11[j] * w11;
        }
    }
    {   // +upsample x4 from 40x40
        float fy = h * (39.f / 159.f); int i0 = (int)fy; if (i0 > 38) i0 = 38; float ty = fy - i0;
        float fx = w * (39.f / 159.f); int j0 = (int)fx; if (j0 > 38) j0 = 38; float tx = fx - j0;
        float w00 = (1.f - ty) * (1.f - tx), w01 = (1.f - ty) * tx, w10 = ty * (1.f - tx), w11 = ty * tx;
        const float* y = ws + Y2_OFF + ((size_t)b * 1600 + (size_t)(i0 * 40 + j0)) * 64 + cb * 16;
#pragma unroll
        for (int c4 = 0; c4 < 4; c4++) {
            f32x4 a00 = *(const f32x4*)(y + c4 * 4);
            f32x4 a01 = *(const f32x4*)(y + 64 + c4 * 4);
            f32x4 a10 = *(const f32x4*)(y + 40 * 64 + c4 * 4);
            f32x4 a11 = *(const f32x4*)(y + 41 * 64 + c4 * 4);
#pragma unroll
            for (int j = 0; j < 4; j++)
                acc[c4 * 4 + j] += a00[j] * w00 + a01[j] * w01 + a10[j] * w10 + a11[j] * w11;
        }
    }
    {   // +upsample x8 from 20x20
        float fy = h * (19.f / 159.f); int i0 = (int)fy; if (i0 > 18) i0 = 18; float ty = fy - i0;
        float fx = w * (19.f / 159.f); int j0 = (int)fx; if (j0 > 18) j0 = 18; float tx = fx - j0;
        float w00 = (1.f - ty) * (1.f - tx), w01 = (1.f - ty) * tx, w10 = ty * (1.f - tx), w11 = ty * tx;
        const float* y = ws + Y3_OFF + ((size_t)b * 400 + (size_t)(i0 * 20 + j0)) * 64 + cb * 16;
#pragma unroll
        for (int c4 = 0; c4 < 4; c4++) {
            f32x4 a00 = *(const f32x4*)(y + c4 * 4);
            f32x4 a01 = *(const f32x4*)(y + 64 + c4 * 4);
            f32x4 a10 = *(const f32x4*)(y + 20 * 64 + c4 * 4);
            f32x4 a11 = *(const f32x4*)(y + 21 * 64 + c4 * 4);
#pragma unroll
            for (int j = 0; j < 4; j++)
                acc[c4 * 4 + j] += a00[j] * w00 + a01[j] * w01 + a10[j] * w10 + a11[j] * w11;
        }
    }

    float* x = ws + X_OFF + ((size_t)b * HW_ + p) * 64 + cb * 16;
#pragma unroll
    for (int i = 0; i < 16; i++) x[i] = fmaxf(acc[i], 0.f);
}

// offconv as MFMA GEMM: M=64 px, K=9*64, N=27(pad32). Writes om[b][p][27].  (round-3 verbatim)
__global__ __launch_bounds__(256) void offconv_mfma_kernel(const float* __restrict__ off_b, float* __restrict__ ws)
{
    __shared__ __align__(16) unsigned short Bt[9 * 32 * 72];   // all-tap B, rows pad72
    __shared__ __align__(16) unsigned short Asm[64 * 72];      // A tile; reused as C float[64][28]

    int tid = threadIdx.x;
    int blk = blockIdx.x;
    int b = blk / 400, t = blk % 400;
    int p0 = t * 64;
    int lane = tid & 63, cb = tid >> 6;
    int px = lane;
    int p = p0 + px;
    int h = p / W_, w = p % W_;
    int mrow = lane & 15, quad = lane >> 4;

    const unsigned short* rwb = (const unsigned short*)(ws + RWB_OFF);
    const float* xb = ws + X_OFF + (size_t)b * HW_ * 64;

    // stage all 9 B tiles once (rows 64 -> pad 72)
    for (int i = tid; i < 2592; i += 256) {
        int row = i / 9, cj = i % 9;
        bf16x8 v = {0, 0, 0, 0, 0, 0, 0, 0};
        if (cj < 8) v = *(const bf16x8*)(rwb + row * 64 + cj * 8);
        *(bf16x8*)(Bt + row * 72 + cj * 8) = v;
    }

    f32x4 acc[2];
    acc[0] = (f32x4){0.f, 0.f, 0.f, 0.f};
    acc[1] = (f32x4){0.f, 0.f, 0.f, 0.f};

    for (int tap = 0; tap < 9; ++tap) {
        __syncthreads();  // prev A reads done; first iter: Bt staged
        int yy = h + tap / 3 - 1;
        int xx = w + tap % 3 - 1;
        bool valid = (yy >= 0) && (yy < H_) && (xx >= 0) && (xx < W_);
        bf16x8 pk0 = {0, 0, 0, 0, 0, 0, 0, 0}, pk1 = pk0;
        if (valid) {
            const float* src = xb + ((size_t)(yy * W_ + xx)) * 64 + cb * 16;
            f32x4 g0 = *(const f32x4*)(src);
            f32x4 g1 = *(const f32x4*)(src + 4);
            f32x4 g2 = *(const f32x4*)(src + 8);
            f32x4 g3 = *(const f32x4*)(src + 12);
#pragma unroll
            for (int j = 0; j < 4; j++) {
                pk0[j]     = (short)f2bf(g0[j]);
                pk0[j + 4] = (short)f2bf(g1[j]);
                pk1[j]     = (short)f2bf(g2[j]);
                pk1[j + 4] = (short)f2bf(g3[j]);
            }
        }
        unsigned short* dst = Asm + px * 72 + cb * 16;
        *(bf16x8*)(dst)     = pk0;
        *(bf16x8*)(dst + 8) = pk1;
        __syncthreads();

        const unsigned short* Ab = Asm + (cb * 16 + mrow) * 72;
#pragma unroll
        for (int ks = 0; ks < 2; ks++) {
            bf16x8 af = *(const bf16x8*)(Ab + ks * 32 + quad * 8);
#pragma unroll
            for (int nt = 0; nt < 2; nt++) {
                bf16x8 bf_ = *(const bf16x8*)(Bt + (tap * 32 + nt * 16 + mrow) * 72 + ks * 32 + quad * 8);
                acc[nt] = __builtin_amdgcn_mfma_f32_16x16x32_bf16(af, bf_, acc[nt], 0, 0, 0);
            }
        }
    }

    __syncthreads();
    float* Cl = (float*)Asm;  // [64 px][28]
#pragma unroll
    for (int nt = 0; nt < 2; nt++) {
        int o = nt * 16 + mrow;
        if (o < 27) {
            int pr = cb * 16 + quad * 4;
#pragma unroll
            for (int r = 0; r < 4; r++) Cl[(pr + r) * 28 + o] = acc[nt][r];
        }
    }
    __syncthreads();

    int j = tid >> 6;
    for (int k = j; k < 9; k += 4) {
        float ady = Cl[px * 28 + 2 * k]     + off_b[2 * k];
        float adx = Cl[px * 28 + 2 * k + 1] + off_b[2 * k + 1];
        float am  = Cl[px * 28 + 18 + k]    + off_b[18 + k];
        float sy = (float)(h + k / 3 - 1) + ady;
        float sx = (float)(w + k % 3 - 1) + adx;
        float mk = 1.f / (1.f + __expf(-am));
        float* om = ws + OM_OFF + ((size_t)b * HW_ + p) * 27 + 3 * k;
        om[0] = sy; om[1] = sx; om[2] = mk;
    }
}

// dcn: MFMA GEMM with NHWC float4 gathers; om staged in LDS   (round-3 verbatim)
__global__ __launch_bounds__(256) void dcn_mfma_kernel(const float* __restrict__ ws, float* __restrict__ out)
{
    __shared__ __align__(16) unsigned short smem[2 * 64 * 72];  // A | B; reused as C float[64][65]
    __shared__ float OMs[64 * 27];
    unsigned short* A_lds = smem;
    unsigned short* B_lds = smem + 64 * 72;

    int tid = threadIdx.x;
    int blk = blockIdx.x;
    int b = blk / 400, t = blk % 400;
    int p0 = t * 64;
    int lane = tid & 63, cb = tid >> 6;
    int px = lane;
    int mrow = lane & 15, quad = lane >> 4;

    const float* xb  = ws + X_OFF + (size_t)b * HW_ * 64;
    const unsigned short* wtb = (const unsigned short*)(ws + WTB_OFF);
    const float* sb  = ws + SB_OFF + 4 * 128;  // final bn

    // stage om for this block's 64 px
    {
        const float* omg = ws + OM_OFF + ((size_t)b * HW_ + p0) * 27;
        for (int i = tid; i < 64 * 27; i += 256) OMs[i] = omg[i];
    }

    f32x4 acc[4];
#pragma unroll
    for (int nt = 0; nt < 4; nt++) acc[nt] = (f32x4){0.f, 0.f, 0.f, 0.f};

    for (int k = 0; k < 9; ++k) {
        __syncthreads();  // prev LDS reads done; first iter: OMs staged
        // stage B tile (bf16x8 chunks, contiguous)
        {
            const bf16x8* src = (const bf16x8*)(wtb + k * 4608);
            bf16x8* dst = (bf16x8*)B_lds;
            for (int i = tid; i < 576; i += 256) dst[i] = src[i];
        }
        // gather: A[px][cb*16 .. +15]
        float sy = OMs[px * 27 + 3 * k];
        float sx = OMs[px * 27 + 3 * k + 1];
        float mk = OMs[px * 27 + 3 * k + 2];
        float y0f = floorf(sy), x0f = floorf(sx);
        int y0 = (int)y0f, x0 = (int)x0f;
        float ty = sy - y0f, tx = sx - x0f;

        float val[16];
#pragma unroll
        for (int i = 0; i < 16; i++) val[i] = 0.f;
#pragma unroll
        for (int cr = 0; cr < 4; cr++) {
            int dy = cr >> 1, dx = cr & 1;
            int yy = y0 + dy, xx = x0 + dx;
            float wy = dy ? ty : 1.f - ty;
            float wx = dx ? tx : 1.f - tx;
            bool vld = (yy >= 0) && (yy < H_) && (xx >= 0) && (xx < W_);
            int yc = min(max(yy, 0), H_ - 1);
            int xc = min(max(xx, 0), W_ - 1);
            float wv = vld ? wy * wx * mk : 0.f;
            const float* src = xb + ((size_t)(yc * W_ + xc)) * 64 + cb * 16;
#pragma unroll
            for (int c4 = 0; c4 < 4; c4++) {
                f32x4 g = *(const f32x4*)(src + c4 * 4);
#pragma unroll
                for (int jj = 0; jj < 4; jj++) val[c4 * 4 + jj] = fmaf(g[jj], wv, val[c4 * 4 + jj]);
            }
        }
        bf16x8 pk0, pk1;
#pragma unroll
        for (int jj = 0; jj < 8; jj++) {
            pk0[jj] = (short)f2bf(val[jj]);
            pk1[jj] = (short)f2bf(val[8 + jj]);
        }
        unsigned short* dst = A_lds + px * 72 + cb * 16;
        *(bf16x8*)(dst)     = pk0;
        *(bf16x8*)(dst + 8) = pk1;
        __syncthreads();

        // MFMA: wave cb -> C rows cb*16..+15 (pixels), cols 0..63 (out ch)
        const unsigned short* Ab = A_lds + (cb * 16 + mrow) * 72;
#pragma unroll
        for (int ks = 0; ks < 2; ks++) {
            bf16x8 af = *(const bf16x8*)(Ab + ks * 32 + quad * 8);
#pragma unroll
            for (int nt = 0; nt < 4; nt++) {
                bf16x8 bf_ = *(const bf16x8*)(B_lds + (nt * 16 + mrow) * 72 + ks * 32 + quad * 8);
                acc[nt] = __builtin_amdgcn_mfma_f32_16x16x32_bf16(af, bf_, acc[nt], 0, 0, 0);
            }
        }
    }

    // epilogue: C frag (col o = mrow(+nt*16), row px = quad*4+r (+cb*16)) -> LDS [o][px pad65] -> NCHW store
    __syncthreads();
    float* C_lds = (float*)smem;
#pragma unroll
    for (int nt = 0; nt < 4; nt++) {
        int o = nt * 16 + mrow;
        int pxb = cb * 16 + quad * 4;
#pragma unroll
        for (int r = 0; r < 4; r++) C_lds[o * 65 + pxb + r] = acc[nt][r];
    }
    __syncthreads();
#pragma unroll
    for (int i = 0; i < 16; i++) {
        int o = cb * 16 + i;
        float v = C_lds[o * 65 + lane];
        v = fmaf(v, sb[o], sb[64 + o]);
        out[((size_t)b * 64 + o) * HW_ + p0 + lane] = fmaxf(v, 0.f);
    }
}

extern "C" void kernel_launch(void* const* d_in, const int* in_sizes, int n_in,
                              void* d_out, int out_size, void* d_ws, size_t ws_size,
                              hipStream_t stream)
{
    const float* f0 = (const float*)d_in[0];
    const float* f1 = (const float*)d_in[1];
    const float* f2 = (const float*)d_in[2];
    const float* f3 = (const float*)d_in[3];
    const float* w0 = (const float*)d_in[4];
    const float* g0 = (const float*)d_in[5];
    const float* b0 = (const float*)d_in[6];
    const float* m0 = (const float*)d_in[7];
    const float* v0 = (const float*)d_in[8];
    const float* w1 = (const float*)d_in[9];
    const float* g1 = (const float*)d_in[10];
    const float* b1 = (const float*)d_in[11];
    const float* m1 = (const float*)d_in[12];
    const float* v1 = (const float*)d_in[13];
    const float* w2 = (const float*)d_in[14];
    const float* g2 = (const float*)d_in[15];
    const float* b2 = (const float*)d_in[16];
    const float* m2 = (const float*)d_in[17];
    const float* v2 = (const float*)d_in[18];
    const float* w3 = (const float*)d_in[19];
    const float* g3 = (const float*)d_in[20];
    const float* b3 = (const float*)d_in[21];
    const float* m3 = (const float*)d_in[22];
    const float* v3 = (const float*)d_in[23];
    const float* off_w = (const float*)d_in[24];
    const float* off_b = (const float*)d_in[25];
    const float* dcn_w = (const float*)d_in[26];
    const float* gf = (const float*)d_in[27];
    const float* bf = (const float*)d_in[28];
    const float* mf = (const float*)d_in[29];
    const float* vf = (const float*)d_in[30];

    float* ws  = (float*)d_ws;
    float* out = (float*)d_out;

    // prep: 320 + 4096 + 41472 + 18432 + 8192 + 16384 + 32768 = 121,664 -> 476 blocks
    prep_kernel<<<dim3(476), dim3(256), 0, stream>>>(
        g0, b0, m0, v0, g1, b1, m1, v1, g2, b2, m2, v2, g3, b3, m3, v3,
        gf, bf, mf, vf, w0, w1, w2, w3, dcn_w, off_w, ws);

    // 1x1 convs + bn -> NHWC y (coalesced [ci][o] weights; wr regions die before fuse overwrites X)
    conv1x1_bn_kernel<<<dim3(6400), dim3(256), 0, stream>>>(f1, ws + WR1_OFF, ws + SB_OFF + 128, ws + Y1_OFF, 128, 6400);
    conv1x1_bn_kernel<<<dim3(1600), dim3(256), 0, stream>>>(f2, ws + WR2_OFF, ws + SB_OFF + 256, ws + Y2_OFF, 256, 1600);
    conv1x1_bn_kernel<<<dim3(400),  dim3(256), 0, stream>>>(f3, ws + WR3_OFF, ws + SB_OFF + 384, ws + Y3_OFF, 512, 400);

    // fuse -> x (NHWC)
    fuse_kernel<<<dim3(1600), dim3(256), 0, stream>>>(f0, ws);

    // offset conv via MFMA -> om [b][p][27]
    offconv_mfma_kernel<<<dim3(1600), dim3(256), 0, stream>>>(off_b, ws);

    // deformable conv via MFMA + final bn + relu
    dcn_mfma_kernel<<<dim3(1600), dim3(256), 0, stream>>>(ws, out);
}

// Round 7
// 496.276 us; speedup vs baseline: 1.5775x; 1.1047x over previous
//
#include <hip/hip_runtime.h>
#include <math.h>

#define EPSB 1e-5f

constexpr int B_ = 4;
constexpr int C_ = 64;
constexpr int H_ = 160;
constexpr int W_ = 160;
constexpr int HW_ = H_ * W_;

// workspace layout (float offsets) — round-3 layout, total 11,503,488 floats = 46.01 MB
constexpr size_t X_OFF   = 0;                                    // x NHWC: [b][p][64]
constexpr size_t Y1_OFF  = X_OFF  + (size_t)B_ * HW_ * 64;       // y1 NHWC @80x80
constexpr size_t Y2_OFF  = Y1_OFF + (size_t)B_ * 6400 * 64;      // y2 NHWC @40x40
constexpr size_t Y3_OFF  = Y2_OFF + (size_t)B_ * 1600 * 64;      // y3 NHWC @20x20
constexpr size_t OM_OFF  = Y3_OFF + (size_t)B_ * 400 * 64;       // om: [b][p][27] (sy,sx,mk)*9
constexpr size_t WR0_OFF = OM_OFF + (size_t)B_ * HW_ * 27;       // w0 fp32 [ci][o]: 4096
constexpr size_t WTB_OFF = WR0_OFF + 4096;                       // dcn_w bf16 [k][o][c pad72]: 41472 ush
constexpr size_t RWB_OFF = WTB_OFF + (9 * 64 * 72) / 2;          // off_w bf16 [tap][o pad32][ci]: 18432 ush
constexpr size_t SB_OFF  = RWB_OFF + (9 * 32 * 64) / 2;          // 5 BNs x (scale[64], bias[64])
// transposed conv1x1 weights OVERLAID at head of X region:
// written by prep, read by conv1x1 kernels, clobbered afterwards by fuse (stream-ordered).
constexpr size_t WR1_OFF = X_OFF + 0;       // w1 fp32 [ci][o]: 128*64 = 8192
constexpr size_t WR2_OFF = X_OFF + 8192;    // w2 fp32 [ci][o]: 256*64 = 16384
constexpr size_t WR3_OFF = X_OFF + 24576;   // w3 fp32 [ci][o]: 512*64 = 32768 (ends 57344 << X size)

typedef short bf16x8 __attribute__((ext_vector_type(8)));
typedef float f32x4 __attribute__((ext_vector_type(4)));

static __device__ __forceinline__ unsigned short f2bf(float f) {
    unsigned int u = __float_as_uint(f);
    u += 0x7fff + ((u >> 16) & 1);   // RNE
    return (unsigned short)(u >> 16);
}

__global__ __launch_bounds__(256) void prep_kernel(
    const float* __restrict__ g0, const float* __restrict__ b0, const float* __restrict__ m0, const float* __restrict__ v0,
    const float* __restrict__ g1, const float* __restrict__ b1, const float* __restrict__ m1, const float* __restrict__ v1,
    const float* __restrict__ g2, const float* __restrict__ b2, const float* __restrict__ m2, const float* __restrict__ v2,
    const float* __restrict__ g3, const float* __restrict__ b3, const float* __restrict__ m3, const float* __restrict__ v3,
    const float* __restrict__ gf, const float* __restrict__ bf, const float* __restrict__ mf, const float* __restrict__ vf,
    const float* __restrict__ w0, const float* __restrict__ w1, const float* __restrict__ w2, const float* __restrict__ w3,
    const float* __restrict__ dcn_w, const float* __restrict__ off_w,
    float* __restrict__ ws)
{
    int tid = blockIdx.x * 256 + threadIdx.x;
    if (tid < 320) {  // BN scale/bias fold
        int j = tid >> 6, c = tid & 63;
        const float *g, *b, *m, *v;
        switch (j) {
            case 0: g = g0; b = b0; m = m0; v = v0; break;
            case 1: g = g1; b = b1; m = m1; v = v1; break;
            case 2: g = g2; b = b2; m = m2; v = v2; break;
            case 3: g = g3; b = b3; m = m3; v = v3; break;
            default: g = gf; b = bf; m = mf; v = vf; break;
        }
        float sc = g[c] * rsqrtf(v[c] + EPSB);
        ws[SB_OFF + j * 128 + c]      = sc;
        ws[SB_OFF + j * 128 + 64 + c] = b[c] - m[c] * sc;
        return;
    }
    int t = tid - 320;
    if (t < 4096) {  // wr0[ci*64+o] = w0[o*64+ci]
        int ci = t >> 6, o = t & 63;
        ws[WR0_OFF + t] = w0[o * 64 + ci];
        return;
    }
    t -= 4096;
    if (t < 9 * 64 * 72) {  // wtb[k][o][c pad72] bf16 = dcn_w[o][c][k]
        int k = t / 4608, r = t % 4608, o = r / 72, c = r % 72;
        float v = (c < 64) ? dcn_w[o * 576 + c * 9 + k] : 0.f;
        ((unsigned short*)(ws + WTB_OFF))[t] = f2bf(v);
        return;
    }
    t -= 9 * 64 * 72;
    if (t < 9 * 32 * 64) {  // rwb[tap][o pad32][ci] bf16 = off_w[o][ci][tap]
        int tap = t >> 11, r = t & 2047, o = r >> 6, ci = r & 63;
        float v = (o < 27) ? off_w[o * 576 + ci * 9 + tap] : 0.f;
        ((unsigned short*)(ws + RWB_OFF))[t] = f2bf(v);
        return;
    }
    t -= 9 * 32 * 64;
    if (t < 8192) {  // wr1[ci*64+o] = w1[o*128+ci]
        int ci = t >> 6, o = t & 63;
        ws[WR1_OFF + t] = w1[o * 128 + ci];
        return;
    }
    t -= 8192;
    if (t < 16384) {  // wr2[ci*64+o] = w2[o*256+ci]
        int ci = t >> 6, o = t & 63;
        ws[WR2_OFF + t] = w2[o * 256 + ci];
        return;
    }
    t -= 16384;
    if (t < 32768) {  // wr3[ci*64+o] = w3[o*512+ci]
        int ci = t >> 6, o = t & 63;
        ws[WR3_OFF + t] = w3[o * 512 + ci];
        return;
    }
}

// wave = one (b,p); lanes = 64 output channels; weights [ci][o] -> coalesced. NHWC out.
// XCD-affinity: grid = hw blocks; xcd=blk&7 owns (b = xcd>>1, half-image xcd&1).
__global__ __launch_bounds__(256) void conv1x1_bn_kernel(
    const float* __restrict__ f, const float* __restrict__ wr,
    const float* __restrict__ sb, float* __restrict__ out, int Cin, int hw)
{
    int xcd = blockIdx.x & 7, slot = blockIdx.x >> 3;
    int b = xcd >> 1;
    int g = (xcd & 1) * (hw >> 3) + slot;          // pixel-group of 4
    int o = threadIdx.x & 63;
    int p = g * 4 + (threadIdx.x >> 6);
    p = __builtin_amdgcn_readfirstlane(p);
    b = __builtin_amdgcn_readfirstlane(b);
    const float* fb = f + (size_t)b * Cin * hw + p;
    float acc = 0.f;
#pragma unroll 8
    for (int ci = 0; ci < Cin; ++ci) acc = fmaf(fb[(size_t)ci * hw], wr[ci * 64 + o], acc);
    out[((size_t)b * hw + p) * 64 + o] = fmaf(acc, sb[o], sb[64 + o]);
}

// block = 64 px x 4 ch-groups; NHWC y-reads (float4) and NHWC x-write. XCD-affinity swizzle.
__global__ __launch_bounds__(256) void fuse_kernel(const float* __restrict__ f0, float* __restrict__ ws)
{
    int tid = threadIdx.x;
    int blk = blockIdx.x;
    int xcd = blk & 7, slot = blk >> 3;
    int b = xcd >> 1;
    int t = (xcd & 1) * 200 + slot;
    int p0 = t * 64;
    int lane = tid & 63, cb = tid >> 6;
    int p = p0 + lane;
    int h = p / W_, w = p % W_;
    const float* wr0 = ws + WR0_OFF + cb * 16;
    const float* sb  = ws + SB_OFF;  // bn0

    float acc[16];
#pragma unroll
    for (int i = 0; i < 16; i++) acc[i] = 0.f;

    const float* f0b = f0 + (size_t)b * 64 * HW_ + p;
    for (int ci = 0; ci < 64; ++ci) {
        float fv = f0b[(size_t)ci * HW_];
        const float* wrow = wr0 + ci * 64;
#pragma unroll
        for (int i = 0; i < 16; i++) acc[i] = fmaf(fv, wrow[i], acc[i]);
    }
#pragma unroll
    for (int i = 0; i < 16; i++) {
        int o = cb * 16 + i;
        acc[i] = fmaf(acc[i], sb[o], sb[64 + o]);
    }

    {   // +upsample x2 from 80x80 (align_corners), NHWC
        float fy = h * (79.f / 159.f); int i0 = (int)fy; if (i0 > 78) i0 = 78; float ty = fy - i0;
        float fx = w * (79.f / 159.f); int j0 = (int)fx; if (j0 > 78) j0 = 78; float tx = fx - j0;
        float w00 = (1.f - ty) * (1.f - tx), w01 = (1.f - ty) * tx, w10 = ty * (1.f - tx), w11 = ty * tx;
        const float* y = ws + Y1_OFF + ((size_t)b * 6400 + (size_t)(i0 * 80 + j0)) * 64 + cb * 16;
#pragma unroll
        for (int c4 = 0; c4 < 4; c4++) {
            f32x4 a00 = *(const f32x4*)(y + c4 * 4);
            f32x4 a01 = *(const f32x4*)(y + 64 + c4 * 4);
            f32x4 a10 = *(const f32x4*)(y + 80 * 64 + c4 * 4);
            f32x4 a11 = *(const f32x4*)(y + 81 * 64 + c4 * 4);
#pragma unroll
            for (int j = 0; j < 4; j++)
                acc[c4 * 4 + j] += a00[j] * w00 + a01[j] * w01 + a10[j] * w10 + a11[j] * w11;
        }
    }
    {   // +upsample x4 from 40x40
        float fy = h * (39.f / 159.f); int i0 = (int)fy; if (i0 > 38) i0 = 38; float ty = fy - i0;
        float fx = w * (39.f / 159.f); int j0 = (int)fx; if (j0 > 38) j0 = 38; float tx = fx - j0;
        float w00 = (1.f - ty) * (1.f - tx), w01 = (1.f - ty) * tx, w10 = ty * (1.f - tx), w11 = ty * tx;
        const float* y = ws + Y2_OFF + ((size_t)b * 1600 + (size_t)(i0 * 40 + j0)) * 64 + cb * 16;
#pragma unroll
        for (int c4 = 0; c4 < 4; c4++) {
            f32x4 a00 = *(const f32x4*)(y + c4 * 4);
            f32x4 a01 = *(const f32x4*)(y + 64 + c4 * 4);
            f32x4 a10 = *(const f32x4*)(y + 40 * 64 + c4 * 4);
            f32x4 a11 = *(const f32x4*)(y + 41 * 64 + c4 * 4);
#pragma unroll
            for (int j = 0; j < 4; j++)
                acc[c4 * 4 + j] += a00[j] * w00 + a01[j] * w01 + a10[j] * w10 + a11[j] * w11;
        }
    }
    {   // +upsample x8 from 20x20
        float fy = h * (19.f / 159.f); int i0 = (int)fy; if (i0 > 18) i0 = 18; float ty = fy - i0;
        float fx = w * (19.f / 159.f); int j0 = (int)fx; if (j0 > 18) j0 = 18; float tx = fx - j0;
        float w00 = (1.f - ty) * (1.f - tx), w01 = (1.f - ty) * tx, w10 = ty * (1.f - tx), w11 = ty * tx;
        const float* y = ws + Y3_OFF + ((size_t)b * 400 + (size_t)(i0 * 20 + j0)) * 64 + cb * 16;
#pragma unroll
        for (int c4 = 0; c4 < 4; c4++) {
            f32x4 a00 = *(const f32x4*)(y + c4 * 4);
            f32x4 a01 = *(const f32x4*)(y + 64 + c4 * 4);
            f32x4 a10 = *(const f32x4*)(y + 20 * 64 + c4 * 4);
            f32x4 a11 = *(const f32x4*)(y + 21 * 64 + c4 * 4);
#pragma unroll
            for (int j = 0; j < 4; j++)
                acc[c4 * 4 + j] += a00[j] * w00 + a01[j] * w01 + a10[j] * w10 + a11[j] * w11;
        }
    }

    float* x = ws + X_OFF + ((size_t)b * HW_ + p) * 64 + cb * 16;
#pragma unroll
    for (int i = 0; i < 16; i++) x[i] = fmaxf(acc[i], 0.f);
}

// offconv as MFMA GEMM: M=64 px, K=9*64, N=27(pad32). 2 taps per barrier window,
// B fragments direct from global (read-only, prep-written). Writes om[b][p][27].
__global__ __launch_bounds__(256) void offconv_mfma_kernel(const float* __restrict__ off_b, float* __restrict__ ws)
{
    __shared__ __align__(16) unsigned short A_lds[2][64 * 72];   // tap-pair; reused as C float[64][28]

    int tid = threadIdx.x;
    int blk = blockIdx.x;
    int xcd = blk & 7, slot = blk >> 3;
    int b = xcd >> 1;
    int t = (xcd & 1) * 200 + slot;
    int p0 = t * 64;
    int lane = tid & 63, cb = tid >> 6;
    int px = lane;
    int p = p0 + px;
    int h = p / W_, w = p % W_;
    int mrow = lane & 15, quad = lane >> 4;

    const unsigned short* rwb = (const unsigned short*)(ws + RWB_OFF);
    const float* xb = ws + X_OFF + (size_t)b * HW_ * 64;

    f32x4 acc2[2];
    acc2[0] = (f32x4){0.f, 0.f, 0.f, 0.f};
    acc2[1] = (f32x4){0.f, 0.f, 0.f, 0.f};

    for (int kk = 0; kk < 9; kk += 2) {
        __syncthreads();  // prev window's A reads done
#pragma unroll
        for (int u = 0; u < 2; u++) {
            int tap = kk + u;
            if (tap > 8) break;
            int yy = h + tap / 3 - 1;
            int xx = w + tap % 3 - 1;
            bool valid = (yy >= 0) && (yy < H_) && (xx >= 0) && (xx < W_);
            bf16x8 pk0 = {0, 0, 0, 0, 0, 0, 0, 0}, pk1 = pk0;
            if (valid) {
                const float* src = xb + ((size_t)(yy * W_ + xx)) * 64 + cb * 16;
                f32x4 g0 = *(const f32x4*)(src);
                f32x4 g1 = *(const f32x4*)(src + 4);
                f32x4 g2 = *(const f32x4*)(src + 8);
                f32x4 g3 = *(const f32x4*)(src + 12);
#pragma unroll
                for (int j = 0; j < 4; j++) {
                    pk0[j]     = (short)f2bf(g0[j]);
                    pk0[j + 4] = (short)f2bf(g1[j]);
                    pk1[j]     = (short)f2bf(g2[j]);
                    pk1[j + 4] = (short)f2bf(g3[j]);
                }
            }
            unsigned short* dst = A_lds[u] + px * 72 + cb * 16;
            *(bf16x8*)(dst)     = pk0;
            *(bf16x8*)(dst + 8) = pk1;
        }
        __syncthreads();  // A visible

#pragma unroll
        for (int u = 0; u < 2; u++) {
            int tap = kk + u;
            if (tap > 8) break;
            const unsigned short* Ab = A_lds[u] + (cb * 16 + mrow) * 72;
#pragma unroll
            for (int ks = 0; ks < 2; ks++) {
                bf16x8 af = *(const bf16x8*)(Ab + ks * 32 + quad * 8);
#pragma unroll
                for (int nt = 0; nt < 2; nt++) {
                    bf16x8 bf_ = *(const bf16x8*)(rwb + tap * 2048 + (nt * 16 + mrow) * 64 + ks * 32 + quad * 8);
                    acc2[nt] = __builtin_amdgcn_mfma_f32_16x16x32_bf16(af, bf_, acc2[nt], 0, 0, 0);
                }
            }
        }
    }

    __syncthreads();
    float* Cl = (float*)A_lds;  // [64 px][28]
#pragma unroll
    for (int nt = 0; nt < 2; nt++) {
        int o = nt * 16 + mrow;
        if (o < 27) {
            int pr = cb * 16 + quad * 4;
#pragma unroll
            for (int r = 0; r < 4; r++) Cl[(pr + r) * 28 + o] = acc2[nt][r];
        }
    }
    __syncthreads();

    for (int k = cb; k < 9; k += 4) {
        float ady = Cl[px * 28 + 2 * k]     + off_b[2 * k];
        float adx = Cl[px * 28 + 2 * k + 1] + off_b[2 * k + 1];
        float am  = Cl[px * 28 + 18 + k]    + off_b[18 + k];
        float sy = (float)(h + k / 3 - 1) + ady;
        float sx = (float)(w + k % 3 - 1) + adx;
        float mk = 1.f / (1.f + __expf(-am));
        float* om = ws + OM_OFF + ((size_t)b * HW_ + p) * 27 + 3 * k;
        om[0] = sy; om[1] = sx; om[2] = mk;
    }
}

// dcn: MFMA GEMM; 2 taps per barrier window, B fragments direct from global, om staged in LDS.
__global__ __launch_bounds__(256) void dcn_mfma_kernel(const float* __restrict__ ws, float* __restrict__ out)
{
    __shared__ __align__(16) unsigned short A_lds[2][64 * 72];  // tap-pair; reused as C float[64][65]
    __shared__ float OMs[64 * 27];

    int tid = threadIdx.x;
    int blk = blockIdx.x;
    int xcd = blk & 7, slot = blk >> 3;
    int b = xcd >> 1;
    int t = (xcd & 1) * 200 + slot;
    int p0 = t * 64;
    int lane = tid & 63, cb = tid >> 6;
    int px = lane;
    int mrow = lane & 15, quad = lane >> 4;

    const float* xb  = ws + X_OFF + (size_t)b * HW_ * 64;
    const unsigned short* wtb = (const unsigned short*)(ws + WTB_OFF);
    const float* sb  = ws + SB_OFF + 4 * 128;  // final bn

    // stage om for this block's 64 px
    {
        const float* omg = ws + OM_OFF + ((size_t)b * HW_ + p0) * 27;
        for (int i = tid; i < 64 * 27; i += 256) OMs[i] = omg[i];
    }

    f32x4 acc[4];
#pragma unroll
    for (int nt = 0; nt < 4; nt++) acc[nt] = (f32x4){0.f, 0.f, 0.f, 0.f};

    for (int kk = 0; kk < 9; kk += 2) {
        __syncthreads();  // prev window's A reads done; first iter: OMs staged
#pragma unroll
        for (int u = 0; u < 2; u++) {
            int k = kk + u;
            if (k > 8) break;
            float sy = OMs[px * 27 + 3 * k];
            float sx = OMs[px * 27 + 3 * k + 1];
            float mk = OMs[px * 27 + 3 * k + 2];
            float y0f = floorf(sy), x0f = floorf(sx);
            int y0 = (int)y0f, x0 = (int)x0f;
            float ty = sy - y0f, tx = sx - x0f;

            float val[16];
#pragma unroll
            for (int i = 0; i < 16; i++) val[i] = 0.f;
#pragma unroll
            for (int cr = 0; cr < 4; cr++) {
                int dy = cr >> 1, dx = cr & 1;
                int yy = y0 + dy, xx = x0 + dx;
                float wy = dy ? ty : 1.f - ty;
                float wx = dx ? tx : 1.f - tx;
                bool vld = (yy >= 0) && (yy < H_) && (xx >= 0) && (xx < W_);
                int yc = min(max(yy, 0), H_ - 1);
                int xc = min(max(xx, 0), W_ - 1);
                float wv = vld ? wy * wx * mk : 0.f;
                const float* src = xb + ((size_t)(yc * W_ + xc)) * 64 + cb * 16;
#pragma unroll
                for (int c4 = 0; c4 < 4; c4++) {
                    f32x4 g = *(const f32x4*)(src + c4 * 4);
#pragma unroll
                    for (int jj = 0; jj < 4; jj++) val[c4 * 4 + jj] = fmaf(g[jj], wv, val[c4 * 4 + jj]);
                }
            }
            bf16x8 pk0, pk1;
#pragma unroll
            for (int jj = 0; jj < 8; jj++) {
                pk0[jj] = (short)f2bf(val[jj]);
                pk1[jj] = (short)f2bf(val[8 + jj]);
            }
            unsigned short* dst = A_lds[u] + px * 72 + cb * 16;
            *(bf16x8*)(dst)     = pk0;
            *(bf16x8*)(dst + 8) = pk1;
        }
        __syncthreads();  // A visible

#pragma unroll
        for (int u = 0; u < 2; u++) {
            int k = kk + u;
            if (k > 8) break;
            const unsigned short* Ab = A_lds[u] + (cb * 16 + mrow) * 72;
#pragma unroll
            for (int ks = 0; ks < 2; ks++) {
                bf16x8 af = *(const bf16x8*)(Ab + ks * 32 + quad * 8);
#pragma unroll
                for (int nt = 0; nt < 4; nt++) {
                    bf16x8 bf_ = *(const bf16x8*)(wtb + k * 4608 + (nt * 16 + mrow) * 72 + ks * 32 + quad * 8);
                    acc[nt] = __builtin_amdgcn_mfma_f32_16x16x32_bf16(af, bf_, acc[nt], 0, 0, 0);
                }
            }
        }
    }

    // epilogue: C frag (col o = mrow(+nt*16), row px = quad*4+r (+cb*16)) -> LDS [o][px pad65] -> NCHW store
    __syncthreads();
    float* C_lds = (float*)A_lds;  // 64*65*4 = 16,640 B <= 18,432 B
#pragma unroll
    for (int nt = 0; nt < 4; nt++) {
        int o = nt * 16 + mrow;
        int pxb = cb * 16 + quad * 4;
#pragma unroll
        for (int r = 0; r < 4; r++) C_lds[o * 65 + pxb + r] = acc[nt][r];
    }
    __syncthreads();
#pragma unroll
    for (int i = 0; i < 16; i++) {
        int o = cb * 16 + i;
        float v = C_lds[o * 65 + lane];
        v = fmaf(v, sb[o], sb[64 + o]);
        out[((size_t)b * 64 + o) * HW_ + p0 + lane] = fmaxf(v, 0.f);
    }
}

extern "C" void kernel_launch(void* const* d_in, const int* in_sizes, int n_in,
                              void* d_out, int out_size, void* d_ws, size_t ws_size,
                              hipStream_t stream)
{
    const float* f0 = (const float*)d_in[0];
    const float* f1 = (const float*)d_in[1];
    const float* f2 = (const float*)d_in[2];
    const float* f3 = (const float*)d_in[3];
    const float* w0 = (const float*)d_in[4];
    const float* g0 = (const float*)d_in[5];
    const float* b0 = (const float*)d_in[6];
    const float* m0 = (const float*)d_in[7];
    const float* v0 = (const float*)d_in[8];
    const float* w1 = (const float*)d_in[9];
    const float* g1 = (const float*)d_in[10];
    const float* b1 = (const float*)d_in[11];
    const float* m1 = (const float*)d_in[12];
    const float* v1 = (const float*)d_in[13];
    const float* w2 = (const float*)d_in[14];
    const float* g2 = (const float*)d_in[15];
    const float* b2 = (const float*)d_in[16];
    const float* m2 = (const float*)d_in[17];
    const float* v2 = (const float*)d_in[18];
    const float* w3 = (const float*)d_in[19];
    const float* g3 = (const float*)d_in[20];
    const float* b3 = (const float*)d_in[21];
    const float* m3 = (const float*)d_in[22];
    const float* v3 = (const float*)d_in[23];
    const float* off_w = (const float*)d_in[24];
    const float* off_b = (const float*)d_in[25];
    const float* dcn_w = (const float*)d_in[26];
    const float* gf = (const float*)d_in[27];
    const float* bf = (const float*)d_in[28];
    const float* mf = (const float*)d_in[29];
    const float* vf = (const float*)d_in[30];

    float* ws  = (float*)d_ws;
    float* out = (float*)d_out;

    // prep: 320 + 4096 + 41472 + 18432 + 8192 + 16384 + 32768 = 121,664 -> 476 blocks
    prep_kernel<<<dim3(476), dim3(256), 0, stream>>>(
        g0, b0, m0, v0, g1, b1, m1, v1, g2, b2, m2, v2, g3, b3, m3, v3,
        gf, bf, mf, vf, w0, w1, w2, w3, dcn_w, off_w, ws);

    // 1x1 convs + bn -> NHWC y (coalesced [ci][o] weights; XCD-affine block mapping)
    conv1x1_bn_kernel<<<dim3(6400), dim3(256), 0, stream>>>(f1, ws + WR1_OFF, ws + SB_OFF + 128, ws + Y1_OFF, 128, 6400);
    conv1x1_bn_kernel<<<dim3(1600), dim3(256), 0, stream>>>(f2, ws + WR2_OFF, ws + SB_OFF + 256, ws + Y2_OFF, 256, 1600);
    conv1x1_bn_kernel<<<dim3(400),  dim3(256), 0, stream>>>(f3, ws + WR3_OFF, ws + SB_OFF + 384, ws + Y3_OFF, 512, 400);

    // fuse -> x (NHWC, XCD-affine)
    fuse_kernel<<<dim3(1600), dim3(256), 0, stream>>>(f0, ws);

    // offset conv via MFMA -> om [b][p][27] (XCD-affine, 2 taps/window, B from global)
    offconv_mfma_kernel<<<dim3(1600), dim3(256), 0, stream>>>(off_b, ws);

    // deformable conv via MFMA + final bn + relu (XCD-affine, 2 taps/window, B from global)
    dcn_mfma_kernel<<<dim3(1600), dim3(256), 0, stream>>>(ws, out);
}

// Round 10
// 426.329 us; speedup vs baseline: 1.8363x; 1.1641x over previous
//
#include <hip/hip_runtime.h>
#include <math.h>

#define EPSB 1e-5f

constexpr int B_ = 4;
constexpr int C_ = 64;
constexpr int H_ = 160;
constexpr int W_ = 160;
constexpr int HW_ = H_ * W_;

// workspace layout (float offsets) — total 11,503,488 floats = 46.01 MB
constexpr size_t X_OFF   = 0;                                    // x NHWC: [b][p][64]
constexpr size_t Y1_OFF  = X_OFF  + (size_t)B_ * HW_ * 64;       // y1 NHWC @80x80
constexpr size_t Y2_OFF  = Y1_OFF + (size_t)B_ * 6400 * 64;      // y2 NHWC @40x40
constexpr size_t Y3_OFF  = Y2_OFF + (size_t)B_ * 1600 * 64;      // y3 NHWC @20x20
constexpr size_t OM_OFF  = Y3_OFF + (size_t)B_ * 400 * 64;       // om: [b][p][27] (sy,sx,mk)*9
constexpr size_t WR0_OFF = OM_OFF + (size_t)B_ * HW_ * 27;       // w0 fp32 [ci][o]: 4096
constexpr size_t WTB_OFF = WR0_OFF + 4096;                       // dcn_w bf16 [k][o][c pad72]: 41472 ush
constexpr size_t RWB_OFF = WTB_OFF + (9 * 64 * 72) / 2;          // off_w bf16 [tap][o pad32][ci]: 18432 ush
constexpr size_t SB_OFF  = RWB_OFF + (9 * 32 * 64) / 2;          // 5 BNs x (scale[64], bias[64])
// transposed conv1x1 weights OVERLAID at head of X region (die before fuse writes x).
constexpr size_t WR1_OFF = X_OFF + 0;       // w1 fp32 [ci][o]
constexpr size_t WR2_OFF = X_OFF + 8192;    // w2 fp32 [ci][o]
constexpr size_t WR3_OFF = X_OFF + 24576;   // w3 fp32 [ci][o]

typedef short bf16x8 __attribute__((ext_vector_type(8)));
typedef float f32x4 __attribute__((ext_vector_type(4)));

static __device__ __forceinline__ unsigned short f2bf(float f) {
    unsigned int u = __float_as_uint(f);
    u += 0x7fff + ((u >> 16) & 1);   // RNE
    return (unsigned short)(u >> 16);
}

__global__ __launch_bounds__(256) void prep_kernel(
    const float* __restrict__ g0, const float* __restrict__ b0, const float* __restrict__ m0, const float* __restrict__ v0,
    const float* __restrict__ g1, const float* __restrict__ b1, const float* __restrict__ m1, const float* __restrict__ v1,
    const float* __restrict__ g2, const float* __restrict__ b2, const float* __restrict__ m2, const float* __restrict__ v2,
    const float* __restrict__ g3, const float* __restrict__ b3, const float* __restrict__ m3, const float* __restrict__ v3,
    const float* __restrict__ gf, const float* __restrict__ bf, const float* __restrict__ mf, const float* __restrict__ vf,
    const float* __restrict__ w0, const float* __restrict__ w1, const float* __restrict__ w2, const float* __restrict__ w3,
    const float* __restrict__ dcn_w, const float* __restrict__ off_w,
    float* __restrict__ ws)
{
    int tid = blockIdx.x * 256 + threadIdx.x;
    if (tid < 320) {  // BN scale/bias fold
        int j = tid >> 6, c = tid & 63;
        const float *g, *b, *m, *v;
        switch (j) {
            case 0: g = g0; b = b0; m = m0; v = v0; break;
            case 1: g = g1; b = b1; m = m1; v = v1; break;
            case 2: g = g2; b = b2; m = m2; v = v2; break;
            case 3: g = g3; b = b3; m = m3; v = v3; break;
            default: g = gf; b = bf; m = mf; v = vf; break;
        }
        float sc = g[c] * rsqrtf(v[c] + EPSB);
        ws[SB_OFF + j * 128 + c]      = sc;
        ws[SB_OFF + j * 128 + 64 + c] = b[c] - m[c] * sc;
        return;
    }
    int t = tid - 320;
    if (t < 4096) {  // wr0[ci*64+o] = w0[o*64+ci]
        int ci = t >> 6, o = t & 63;
        ws[WR0_OFF + t] = w0[o * 64 + ci];
        return;
    }
    t -= 4096;
    if (t < 9 * 64 * 72) {  // wtb[k][o][c pad72] bf16 = dcn_w[o][c][k]
        int k = t / 4608, r = t % 4608, o = r / 72, c = r % 72;
        float v = (c < 64) ? dcn_w[o * 576 + c * 9 + k] : 0.f;
        ((unsigned short*)(ws + WTB_OFF))[t] = f2bf(v);
        return;
    }
    t -= 9 * 64 * 72;
    if (t < 9 * 32 * 64) {  // rwb[tap][o pad32][ci] bf16 = off_w[o][ci][tap]
        int tap = t >> 11, r = t & 2047, o = r >> 6, ci = r & 63;
        float v = (o < 27) ? off_w[o * 576 + ci * 9 + tap] : 0.f;
        ((unsigned short*)(ws + RWB_OFF))[t] = f2bf(v);
        return;
    }
    t -= 9 * 32 * 64;
    if (t < 8192) {  // wr1[ci*64+o] = w1[o*128+ci]
        int ci = t >> 6, o = t & 63;
        ws[WR1_OFF + t] = w1[o * 128 + ci];
        return;
    }
    t -= 8192;
    if (t < 16384) {  // wr2
        int ci = t >> 6, o = t & 63;
        ws[WR2_OFF + t] = w2[o * 256 + ci];
        return;
    }
    t -= 16384;
    if (t < 32768) {  // wr3
        int ci = t >> 6, o = t & 63;
        ws[WR3_OFF + t] = w3[o * 512 + ci];
        return;
    }
}

// wave = one (b,p); lanes = 64 output channels; weights [ci][o] -> coalesced. NHWC out. XCD-affine.
__global__ __launch_bounds__(256) void conv1x1_bn_kernel(
    const float* __restrict__ f, const float* __restrict__ wr,
    const float* __restrict__ sb, float* __restrict__ out, int Cin, int hw)
{
    int xcd = blockIdx.x & 7, slot = blockIdx.x >> 3;
    int b = xcd >> 1;
    int g = (xcd & 1) * (hw >> 3) + slot;
    int o = threadIdx.x & 63;
    int p = g * 4 + (threadIdx.x >> 6);
    p = __builtin_amdgcn_readfirstlane(p);
    b = __builtin_amdgcn_readfirstlane(b);
    const float* fb = f + (size_t)b * Cin * hw + p;
    float acc = 0.f;
#pragma unroll 8
    for (int ci = 0; ci < Cin; ++ci) acc = fmaf(fb[(size_t)ci * hw], wr[ci * 64 + o], acc);
    out[((size_t)b * hw + p) * 64 + o] = fmaf(acc, sb[o], sb[64 + o]);
}

// block = 64 px x 4 ch-groups; NHWC y-reads (float4) and NHWC x-write. XCD-affine.
__global__ __launch_bounds__(256) void fuse_kernel(const float* __restrict__ f0, float* __restrict__ ws)
{
    int tid = threadIdx.x;
    int blk = blockIdx.x;
    int xcd = blk & 7, slot = blk >> 3;
    int b = xcd >> 1;
    int t = (xcd & 1) * 200 + slot;
    int p0 = t * 64;
    int lane = tid & 63, cb = tid >> 6;
    int p = p0 + lane;
    int h = p / W_, w = p % W_;
    const float* wr0 = ws + WR0_OFF + cb * 16;
    const float* sb  = ws + SB_OFF;  // bn0

    float acc[16];
#pragma unroll
    for (int i = 0; i < 16; i++) acc[i] = 0.f;

    const float* f0b = f0 + (size_t)b * 64 * HW_ + p;
    for (int ci = 0; ci < 64; ++ci) {
        float fv = f0b[(size_t)ci * HW_];
        const float* wrow = wr0 + ci * 64;
#pragma unroll
        for (int i = 0; i < 16; i++) acc[i] = fmaf(fv, wrow[i], acc[i]);
    }
#pragma unroll
    for (int i = 0; i < 16; i++) {
        int o = cb * 16 + i;
        acc[i] = fmaf(acc[i], sb[o], sb[64 + o]);
    }

    {   // +upsample x2 from 80x80 (align_corners), NHWC
        float fy = h * (79.f / 159.f); int i0 = (int)fy; if (i0 > 78) i0 = 78; float ty = fy - i0;
        float fx = w * (79.f / 159.f); int j0 = (int)fx; if (j0 > 78) j0 = 78; float tx = fx - j0;
        float w00 = (1.f - ty) * (1.f - tx), w01 = (1.f - ty) * tx, w10 = ty * (1.f - tx), w11 = ty * tx;
        const float* y = ws + Y1_OFF + ((size_t)b * 6400 + (size_t)(i0 * 80 + j0)) * 64 + cb * 16;
#pragma unroll
        for (int c4 = 0; c4 < 4; c4++) {
            f32x4 a00 = *(const f32x4*)(y + c4 * 4);
            f32x4 a01 = *(const f32x4*)(y + 64 + c4 * 4);
            f32x4 a10 = *(const f32x4*)(y + 80 * 64 + c4 * 4);
            f32x4 a11 = *(const f32x4*)(y + 81 * 64 + c4 * 4);
#pragma unroll
            for (int j = 0; j < 4; j++)
                acc[c4 * 4 + j] += a00[j] * w00 + a01[j] * w01 + a10[j] * w10 + a11[j] * w11;
        }
    }
    {   // +upsample x4 from 40x40
        float fy = h * (39.f / 159.f); int i0 = (int)fy; if (i0 > 38) i0 = 38; float ty = fy - i0;
        float fx = w * (39.f / 159.f); int j0 = (int)fx; if (j0 > 38) j0 = 38; float tx = fx - j0;
        float w00 = (1.f - ty) * (1.f - tx), w01 = (1.f - ty) * tx, w10 = ty * (1.f - tx), w11 = ty * tx;
        const float* y = ws + Y2_OFF + ((size_t)b * 1600 + (size_t)(i0 * 40 + j0)) * 64 + cb * 16;
#pragma unroll
        for (int c4 = 0; c4 < 4; c4++) {
            f32x4 a00 = *(const f32x4*)(y + c4 * 4);
            f32x4 a01 = *(const f32x4*)(y + 64 + c4 * 4);
            f32x4 a10 = *(const f32x4*)(y + 40 * 64 + c4 * 4);
            f32x4 a11 = *(const f32x4*)(y + 41 * 64 + c4 * 4);
#pragma unroll
            for (int j = 0; j < 4; j++)
                acc[c4 * 4 + j] += a00[j] * w00 + a01[j] * w01 + a10[j] * w10 + a11[j] * w11;
        }
    }
    {   // +upsample x8 from 20x20
        float fy = h * (19.f / 159.f); int i0 = (int)fy; if (i0 > 18) i0 = 18; float ty = fy - i0;
        float fx = w * (19.f / 159.f); int j0 = (int)fx; if (j0 > 18) j0 = 18; float tx = fx - j0;
        float w00 = (1.f - ty) * (1.f - tx), w01 = (1.f - ty) * tx, w10 = ty * (1.f - tx), w11 = ty * tx;
        const float* y = ws + Y3_OFF + ((size_t)b * 400 + (size_t)(i0 * 20 + j0)) * 64 + cb * 16;
#pragma unroll
        for (int c4 = 0; c4 < 4; c4++) {
            f32x4 a00 = *(const f32x4*)(y + c4 * 4);
            f32x4 a01 = *(const f32x4*)(y + 64 + c4 * 4);
            f32x4 a10 = *(const f32x4*)(y + 20 * 64 + c4 * 4);
            f32x4 a11 = *(const f32x4*)(y + 21 * 64 + c4 * 4);
#pragma unroll
            for (int j = 0; j < 4; j++)
                acc[c4 * 4 + j] += a00[j] * w00 + a01[j] * w01 + a10[j] * w10 + a11[j] * w11;
        }
    }

    float* x = ws + X_OFF + ((size_t)b * HW_ + p) * 64 + cb * 16;
#pragma unroll
    for (int i = 0; i < 16; i++) x[i] = fmaxf(acc[i], 0.f);
}

// offconv as MFMA GEMM (R7 VERBATIM): 2 taps per barrier window, per-pixel gather,
// B fragments direct from global. Writes om[b][p][27].
__global__ __launch_bounds__(256) void offconv_mfma_kernel(const float* __restrict__ off_b, float* __restrict__ ws)
{
    __shared__ __align__(16) unsigned short A_lds[2][64 * 72];   // tap-pair; reused as C float[64][28]

    int tid = threadIdx.x;
    int blk = blockIdx.x;
    int xcd = blk & 7, slot = blk >> 3;
    int b = xcd >> 1;
    int t = (xcd & 1) * 200 + slot;
    int p0 = t * 64;
    int lane = tid & 63, cb = tid >> 6;
    int px = lane;
    int p = p0 + px;
    int h = p / W_, w = p % W_;
    int mrow = lane & 15, quad = lane >> 4;

    const unsigned short* rwb = (const unsigned short*)(ws + RWB_OFF);
    const float* xb = ws + X_OFF + (size_t)b * HW_ * 64;

    f32x4 acc2[2];
    acc2[0] = (f32x4){0.f, 0.f, 0.f, 0.f};
    acc2[1] = (f32x4){0.f, 0.f, 0.f, 0.f};

    for (int kk = 0; kk < 9; kk += 2) {
        __syncthreads();  // prev window's A reads done
#pragma unroll
        for (int u = 0; u < 2; u++) {
            int tap = kk + u;
            if (tap > 8) break;
            int yy = h + tap / 3 - 1;
            int xx = w + tap % 3 - 1;
            bool valid = (yy >= 0) && (yy < H_) && (xx >= 0) && (xx < W_);
            bf16x8 pk0 = {0, 0, 0, 0, 0, 0, 0, 0}, pk1 = pk0;
            if (valid) {
                const float* src = xb + ((size_t)(yy * W_ + xx)) * 64 + cb * 16;
                f32x4 g0 = *(const f32x4*)(src);
                f32x4 g1 = *(const f32x4*)(src + 4);
                f32x4 g2 = *(const f32x4*)(src + 8);
                f32x4 g3 = *(const f32x4*)(src + 12);
#pragma unroll
                for (int j = 0; j < 4; j++) {
                    pk0[j]     = (short)f2bf(g0[j]);
                    pk0[j + 4] = (short)f2bf(g1[j]);
                    pk1[j]     = (short)f2bf(g2[j]);
                    pk1[j + 4] = (short)f2bf(g3[j]);
                }
            }
            unsigned short* dst = A_lds[u] + px * 72 + cb * 16;
            *(bf16x8*)(dst)     = pk0;
            *(bf16x8*)(dst + 8) = pk1;
        }
        __syncthreads();  // A visible

#pragma unroll
        for (int u = 0; u < 2; u++) {
            int tap = kk + u;
            if (tap > 8) break;
            const unsigned short* Ab = A_lds[u] + (cb * 16 + mrow) * 72;
#pragma unroll
            for (int ks = 0; ks < 2; ks++) {
                bf16x8 af = *(const bf16x8*)(Ab + ks * 32 + quad * 8);
#pragma unroll
                for (int nt = 0; nt < 2; nt++) {
                    bf16x8 bf_ = *(const bf16x8*)(rwb + tap * 2048 + (nt * 16 + mrow) * 64 + ks * 32 + quad * 8);
                    acc2[nt] = __builtin_amdgcn_mfma_f32_16x16x32_bf16(af, bf_, acc2[nt], 0, 0, 0);
                }
            }
        }
    }

    __syncthreads();
    float* Cl = (float*)A_lds;  // [64 px][28]
#pragma unroll
    for (int nt = 0; nt < 2; nt++) {
        int o = nt * 16 + mrow;
        if (o < 27) {
            int pr = cb * 16 + quad * 4;
#pragma unroll
            for (int r = 0; r < 4; r++) Cl[(pr + r) * 28 + o] = acc2[nt][r];
        }
    }
    __syncthreads();

    for (int k = cb; k < 9; k += 4) {
        float ady = Cl[px * 28 + 2 * k]     + off_b[2 * k];
        float adx = Cl[px * 28 + 2 * k + 1] + off_b[2 * k + 1];
        float am  = Cl[px * 28 + 18 + k]    + off_b[18 + k];
        float sy = (float)(h + k / 3 - 1) + ady;
        float sx = (float)(w + k % 3 - 1) + adx;
        float mk = 1.f / (1.f + __expf(-am));
        float* om = ws + OM_OFF + ((size_t)b * HW_ + p) * 27 + 3 * k;
        om[0] = sy; om[1] = sx; om[2] = mk;
    }
}

// dcn MFMA GEMM — BISECT R10: chunk-major coalesced gather (lane = 4px x 16chunk,
// 16 lines/instr), NO IW table: OMs staged in LDS (R7-proven), (idx,wv) recomputed
// inline per lane. Per-channel math bit-identical to R7.
__global__ __launch_bounds__(256) void dcn_mfma_kernel(const float* __restrict__ ws, float* __restrict__ out)
{
    __shared__ __align__(16) unsigned short A_lds[2][64 * 72];  // tap-pair; reused as C float[64][65]
    __shared__ float OMs[64 * 27];

    int tid = threadIdx.x;
    int blk = blockIdx.x;
    int xcd = blk & 7, slot = blk >> 3;
    int b = xcd >> 1;
    int t = (xcd & 1) * 200 + slot;
    int p0 = t * 64;
    int lane = tid & 63, cb = tid >> 6;
    int mrow = lane & 15, quad = lane >> 4;
    int chunk = lane & 15, pxo = lane >> 4;   // gather mapping

    const float* xb  = ws + X_OFF + (size_t)b * HW_ * 64;
    const unsigned short* wtb = (const unsigned short*)(ws + WTB_OFF);
    const float* sb  = ws + SB_OFF + 4 * 128;  // final bn

    // stage om for this block's 64 px (R7-verbatim)
    {
        const float* omg = ws + OM_OFF + ((size_t)b * HW_ + p0) * 27;
        for (int i = tid; i < 64 * 27; i += 256) OMs[i] = omg[i];
    }

    f32x4 acc[4];
#pragma unroll
    for (int nt = 0; nt < 4; nt++) acc[nt] = (f32x4){0.f, 0.f, 0.f, 0.f};

    for (int kk = 0; kk < 9; kk += 2) {
        __syncthreads();  // prev window's A reads done; first iter: OMs staged
#pragma unroll
        for (int u = 0; u < 2; u++) {
            int k = kk + u;
            if (k > 8) break;
#pragma unroll
            for (int r = 0; r < 4; r++) {
                int gpx = cb * 16 + r * 4 + pxo;   // pixel this lane serves
                float sy = OMs[gpx * 27 + 3 * k];
                float sx = OMs[gpx * 27 + 3 * k + 1];
                float mk = OMs[gpx * 27 + 3 * k + 2];
                float y0f = floorf(sy), x0f = floorf(sx);
                int y0 = (int)y0f, x0 = (int)x0f;
                float ty = sy - y0f, tx = sx - x0f;
                f32x4 v = (f32x4){0.f, 0.f, 0.f, 0.f};
#pragma unroll
                for (int cr = 0; cr < 4; cr++) {
                    int dy = cr >> 1, dx = cr & 1;
                    int yy = y0 + dy, xx = x0 + dx;
                    float wy = dy ? ty : 1.f - ty;
                    float wx = dx ? tx : 1.f - tx;
                    bool vld = (yy >= 0) && (yy < H_) && (xx >= 0) && (xx < W_);
                    int yc = min(max(yy, 0), H_ - 1);
                    int xc = min(max(xx, 0), W_ - 1);
                    float wv = vld ? wy * wx * mk : 0.f;
                    f32x4 g = *(const f32x4*)(xb + (size_t)(yc * W_ + xc) * 64 + chunk * 4);
#pragma unroll
                    for (int j = 0; j < 4; j++) v[j] = fmaf(g[j], wv, v[j]);
                }
                unsigned short pk[4];
#pragma unroll
                for (int j = 0; j < 4; j++) pk[j] = f2bf(v[j]);
                *(unsigned int*)(A_lds[u] + gpx * 72 + chunk * 4)     = ((unsigned int)pk[1] << 16) | pk[0];
                *(unsigned int*)(A_lds[u] + gpx * 72 + chunk * 4 + 2) = ((unsigned int)pk[3] << 16) | pk[2];
            }
        }
        __syncthreads();  // A visible

#pragma unroll
        for (int u = 0; u < 2; u++) {
            int k = kk + u;
            if (k > 8) break;
            const unsigned short* Ab = A_lds[u] + (cb * 16 + mrow) * 72;
#pragma unroll
            for (int ks = 0; ks < 2; ks++) {
                bf16x8 af = *(const bf16x8*)(Ab + ks * 32 + quad * 8);
#pragma unroll
                for (int nt = 0; nt < 4; nt++) {
                    bf16x8 bf_ = *(const bf16x8*)(wtb + k * 4608 + (nt * 16 + mrow) * 72 + ks * 32 + quad * 8);
                    acc[nt] = __builtin_amdgcn_mfma_f32_16x16x32_bf16(af, bf_, acc[nt], 0, 0, 0);
                }
            }
        }
    }

    // epilogue: C frag -> LDS [o][px pad65] -> NCHW store  (R7-verbatim)
    __syncthreads();
    float* C_lds = (float*)A_lds;
#pragma unroll
    for (int nt = 0; nt < 4; nt++) {
        int o = nt * 16 + mrow;
        int pxb = cb * 16 + quad * 4;
#pragma unroll
        for (int r = 0; r < 4; r++) C_lds[o * 65 + pxb + r] = acc[nt][r];
    }
    __syncthreads();
#pragma unroll
    for (int i = 0; i < 16; i++) {
        int o = cb * 16 + i;
        float v = C_lds[o * 65 + lane];
        v = fmaf(v, sb[o], sb[64 + o]);
        out[((size_t)b * 64 + o) * HW_ + p0 + lane] = fmaxf(v, 0.f);
    }
}

extern "C" void kernel_launch(void* const* d_in, const int* in_sizes, int n_in,
                              void* d_out, int out_size, void* d_ws, size_t ws_size,
                              hipStream_t stream)
{
    const float* f0 = (const float*)d_in[0];
    const float* f1 = (const float*)d_in[1];
    const float* f2 = (const float*)d_in[2];
    const float* f3 = (const float*)d_in[3];
    const float* w0 = (const float*)d_in[4];
    const float* g0 = (const float*)d_in[5];
    const float* b0 = (const float*)d_in[6];
    const float* m0 = (const float*)d_in[7];
    const float* v0 = (const float*)d_in[8];
    const float* w1 = (const float*)d_in[9];
    const float* g1 = (const float*)d_in[10];
    const float* b1 = (const float*)d_in[11];
    const float* m1 = (const float*)d_in[12];
    const float* v1 = (const float*)d_in[13];
    const float* w2 = (const float*)d_in[14];
    const float* g2 = (const float*)d_in[15];
    const float* b2 = (const float*)d_in[16];
    const float* m2 = (const float*)d_in[17];
    const float* v2 = (const float*)d_in[18];
    const float* w3 = (const float*)d_in[19];
    const float* g3 = (const float*)d_in[20];
    const float* b3 = (const float*)d_in[21];
    const float* m3 = (const float*)d_in[22];
    const float* v3 = (const float*)d_in[23];
    const float* off_w = (const float*)d_in[24];
    const float* off_b = (const float*)d_in[25];
    const float* dcn_w = (const float*)d_in[26];
    const float* gf = (const float*)d_in[27];
    const float* bf = (const float*)d_in[28];
    const float* mf = (const float*)d_in[29];
    const float* vf = (const float*)d_in[30];

    float* ws  = (float*)d_ws;
    float* out = (float*)d_out;

    prep_kernel<<<dim3(476), dim3(256), 0, stream>>>(
        g0, b0, m0, v0, g1, b1, m1, v1, g2, b2, m2, v2, g3, b3, m3, v3,
        gf, bf, mf, vf, w0, w1, w2, w3, dcn_w, off_w, ws);

    conv1x1_bn_kernel<<<dim3(6400), dim3(256), 0, stream>>>(f1, ws + WR1_OFF, ws + SB_OFF + 128, ws + Y1_OFF, 128, 6400);
    conv1x1_bn_kernel<<<dim3(1600), dim3(256), 0, stream>>>(f2, ws + WR2_OFF, ws + SB_OFF + 256, ws + Y2_OFF, 256, 1600);
    conv1x1_bn_kernel<<<dim3(400),  dim3(256), 0, stream>>>(f3, ws + WR3_OFF, ws + SB_OFF + 384, ws + Y3_OFF, 512, 400);

    fuse_kernel<<<dim3(1600), dim3(256), 0, stream>>>(f0, ws);

    offconv_mfma_kernel<<<dim3(1600), dim3(256), 0, stream>>>(off_b, ws);

    dcn_mfma_kernel<<<dim3(1600), dim3(256), 0, stream>>>(ws, out);
}

// Round 11
// 411.148 us; speedup vs baseline: 1.9041x; 1.0369x over previous
//
#include <hip/hip_runtime.h>
#include <math.h>

#define EPSB 1e-5f

constexpr int B_ = 4;
constexpr int C_ = 64;
constexpr int H_ = 160;
constexpr int W_ = 160;
constexpr int HW_ = H_ * W_;

// workspace layout (float offsets) — total 11,503,488 floats = 46.01 MB
constexpr size_t X_OFF   = 0;                                    // x NHWC: [b][p][64]
constexpr size_t Y1_OFF  = X_OFF  + (size_t)B_ * HW_ * 64;       // y1 NHWC @80x80
constexpr size_t Y2_OFF  = Y1_OFF + (size_t)B_ * 6400 * 64;      // y2 NHWC @40x40
constexpr size_t Y3_OFF  = Y2_OFF + (size_t)B_ * 1600 * 64;      // y3 NHWC @20x20
constexpr size_t OM_OFF  = Y3_OFF + (size_t)B_ * 400 * 64;       // om: [b][p][27] (sy,sx,mk)*9
constexpr size_t WR0_OFF = OM_OFF + (size_t)B_ * HW_ * 27;       // w0 fp32 [ci][o]: 4096
constexpr size_t WTB_OFF = WR0_OFF + 4096;                       // dcn_w bf16 [k][o][c pad72]: 41472 ush
constexpr size_t RWB_OFF = WTB_OFF + (9 * 64 * 72) / 2;          // off_w bf16 [tap][o pad32][ci]: 18432 ush
constexpr size_t SB_OFF  = RWB_OFF + (9 * 32 * 64) / 2;          // 5 BNs x (scale[64], bias[64])
// transposed conv1x1 weights OVERLAID at head of X region (die before fuse writes x).
constexpr size_t WR1_OFF = X_OFF + 0;       // w1 fp32 [ci][o]
constexpr size_t WR2_OFF = X_OFF + 8192;    // w2 fp32 [ci][o]
constexpr size_t WR3_OFF = X_OFF + 24576;   // w3 fp32 [ci][o]

typedef short bf16x8 __attribute__((ext_vector_type(8)));
typedef float f32x4 __attribute__((ext_vector_type(4)));

static __device__ __forceinline__ unsigned short f2bf(float f) {
    unsigned int u = __float_as_uint(f);
    u += 0x7fff + ((u >> 16) & 1);   // RNE
    return (unsigned short)(u >> 16);
}

__global__ __launch_bounds__(256) void prep_kernel(
    const float* __restrict__ g0, const float* __restrict__ b0, const float* __restrict__ m0, const float* __restrict__ v0,
    const float* __restrict__ g1, const float* __restrict__ b1, const float* __restrict__ m1, const float* __restrict__ v1,
    const float* __restrict__ g2, const float* __restrict__ b2, const float* __restrict__ m2, const float* __restrict__ v2,
    const float* __restrict__ g3, const float* __restrict__ b3, const float* __restrict__ m3, const float* __restrict__ v3,
    const float* __restrict__ gf, const float* __restrict__ bf, const float* __restrict__ mf, const float* __restrict__ vf,
    const float* __restrict__ w0, const float* __restrict__ w1, const float* __restrict__ w2, const float* __restrict__ w3,
    const float* __restrict__ dcn_w, const float* __restrict__ off_w,
    float* __restrict__ ws)
{
    int tid = blockIdx.x * 256 + threadIdx.x;
    if (tid < 320) {  // BN scale/bias fold
        int j = tid >> 6, c = tid & 63;
        const float *g, *b, *m, *v;
        switch (j) {
            case 0: g = g0; b = b0; m = m0; v = v0; break;
            case 1: g = g1; b = b1; m = m1; v = v1; break;
            case 2: g = g2; b = b2; m = m2; v = v2; break;
            case 3: g = g3; b = b3; m = m3; v = v3; break;
            default: g = gf; b = bf; m = mf; v = vf; break;
        }
        float sc = g[c] * rsqrtf(v[c] + EPSB);
        ws[SB_OFF + j * 128 + c]      = sc;
        ws[SB_OFF + j * 128 + 64 + c] = b[c] - m[c] * sc;
        return;
    }
    int t = tid - 320;
    if (t < 4096) {  // wr0[ci*64+o] = w0[o*64+ci]
        int ci = t >> 6, o = t & 63;
        ws[WR0_OFF + t] = w0[o * 64 + ci];
        return;
    }
    t -= 4096;
    if (t < 9 * 64 * 72) {  // wtb[k][o][c pad72] bf16 = dcn_w[o][c][k]
        int k = t / 4608, r = t % 4608, o = r / 72, c = r % 72;
        float v = (c < 64) ? dcn_w[o * 576 + c * 9 + k] : 0.f;
        ((unsigned short*)(ws + WTB_OFF))[t] = f2bf(v);
        return;
    }
    t -= 9 * 64 * 72;
    if (t < 9 * 32 * 64) {  // rwb[tap][o pad32][ci] bf16 = off_w[o][ci][tap]
        int tap = t >> 11, r = t & 2047, o = r >> 6, ci = r & 63;
        float v = (o < 27) ? off_w[o * 576 + ci * 9 + tap] : 0.f;
        ((unsigned short*)(ws + RWB_OFF))[t] = f2bf(v);
        return;
    }
    t -= 9 * 32 * 64;
    if (t < 8192) {  // wr1[ci*64+o] = w1[o*128+ci]
        int ci = t >> 6, o = t & 63;
        ws[WR1_OFF + t] = w1[o * 128 + ci];
        return;
    }
    t -= 8192;
    if (t < 16384) {  // wr2
        int ci = t >> 6, o = t & 63;
        ws[WR2_OFF + t] = w2[o * 256 + ci];
        return;
    }
    t -= 16384;
    if (t < 32768) {  // wr3
        int ci = t >> 6, o = t & 63;
        ws[WR3_OFF + t] = w3[o * 512 + ci];
        return;
    }
}

// wave = one (b,p); lanes = 64 output channels; weights [ci][o] -> coalesced. NHWC out. XCD-affine.
__global__ __launch_bounds__(256) void conv1x1_bn_kernel(
    const float* __restrict__ f, const float* __restrict__ wr,
    const float* __restrict__ sb, float* __restrict__ out, int Cin, int hw)
{
    int xcd = blockIdx.x & 7, slot = blockIdx.x >> 3;
    int b = xcd >> 1;
    int g = (xcd & 1) * (hw >> 3) + slot;
    int o = threadIdx.x & 63;
    int p = g * 4 + (threadIdx.x >> 6);
    p = __builtin_amdgcn_readfirstlane(p);
    b = __builtin_amdgcn_readfirstlane(b);
    const float* fb = f + (size_t)b * Cin * hw + p;
    float acc = 0.f;
#pragma unroll 8
    for (int ci = 0; ci < Cin; ++ci) acc = fmaf(fb[(size_t)ci * hw], wr[ci * 64 + o], acc);
    out[((size_t)b * hw + p) * 64 + o] = fmaf(acc, sb[o], sb[64 + o]);
}

// block = 64 px x 4 ch-groups; f0 tile staged in LDS; x written via LDS transpose
// with chunk-major f32x4 stores (16 lines/instr instead of 64). XCD-affine.
__global__ __launch_bounds__(256) void fuse_kernel(const float* __restrict__ f0, float* __restrict__ ws)
{
    __shared__ float Ft[64 * 64];    // [ci][px] 16 KB
    __shared__ float Ot[64 * 68];    // [px][ch pad 68] 17.4 KB

    int tid = threadIdx.x;
    int blk = blockIdx.x;
    int xcd = blk & 7, slot = blk >> 3;
    int b = xcd >> 1;
    int t = (xcd & 1) * 200 + slot;
    int p0 = t * 64;
    int lane = tid & 63, cb = tid >> 6;
    int p = p0 + lane;
    int h = p / W_, w = p % W_;
    const float* wr0 = ws + WR0_OFF + cb * 16;
    const float* sb  = ws + SB_OFF;  // bn0

    // stage f0 tile cooperatively: f0[b][ci][p0+px] -> Ft[ci][px]
    {
        const float* f0b = f0 + (size_t)b * 64 * HW_ + p0;
        for (int i = tid; i < 4096; i += 256) {
            int ci = i >> 6, px = i & 63;
            Ft[ci * 64 + px] = f0b[(size_t)ci * HW_ + px];
        }
    }
    __syncthreads();

    float acc[16];
#pragma unroll
    for (int i = 0; i < 16; i++) acc[i] = 0.f;

    for (int ci = 0; ci < 64; ++ci) {
        float fv = Ft[ci * 64 + lane];
        const float* wrow = wr0 + ci * 64;
#pragma unroll
        for (int i = 0; i < 16; i++) acc[i] = fmaf(fv, wrow[i], acc[i]);
    }
#pragma unroll
    for (int i = 0; i < 16; i++) {
        int o = cb * 16 + i;
        acc[i] = fmaf(acc[i], sb[o], sb[64 + o]);
    }

    {   // +upsample x2 from 80x80 (align_corners), NHWC
        float fy = h * (79.f / 159.f); int i0 = (int)fy; if (i0 > 78) i0 = 78; float ty = fy - i0;
        float fx = w * (79.f / 159.f); int j0 = (int)fx; if (j0 > 78) j0 = 78; float tx = fx - j0;
        float w00 = (1.f - ty) * (1.f - tx), w01 = (1.f - ty) * tx, w10 = ty * (1.f - tx), w11 = ty * tx;
        const float* y = ws + Y1_OFF + ((size_t)b * 6400 + (size_t)(i0 * 80 + j0)) * 64 + cb * 16;
#pragma unroll
        for (int c4 = 0; c4 < 4; c4++) {
            f32x4 a00 = *(const f32x4*)(y + c4 * 4);
            f32x4 a01 = *(const f32x4*)(y + 64 + c4 * 4);
            f32x4 a10 = *(const f32x4*)(y + 80 * 64 + c4 * 4);
            f32x4 a11 = *(const f32x4*)(y + 81 * 64 + c4 * 4);
#pragma unroll
            for (int j = 0; j < 4; j++)
                acc[c4 * 4 + j] += a00[j] * w00 + a01[j] * w01 + a10[j] * w10 + a11[j] * w11;
        }
    }
    {   // +upsample x4 from 40x40
        float fy = h * (39.f / 159.f); int i0 = (int)fy; if (i0 > 38) i0 = 38; float ty = fy - i0;
        float fx = w * (39.f / 159.f); int j0 = (int)fx; if (j0 > 38) j0 = 38; float tx = fx - j0;
        float w00 = (1.f - ty) * (1.f - tx), w01 = (1.f - ty) * tx, w10 = ty * (1.f - tx), w11 = ty * tx;
        const float* y = ws + Y2_OFF + ((size_t)b * 1600 + (size_t)(i0 * 40 + j0)) * 64 + cb * 16;
#pragma unroll
        for (int c4 = 0; c4 < 4; c4++) {
            f32x4 a00 = *(const f32x4*)(y + c4 * 4);
            f32x4 a01 = *(const f32x4*)(y + 64 + c4 * 4);
            f32x4 a10 = *(const f32x4*)(y + 40 * 64 + c4 * 4);
            f32x4 a11 = *(const f32x4*)(y + 41 * 64 + c4 * 4);
#pragma unroll
            for (int j = 0; j < 4; j++)
                acc[c4 * 4 + j] += a00[j] * w00 + a01[j] * w01 + a10[j] * w10 + a11[j] * w11;
        }
    }
    {   // +upsample x8 from 20x20
        float fy = h * (19.f / 159.f); int i0 = (int)fy; if (i0 > 18) i0 = 18; float ty = fy - i0;
        float fx = w * (19.f / 159.f); int j0 = (int)fx; if (j0 > 18) j0 = 18; float tx = fx - j0;
        float w00 = (1.f - ty) * (1.f - tx), w01 = (1.f - ty) * tx, w10 = ty * (1.f - tx), w11 = ty * tx;
        const float* y = ws + Y3_OFF + ((size_t)b * 400 + (size_t)(i0 * 20 + j0)) * 64 + cb * 16;
#pragma unroll
        for (int c4 = 0; c4 < 4; c4++) {
            f32x4 a00 = *(const f32x4*)(y + c4 * 4);
            f32x4 a01 = *(const f32x4*)(y + 64 + c4 * 4);
            f32x4 a10 = *(const f32x4*)(y + 20 * 64 + c4 * 4);
            f32x4 a11 = *(const f32x4*)(y + 21 * 64 + c4 * 4);
#pragma unroll
            for (int j = 0; j < 4; j++)
                acc[c4 * 4 + j] += a00[j] * w00 + a01[j] * w01 + a10[j] * w10 + a11[j] * w11;
        }
    }

    // relu -> Ot[px][ch]
    {
        float* orow = Ot + lane * 68 + cb * 16;
#pragma unroll
        for (int c4 = 0; c4 < 4; c4++) {
            f32x4 v;
#pragma unroll
            for (int j = 0; j < 4; j++) v[j] = fmaxf(acc[c4 * 4 + j], 0.f);
            *(f32x4*)(orow + c4 * 4) = v;
        }
    }
    __syncthreads();

    // chunk-major coalesced write-out: 4 px x 256B contiguous per instruction
    {
        int chunk = lane & 15, pxo = lane >> 4;
        float* xb = ws + X_OFF + ((size_t)b * HW_ + p0) * 64;
#pragma unroll
        for (int r = 0; r < 4; r++) {
            int gpx = cb * 16 + r * 4 + pxo;
            f32x4 v = *(const f32x4*)(Ot + gpx * 68 + chunk * 4);
            *(f32x4*)(xb + (size_t)gpx * 64 + chunk * 4) = v;
        }
    }
}

// offconv MFMA GEMM: chunk-major coalesced gather (IW-free, inline bounds calc),
// 2 taps per barrier window, B fragments direct from global. Writes om[b][p][27].
__global__ __launch_bounds__(256) void offconv_mfma_kernel(const float* __restrict__ off_b, float* __restrict__ ws)
{
    __shared__ __align__(16) unsigned short A_lds[2][64 * 72];   // tap-pair; reused as C float[64][28]

    int tid = threadIdx.x;
    int blk = blockIdx.x;
    int xcd = blk & 7, slot = blk >> 3;
    int b = xcd >> 1;
    int t = (xcd & 1) * 200 + slot;
    int p0 = t * 64;
    int lane = tid & 63, cb = tid >> 6;
    int px = lane;
    int p = p0 + px;
    int h = p / W_, w = p % W_;
    int mrow = lane & 15, quad = lane >> 4;
    int chunk = lane & 15, pxo = lane >> 4;   // gather mapping

    const unsigned short* rwb = (const unsigned short*)(ws + RWB_OFF);
    const float* xb = ws + X_OFF + (size_t)b * HW_ * 64;

    f32x4 acc2[2];
    acc2[0] = (f32x4){0.f, 0.f, 0.f, 0.f};
    acc2[1] = (f32x4){0.f, 0.f, 0.f, 0.f};

    for (int kk = 0; kk < 9; kk += 2) {
        __syncthreads();  // prev window's A reads done
#pragma unroll
        for (int u = 0; u < 2; u++) {
            int tap = kk + u;
            if (tap > 8) break;
            int dy = tap / 3 - 1, dx = tap % 3 - 1;
            int delta = dy * W_ + dx;
#pragma unroll
            for (int r = 0; r < 4; r++) {
                int gpx = cb * 16 + r * 4 + pxo;      // pixel this lane serves
                int gp = p0 + gpx;
                int gh = gp / W_, gw = gp % W_;
                int yy = gh + dy, xx = gw + dx;
                bool vld = (yy >= 0) && (yy < H_) && (xx >= 0) && (xx < W_);
                int ps = gp + delta;
                ps = min(max(ps, 0), HW_ - 1);
                f32x4 g = *(const f32x4*)(xb + (size_t)ps * 64 + chunk * 4);
                unsigned short pk[4];
#pragma unroll
                for (int j = 0; j < 4; j++) pk[j] = vld ? f2bf(g[j]) : (unsigned short)0;
                *(unsigned int*)(A_lds[u] + gpx * 72 + chunk * 4)     = ((unsigned int)pk[1] << 16) | pk[0];
                *(unsigned int*)(A_lds[u] + gpx * 72 + chunk * 4 + 2) = ((unsigned int)pk[3] << 16) | pk[2];
            }
        }
        __syncthreads();  // A visible

#pragma unroll
        for (int u = 0; u < 2; u++) {
            int tap = kk + u;
            if (tap > 8) break;
            const unsigned short* Ab = A_lds[u] + (cb * 16 + mrow) * 72;
#pragma unroll
            for (int ks = 0; ks < 2; ks++) {
                bf16x8 af = *(const bf16x8*)(Ab + ks * 32 + quad * 8);
#pragma unroll
                for (int nt = 0; nt < 2; nt++) {
                    bf16x8 bf_ = *(const bf16x8*)(rwb + tap * 2048 + (nt * 16 + mrow) * 64 + ks * 32 + quad * 8);
                    acc2[nt] = __builtin_amdgcn_mfma_f32_16x16x32_bf16(af, bf_, acc2[nt], 0, 0, 0);
                }
            }
        }
    }

    __syncthreads();
    float* Cl = (float*)A_lds;  // [64 px][28]
#pragma unroll
    for (int nt = 0; nt < 2; nt++) {
        int o = nt * 16 + mrow;
        if (o < 27) {
            int pr = cb * 16 + quad * 4;
#pragma unroll
            for (int r = 0; r < 4; r++) Cl[(pr + r) * 28 + o] = acc2[nt][r];
        }
    }
    __syncthreads();

    for (int k = cb; k < 9; k += 4) {
        float ady = Cl[px * 28 + 2 * k]     + off_b[2 * k];
        float adx = Cl[px * 28 + 2 * k + 1] + off_b[2 * k + 1];
        float am  = Cl[px * 28 + 18 + k]    + off_b[18 + k];
        float sy = (float)(h + k / 3 - 1) + ady;
        float sx = (float)(w + k % 3 - 1) + adx;
        float mk = 1.f / (1.f + __expf(-am));
        float* om = ws + OM_OFF + ((size_t)b * HW_ + p) * 27 + 3 * k;
        om[0] = sy; om[1] = sx; om[2] = mk;
    }
}

// dcn MFMA GEMM (R10-proven): chunk-major coalesced gather, OMs in LDS, inline (idx,wv).
__global__ __launch_bounds__(256) void dcn_mfma_kernel(const float* __restrict__ ws, float* __restrict__ out)
{
    __shared__ __align__(16) unsigned short A_lds[2][64 * 72];  // tap-pair; reused as C float[64][65]
    __shared__ float OMs[64 * 27];

    int tid = threadIdx.x;
    int blk = blockIdx.x;
    int xcd = blk & 7, slot = blk >> 3;
    int b = xcd >> 1;
    int t = (xcd & 1) * 200 + slot;
    int p0 = t * 64;
    int lane = tid & 63, cb = tid >> 6;
    int mrow = lane & 15, quad = lane >> 4;
    int chunk = lane & 15, pxo = lane >> 4;   // gather mapping

    const float* xb  = ws + X_OFF + (size_t)b * HW_ * 64;
    const unsigned short* wtb = (const unsigned short*)(ws + WTB_OFF);
    const float* sb  = ws + SB_OFF + 4 * 128;  // final bn

    // stage om for this block's 64 px
    {
        const float* omg = ws + OM_OFF + ((size_t)b * HW_ + p0) * 27;
        for (int i = tid; i < 64 * 27; i += 256) OMs[i] = omg[i];
    }

    f32x4 acc[4];
#pragma unroll
    for (int nt = 0; nt < 4; nt++) acc[nt] = (f32x4){0.f, 0.f, 0.f, 0.f};

    for (int kk = 0; kk < 9; kk += 2) {
        __syncthreads();  // prev window's A reads done; first iter: OMs staged
#pragma unroll
        for (int u = 0; u < 2; u++) {
            int k = kk + u;
            if (k > 8) break;
#pragma unroll
            for (int r = 0; r < 4; r++) {
                int gpx = cb * 16 + r * 4 + pxo;   // pixel this lane serves
                float sy = OMs[gpx * 27 + 3 * k];
                float sx = OMs[gpx * 27 + 3 * k + 1];
                float mk = OMs[gpx * 27 + 3 * k + 2];
                float y0f = floorf(sy), x0f = floorf(sx);
                int y0 = (int)y0f, x0 = (int)x0f;
                float ty = sy - y0f, tx = sx - x0f;
                f32x4 v = (f32x4){0.f, 0.f, 0.f, 0.f};
#pragma unroll
                for (int cr = 0; cr < 4; cr++) {
                    int dy = cr >> 1, dx = cr & 1;
                    int yy = y0 + dy, xx = x0 + dx;
                    float wy = dy ? ty : 1.f - ty;
                    float wx = dx ? tx : 1.f - tx;
                    bool vld = (yy >= 0) && (yy < H_) && (xx >= 0) && (xx < W_);
                    int yc = min(max(yy, 0), H_ - 1);
                    int xc = min(max(xx, 0), W_ - 1);
                    float wv = vld ? wy * wx * mk : 0.f;
                    f32x4 g = *(const f32x4*)(xb + (size_t)(yc * W_ + xc) * 64 + chunk * 4);
#pragma unroll
                    for (int j = 0; j < 4; j++) v[j] = fmaf(g[j], wv, v[j]);
                }
                unsigned short pk[4];
#pragma unroll
                for (int j = 0; j < 4; j++) pk[j] = f2bf(v[j]);
                *(unsigned int*)(A_lds[u] + gpx * 72 + chunk * 4)     = ((unsigned int)pk[1] << 16) | pk[0];
                *(unsigned int*)(A_lds[u] + gpx * 72 + chunk * 4 + 2) = ((unsigned int)pk[3] << 16) | pk[2];
            }
        }
        __syncthreads();  // A visible

#pragma unroll
        for (int u = 0; u < 2; u++) {
            int k = kk + u;
            if (k > 8) break;
            const unsigned short* Ab = A_lds[u] + (cb * 16 + mrow) * 72;
#pragma unroll
            for (int ks = 0; ks < 2; ks++) {
                bf16x8 af = *(const bf16x8*)(Ab + ks * 32 + quad * 8);
#pragma unroll
                for (int nt = 0; nt < 4; nt++) {
                    bf16x8 bf_ = *(const bf16x8*)(wtb + k * 4608 + (nt * 16 + mrow) * 72 + ks * 32 + quad * 8);
                    acc[nt] = __builtin_amdgcn_mfma_f32_16x16x32_bf16(af, bf_, acc[nt], 0, 0, 0);
                }
            }
        }
    }

    // epilogue: C frag -> LDS [o][px pad65] -> NCHW store
    __syncthreads();
    float* C_lds = (float*)A_lds;
#pragma unroll
    for (int nt = 0; nt < 4; nt++) {
        int o = nt * 16 + mrow;
        int pxb = cb * 16 + quad * 4;
#pragma unroll
        for (int r = 0; r < 4; r++) C_lds[o * 65 + pxb + r] = acc[nt][r];
    }
    __syncthreads();
#pragma unroll
    for (int i = 0; i < 16; i++) {
        int o = cb * 16 + i;
        float v = C_lds[o * 65 + lane];
        v = fmaf(v, sb[o], sb[64 + o]);
        out[((size_t)b * 64 + o) * HW_ + p0 + lane] = fmaxf(v, 0.f);
    }
}

extern "C" void kernel_launch(void* const* d_in, const int* in_sizes, int n_in,
                              void* d_out, int out_size, void* d_ws, size_t ws_size,
                              hipStream_t stream)
{
    const float* f0 = (const float*)d_in[0];
    const float* f1 = (const float*)d_in[1];
    const float* f2 = (const float*)d_in[2];
    const float* f3 = (const float*)d_in[3];
    const float* w0 = (const float*)d_in[4];
    const float* g0 = (const float*)d_in[5];
    const float* b0 = (const float*)d_in[6];
    const float* m0 = (const float*)d_in[7];
    const float* v0 = (const float*)d_in[8];
    const float* w1 = (const float*)d_in[9];
    const float* g1 = (const float*)d_in[10];
    const float* b1 = (const float*)d_in[11];
    const float* m1 = (const float*)d_in[12];
    const float* v1 = (const float*)d_in[13];
    const float* w2 = (const float*)d_in[14];
    const float* g2 = (const float*)d_in[15];
    const float* b2 = (const float*)d_in[16];
    const float* m2 = (const float*)d_in[17];
    const float* v2 = (const float*)d_in[18];
    const float* w3 = (const float*)d_in[19];
    const float* g3 = (const float*)d_in[20];
    const float* b3 = (const float*)d_in[21];
    const float* m3 = (const float*)d_in[22];
    const float* v3 = (const float*)d_in[23];
    const float* off_w = (const float*)d_in[24];
    const float* off_b = (const float*)d_in[25];
    const float* dcn_w = (const float*)d_in[26];
    const float* gf = (const float*)d_in[27];
    const float* bf = (const float*)d_in[28];
    const float* mf = (const float*)d_in[29];
    const float* vf = (const float*)d_in[30];

    float* ws  = (float*)d_ws;
    float* out = (float*)d_out;

    prep_kernel<<<dim3(476), dim3(256), 0, stream>>>(
        g0, b0, m0, v0, g1, b1, m1, v1, g2, b2, m2, v2, g3, b3, m3, v3,
        gf, bf, mf, vf, w0, w1, w2, w3, dcn_w, off_w, ws);

    conv1x1_bn_kernel<<<dim3(6400), dim3(256), 0, stream>>>(f1, ws + WR1_OFF, ws + SB_OFF + 128, ws + Y1_OFF, 128, 6400);
    conv1x1_bn_kernel<<<dim3(1600), dim3(256), 0, stream>>>(f2, ws + WR2_OFF, ws + SB_OFF + 256, ws + Y2_OFF, 256, 1600);
    conv1x1_bn_kernel<<<dim3(400),  dim3(256), 0, stream>>>(f3, ws + WR3_OFF, ws + SB_OFF + 384, ws + Y3_OFF, 512, 400);

    fuse_kernel<<<dim3(1600), dim3(256), 0, stream>>>(f0, ws);

    offconv_mfma_kernel<<<dim3(1600), dim3(256), 0, stream>>>(off_b, ws);

    dcn_mfma_kernel<<<dim3(1600), dim3(256), 0, stream>>>(ws, out);
}

// Round 12
// 406.610 us; speedup vs baseline: 1.9254x; 1.0112x over previous
//
#include <hip/hip_runtime.h>
#include <math.h>

#define EPSB 1e-5f

constexpr int B_ = 4;
constexpr int C_ = 64;
constexpr int H_ = 160;
constexpr int W_ = 160;
constexpr int HW_ = H_ * W_;

// workspace layout (float offsets) — total 11,503,488 floats = 46.01 MB
constexpr size_t X_OFF   = 0;                                    // x NHWC: [b][p][64]
constexpr size_t Y1_OFF  = X_OFF  + (size_t)B_ * HW_ * 64;       // y1 NHWC @80x80
constexpr size_t Y2_OFF  = Y1_OFF + (size_t)B_ * 6400 * 64;      // y2 NHWC @40x40
constexpr size_t Y3_OFF  = Y2_OFF + (size_t)B_ * 1600 * 64;      // y3 NHWC @20x20
constexpr size_t OM_OFF  = Y3_OFF + (size_t)B_ * 400 * 64;       // om: [b][p][27] (sy,sx,mk)*9
constexpr size_t WR0_OFF = OM_OFF + (size_t)B_ * HW_ * 27;       // w0 fp32 [ci][o]: 4096
constexpr size_t WTB_OFF = WR0_OFF + 4096;                       // dcn_w bf16 [k][o][c pad72]: 41472 ush
constexpr size_t RWB_OFF = WTB_OFF + (9 * 64 * 72) / 2;          // off_w bf16 [tap][o pad32][ci]: 18432 ush
constexpr size_t SB_OFF  = RWB_OFF + (9 * 32 * 64) / 2;          // 5 BNs x (scale[64], bias[64])
// transposed conv1x1 weights OVERLAID at head of X region (die before fuse writes x).
constexpr size_t WR1_OFF = X_OFF + 0;       // w1 fp32 [ci][o]
constexpr size_t WR2_OFF = X_OFF + 8192;    // w2 fp32 [ci][o]
constexpr size_t WR3_OFF = X_OFF + 24576;   // w3 fp32 [ci][o]

typedef short bf16x8 __attribute__((ext_vector_type(8)));
typedef float f32x4 __attribute__((ext_vector_type(4)));

static __device__ __forceinline__ unsigned short f2bf(float f) {
    unsigned int u = __float_as_uint(f);
    u += 0x7fff + ((u >> 16) & 1);   // RNE
    return (unsigned short)(u >> 16);
}

__global__ __launch_bounds__(256) void prep_kernel(
    const float* __restrict__ g0, const float* __restrict__ b0, const float* __restrict__ m0, const float* __restrict__ v0,
    const float* __restrict__ g1, const float* __restrict__ b1, const float* __restrict__ m1, const float* __restrict__ v1,
    const float* __restrict__ g2, const float* __restrict__ b2, const float* __restrict__ m2, const float* __restrict__ v2,
    const float* __restrict__ g3, const float* __restrict__ b3, const float* __restrict__ m3, const float* __restrict__ v3,
    const float* __restrict__ gf, const float* __restrict__ bf, const float* __restrict__ mf, const float* __restrict__ vf,
    const float* __restrict__ w0, const float* __restrict__ w1, const float* __restrict__ w2, const float* __restrict__ w3,
    const float* __restrict__ dcn_w, const float* __restrict__ off_w,
    float* __restrict__ ws)
{
    int tid = blockIdx.x * 256 + threadIdx.x;
    if (tid < 320) {  // BN scale/bias fold
        int j = tid >> 6, c = tid & 63;
        const float *g, *b, *m, *v;
        switch (j) {
            case 0: g = g0; b = b0; m = m0; v = v0; break;
            case 1: g = g1; b = b1; m = m1; v = v1; break;
            case 2: g = g2; b = b2; m = m2; v = v2; break;
            case 3: g = g3; b = b3; m = m3; v = v3; break;
            default: g = gf; b = bf; m = mf; v = vf; break;
        }
        float sc = g[c] * rsqrtf(v[c] + EPSB);
        ws[SB_OFF + j * 128 + c]      = sc;
        ws[SB_OFF + j * 128 + 64 + c] = b[c] - m[c] * sc;
        return;
    }
    int t = tid - 320;
    if (t < 4096) {  // wr0[ci*64+o] = w0[o*64+ci]
        int ci = t >> 6, o = t & 63;
        ws[WR0_OFF + t] = w0[o * 64 + ci];
        return;
    }
    t -= 4096;
    if (t < 9 * 64 * 72) {  // wtb[k][o][c pad72] bf16 = dcn_w[o][c][k]
        int k = t / 4608, r = t % 4608, o = r / 72, c = r % 72;
        float v = (c < 64) ? dcn_w[o * 576 + c * 9 + k] : 0.f;
        ((unsigned short*)(ws + WTB_OFF))[t] = f2bf(v);
        return;
    }
    t -= 9 * 64 * 72;
    if (t < 9 * 32 * 64) {  // rwb[tap][o pad32][ci] bf16 = off_w[o][ci][tap]
        int tap = t >> 11, r = t & 2047, o = r >> 6, ci = r & 63;
        float v = (o < 27) ? off_w[o * 576 + ci * 9 + tap] : 0.f;
        ((unsigned short*)(ws + RWB_OFF))[t] = f2bf(v);
        return;
    }
    t -= 9 * 32 * 64;
    if (t < 8192) {  // wr1[ci*64+o] = w1[o*128+ci]
        int ci = t >> 6, o = t & 63;
        ws[WR1_OFF + t] = w1[o * 128 + ci];
        return;
    }
    t -= 8192;
    if (t < 16384) {  // wr2
        int ci = t >> 6, o = t & 63;
        ws[WR2_OFF + t] = w2[o * 256 + ci];
        return;
    }
    t -= 16384;
    if (t < 32768) {  // wr3
        int ci = t >> 6, o = t & 63;
        ws[WR3_OFF + t] = w3[o * 512 + ci];
        return;
    }
}

// wave = one (b,p); lanes = 64 output channels; weights [ci][o] -> coalesced. NHWC out. XCD-affine.
__global__ __launch_bounds__(256) void conv1x1_bn_kernel(
    const float* __restrict__ f, const float* __restrict__ wr,
    const float* __restrict__ sb, float* __restrict__ out, int Cin, int hw)
{
    int xcd = blockIdx.x & 7, slot = blockIdx.x >> 3;
    int b = xcd >> 1;
    int g = (xcd & 1) * (hw >> 3) + slot;
    int o = threadIdx.x & 63;
    int p = g * 4 + (threadIdx.x >> 6);
    p = __builtin_amdgcn_readfirstlane(p);
    b = __builtin_amdgcn_readfirstlane(b);
    const float* fb = f + (size_t)b * Cin * hw + p;
    float acc = 0.f;
#pragma unroll 8
    for (int ci = 0; ci < Cin; ++ci) acc = fmaf(fb[(size_t)ci * hw], wr[ci * 64 + o], acc);
    out[((size_t)b * hw + p) * 64 + o] = fmaf(acc, sb[o], sb[64 + o]);
}

// fuse v3: phase-1 per-px fp32 conv+BN -> Ot (LDS); phase-2 chunk-major
// (lane = 4px x 16ch-chunk) upsample adds + relu + coalesced store. XCD-affine.
__global__ __launch_bounds__(256) void fuse_kernel(const float* __restrict__ f0, float* __restrict__ ws)
{
    __shared__ float Ot[64 * 68];    // [px][ch pad 68] 17.4 KB

    int tid = threadIdx.x;
    int blk = blockIdx.x;
    int xcd = blk & 7, slot = blk >> 3;
    int b = xcd >> 1;
    int t = (xcd & 1) * 200 + slot;
    int p0 = t * 64;
    int lane = tid & 63, cb = tid >> 6;
    int p = p0 + lane;
    const float* wr0 = ws + WR0_OFF + cb * 16;
    const float* sb  = ws + SB_OFF;  // bn0

    // phase 1: conv1x1(f0)+bn for (px=lane, ch=cb*16..+15), coalesced direct reads
    {
        float acc[16];
#pragma unroll
        for (int i = 0; i < 16; i++) acc[i] = 0.f;

        const float* f0b = f0 + (size_t)b * 64 * HW_ + p;
        for (int ci = 0; ci < 64; ++ci) {
            float fv = f0b[(size_t)ci * HW_];
            const float* wrow = wr0 + ci * 64;
#pragma unroll
            for (int i = 0; i < 16; i++) acc[i] = fmaf(fv, wrow[i], acc[i]);
        }
        float* orow = Ot + lane * 68 + cb * 16;
#pragma unroll
        for (int i = 0; i < 16; i++) {
            int o = cb * 16 + i;
            orow[i] = fmaf(acc[i], sb[o], sb[64 + o]);
        }
    }
    __syncthreads();

    // phase 2: chunk-major upsample + relu + store (16 lines/instr)
    {
        int chunk = lane & 15, pxo = lane >> 4;
        float* xb = ws + X_OFF + ((size_t)b * HW_ + p0) * 64;
#pragma unroll
        for (int r = 0; r < 4; r++) {
            int gpx = cb * 16 + r * 4 + pxo;
            int gp = p0 + gpx;
            int h = gp / W_, w = gp % W_;
            f32x4 v = *(const f32x4*)(Ot + gpx * 68 + chunk * 4);

            {   // +upsample x2 from 80x80
                float fy = h * (79.f / 159.f); int i0 = (int)fy; if (i0 > 78) i0 = 78; float ty = fy - i0;
                float fx = w * (79.f / 159.f); int j0 = (int)fx; if (j0 > 78) j0 = 78; float tx = fx - j0;
                float w00 = (1.f - ty) * (1.f - tx), w01 = (1.f - ty) * tx, w10 = ty * (1.f - tx), w11 = ty * tx;
                const float* y = ws + Y1_OFF + ((size_t)b * 6400 + (size_t)(i0 * 80 + j0)) * 64 + chunk * 4;
                f32x4 a00 = *(const f32x4*)(y);
                f32x4 a01 = *(const f32x4*)(y + 64);
                f32x4 a10 = *(const f32x4*)(y + 80 * 64);
                f32x4 a11 = *(const f32x4*)(y + 81 * 64);
#pragma unroll
                for (int j = 0; j < 4; j++)
                    v[j] += a00[j] * w00 + a01[j] * w01 + a10[j] * w10 + a11[j] * w11;
            }
            {   // +upsample x4 from 40x40
                float fy = h * (39.f / 159.f); int i0 = (int)fy; if (i0 > 38) i0 = 38; float ty = fy - i0;
                float fx = w * (39.f / 159.f); int j0 = (int)fx; if (j0 > 38) j0 = 38; float tx = fx - j0;
                float w00 = (1.f - ty) * (1.f - tx), w01 = (1.f - ty) * tx, w10 = ty * (1.f - tx), w11 = ty * tx;
                const float* y = ws + Y2_OFF + ((size_t)b * 1600 + (size_t)(i0 * 40 + j0)) * 64 + chunk * 4;
                f32x4 a00 = *(const f32x4*)(y);
                f32x4 a01 = *(const f32x4*)(y + 64);
                f32x4 a10 = *(const f32x4*)(y + 40 * 64);
                f32x4 a11 = *(const f32x4*)(y + 41 * 64);
#pragma unroll
                for (int j = 0; j < 4; j++)
                    v[j] += a00[j] * w00 + a01[j] * w01 + a10[j] * w10 + a11[j] * w11;
            }
            {   // +upsample x8 from 20x20
                float fy = h * (19.f / 159.f); int i0 = (int)fy; if (i0 > 18) i0 = 18; float ty = fy - i0;
                float fx = w * (19.f / 159.f); int j0 = (int)fx; if (j0 > 18) j0 = 18; float tx = fx - j0;
                float w00 = (1.f - ty) * (1.f - tx), w01 = (1.f - ty) * tx, w10 = ty * (1.f - tx), w11 = ty * tx;
                const float* y = ws + Y3_OFF + ((size_t)b * 400 + (size_t)(i0 * 20 + j0)) * 64 + chunk * 4;
                f32x4 a00 = *(const f32x4*)(y);
                f32x4 a01 = *(const f32x4*)(y + 64);
                f32x4 a10 = *(const f32x4*)(y + 20 * 64);
                f32x4 a11 = *(const f32x4*)(y + 21 * 64);
#pragma unroll
                for (int j = 0; j < 4; j++)
                    v[j] += a00[j] * w00 + a01[j] * w01 + a10[j] * w10 + a11[j] * w11;
            }

#pragma unroll
            for (int j = 0; j < 4; j++) v[j] = fmaxf(v[j], 0.f);
            *(f32x4*)(xb + (size_t)gpx * 64 + chunk * 4) = v;
        }
    }
}

// offconv MFMA GEMM: chunk-major coalesced gather (IW-free, inline bounds calc),
// 2 taps per barrier window, B fragments direct from global. Writes om[b][p][27].
__global__ __launch_bounds__(256) void offconv_mfma_kernel(const float* __restrict__ off_b, float* __restrict__ ws)
{
    __shared__ __align__(16) unsigned short A_lds[2][64 * 72];   // tap-pair; reused as C float[64][28]

    int tid = threadIdx.x;
    int blk = blockIdx.x;
    int xcd = blk & 7, slot = blk >> 3;
    int b = xcd >> 1;
    int t = (xcd & 1) * 200 + slot;
    int p0 = t * 64;
    int lane = tid & 63, cb = tid >> 6;
    int px = lane;
    int p = p0 + px;
    int h = p / W_, w = p % W_;
    int mrow = lane & 15, quad = lane >> 4;
    int chunk = lane & 15, pxo = lane >> 4;   // gather mapping

    const unsigned short* rwb = (const unsigned short*)(ws + RWB_OFF);
    const float* xb = ws + X_OFF + (size_t)b * HW_ * 64;

    f32x4 acc2[2];
    acc2[0] = (f32x4){0.f, 0.f, 0.f, 0.f};
    acc2[1] = (f32x4){0.f, 0.f, 0.f, 0.f};

    for (int kk = 0; kk < 9; kk += 2) {
        __syncthreads();  // prev window's A reads done
#pragma unroll
        for (int u = 0; u < 2; u++) {
            int tap = kk + u;
            if (tap > 8) break;
            int dy = tap / 3 - 1, dx = tap % 3 - 1;
            int delta = dy * W_ + dx;
#pragma unroll
            for (int r = 0; r < 4; r++) {
                int gpx = cb * 16 + r * 4 + pxo;      // pixel this lane serves
                int gp = p0 + gpx;
                int gh = gp / W_, gw = gp % W_;
                int yy = gh + dy, xx = gw + dx;
                bool vld = (yy >= 0) && (yy < H_) && (xx >= 0) && (xx < W_);
                int ps = gp + delta;
                ps = min(max(ps, 0), HW_ - 1);
                f32x4 g = *(const f32x4*)(xb + (size_t)ps * 64 + chunk * 4);
                unsigned short pk[4];
#pragma unroll
                for (int j = 0; j < 4; j++) pk[j] = vld ? f2bf(g[j]) : (unsigned short)0;
                *(unsigned int*)(A_lds[u] + gpx * 72 + chunk * 4)     = ((unsigned int)pk[1] << 16) | pk[0];
                *(unsigned int*)(A_lds[u] + gpx * 72 + chunk * 4 + 2) = ((unsigned int)pk[3] << 16) | pk[2];
            }
        }
        __syncthreads();  // A visible

#pragma unroll
        for (int u = 0; u < 2; u++) {
            int tap = kk + u;
            if (tap > 8) break;
            const unsigned short* Ab = A_lds[u] + (cb * 16 + mrow) * 72;
#pragma unroll
            for (int ks = 0; ks < 2; ks++) {
                bf16x8 af = *(const bf16x8*)(Ab + ks * 32 + quad * 8);
#pragma unroll
                for (int nt = 0; nt < 2; nt++) {
                    bf16x8 bf_ = *(const bf16x8*)(rwb + tap * 2048 + (nt * 16 + mrow) * 64 + ks * 32 + quad * 8);
                    acc2[nt] = __builtin_amdgcn_mfma_f32_16x16x32_bf16(af, bf_, acc2[nt], 0, 0, 0);
                }
            }
        }
    }

    __syncthreads();
    float* Cl = (float*)A_lds;  // [64 px][28]
#pragma unroll
    for (int nt = 0; nt < 2; nt++) {
        int o = nt * 16 + mrow;
        if (o < 27) {
            int pr = cb * 16 + quad * 4;
#pragma unroll
            for (int r = 0; r < 4; r++) Cl[(pr + r) * 28 + o] = acc2[nt][r];
        }
    }
    __syncthreads();

    for (int k = cb; k < 9; k += 4) {
        float ady = Cl[px * 28 + 2 * k]     + off_b[2 * k];
        float adx = Cl[px * 28 + 2 * k + 1] + off_b[2 * k + 1];
        float am  = Cl[px * 28 + 18 + k]    + off_b[18 + k];
        float sy = (float)(h + k / 3 - 1) + ady;
        float sx = (float)(w + k % 3 - 1) + adx;
        float mk = 1.f / (1.f + __expf(-am));
        float* om = ws + OM_OFF + ((size_t)b * HW_ + p) * 27 + 3 * k;
        om[0] = sy; om[1] = sx; om[2] = mk;
    }
}

// dcn MFMA GEMM (R10-proven): chunk-major coalesced gather, OMs in LDS, inline (idx,wv).
__global__ __launch_bounds__(256) void dcn_mfma_kernel(const float* __restrict__ ws, float* __restrict__ out)
{
    __shared__ __align__(16) unsigned short A_lds[2][64 * 72];  // tap-pair; reused as C float[64][65]
    __shared__ float OMs[64 * 27];

    int tid = threadIdx.x;
    int blk = blockIdx.x;
    int xcd = blk & 7, slot = blk >> 3;
    int b = xcd >> 1;
    int t = (xcd & 1) * 200 + slot;
    int p0 = t * 64;
    int lane = tid & 63, cb = tid >> 6;
    int mrow = lane & 15, quad = lane >> 4;
    int chunk = lane & 15, pxo = lane >> 4;   // gather mapping

    const float* xb  = ws + X_OFF + (size_t)b * HW_ * 64;
    const unsigned short* wtb = (const unsigned short*)(ws + WTB_OFF);
    const float* sb  = ws + SB_OFF + 4 * 128;  // final bn

    // stage om for this block's 64 px
    {
        const float* omg = ws + OM_OFF + ((size_t)b * HW_ + p0) * 27;
        for (int i = tid; i < 64 * 27; i += 256) OMs[i] = omg[i];
    }

    f32x4 acc[4];
#pragma unroll
    for (int nt = 0; nt < 4; nt++) acc[nt] = (f32x4){0.f, 0.f, 0.f, 0.f};

    for (int kk = 0; kk < 9; kk += 2) {
        __syncthreads();  // prev window's A reads done; first iter: OMs staged
#pragma unroll
        for (int u = 0; u < 2; u++) {
            int k = kk + u;
            if (k > 8) break;
#pragma unroll
            for (int r = 0; r < 4; r++) {
                int gpx = cb * 16 + r * 4 + pxo;   // pixel this lane serves
                float sy = OMs[gpx * 27 + 3 * k];
                float sx = OMs[gpx * 27 + 3 * k + 1];
                float mk = OMs[gpx * 27 + 3 * k + 2];
                float y0f = floorf(sy), x0f = floorf(sx);
                int y0 = (int)y0f, x0 = (int)x0f;
                float ty = sy - y0f, tx = sx - x0f;
                f32x4 v = (f32x4){0.f, 0.f, 0.f, 0.f};
#pragma unroll
                for (int cr = 0; cr < 4; cr++) {
                    int dy = cr >> 1, dx = cr & 1;
                    int yy = y0 + dy, xx = x0 + dx;
                    float wy = dy ? ty : 1.f - ty;
                    float wx = dx ? tx : 1.f - tx;
                    bool vld = (yy >= 0) && (yy < H_) && (xx >= 0) && (xx < W_);
                    int yc = min(max(yy, 0), H_ - 1);
                    int xc = min(max(xx, 0), W_ - 1);
                    float wv = vld ? wy * wx * mk : 0.f;
                    f32x4 g = *(const f32x4*)(xb + (size_t)(yc * W_ + xc) * 64 + chunk * 4);
#pragma unroll
                    for (int j = 0; j < 4; j++) v[j] = fmaf(g[j], wv, v[j]);
                }
                unsigned short pk[4];
#pragma unroll
                for (int j = 0; j < 4; j++) pk[j] = f2bf(v[j]);
                *(unsigned int*)(A_lds[u] + gpx * 72 + chunk * 4)     = ((unsigned int)pk[1] << 16) | pk[0];
                *(unsigned int*)(A_lds[u] + gpx * 72 + chunk * 4 + 2) = ((unsigned int)pk[3] << 16) | pk[2];
            }
        }
        __syncthreads();  // A visible

#pragma unroll
        for (int u = 0; u < 2; u++) {
            int k = kk + u;
            if (k > 8) break;
            const unsigned short* Ab = A_lds[u] + (cb * 16 + mrow) * 72;
#pragma unroll
            for (int ks = 0; ks < 2; ks++) {
                bf16x8 af = *(const bf16x8*)(Ab + ks * 32 + quad * 8);
#pragma unroll
                for (int nt = 0; nt < 4; nt++) {
                    bf16x8 bf_ = *(const bf16x8*)(wtb + k * 4608 + (nt * 16 + mrow) * 72 + ks * 32 + quad * 8);
                    acc[nt] = __builtin_amdgcn_mfma_f32_16x16x32_bf16(af, bf_, acc[nt], 0, 0, 0);
                }
            }
        }
    }

    // epilogue: C frag -> LDS [o][px pad65] -> NCHW store
    __syncthreads();
    float* C_lds = (float*)A_lds;
#pragma unroll
    for (int nt = 0; nt < 4; nt++) {
        int o = nt * 16 + mrow;
        int pxb = cb * 16 + quad * 4;
#pragma unroll
        for (int r = 0; r < 4; r++) C_lds[o * 65 + pxb + r] = acc[nt][r];
    }
    __syncthreads();
#pragma unroll
    for (int i = 0; i < 16; i++) {
        int o = cb * 16 + i;
        float v = C_lds[o * 65 + lane];
        v = fmaf(v, sb[o], sb[64 + o]);
        out[((size_t)b * 64 + o) * HW_ + p0 + lane] = fmaxf(v, 0.f);
    }
}

extern "C" void kernel_launch(void* const* d_in, const int* in_sizes, int n_in,
                              void* d_out, int out_size, void* d_ws, size_t ws_size,
                              hipStream_t stream)
{
    const float* f0 = (const float*)d_in[0];
    const float* f1 = (const float*)d_in[1];
    const float* f2 = (const float*)d_in[2];
    const float* f3 = (const float*)d_in[3];
    const float* w0 = (const float*)d_in[4];
    const float* g0 = (const float*)d_in[5];
    const float* b0 = (const float*)d_in[6];
    const float* m0 = (const float*)d_in[7];
    const float* v0 = (const float*)d_in[8];
    const float* w1 = (const float*)d_in[9];
    const float* g1 = (const float*)d_in[10];
    const float* b1 = (const float*)d_in[11];
    const float* m1 = (const float*)d_in[12];
    const float* v1 = (const float*)d_in[13];
    const float* w2 = (const float*)d_in[14];
    const float* g2 = (const float*)d_in[15];
    const float* b2 = (const float*)d_in[16];
    const float* m2 = (const float*)d_in[17];
    const float* v2 = (const float*)d_in[18];
    const float* w3 = (const float*)d_in[19];
    const float* g3 = (const float*)d_in[20];
    const float* b3 = (const float*)d_in[21];
    const float* m3 = (const float*)d_in[22];
    const float* v3 = (const float*)d_in[23];
    const float* off_w = (const float*)d_in[24];
    const float* off_b = (const float*)d_in[25];
    const float* dcn_w = (const float*)d_in[26];
    const float* gf = (const float*)d_in[27];
    const float* bf = (const float*)d_in[28];
    const float* mf = (const float*)d_in[29];
    const float* vf = (const float*)d_in[30];

    float* ws  = (float*)d_ws;
    float* out = (float*)d_out;

    prep_kernel<<<dim3(476), dim3(256), 0, stream>>>(
        g0, b0, m0, v0, g1, b1, m1, v1, g2, b2, m2, v2, g3, b3, m3, v3,
        gf, bf, mf, vf, w0, w1, w2, w3, dcn_w, off_w, ws);

    conv1x1_bn_kernel<<<dim3(6400), dim3(256), 0, stream>>>(f1, ws + WR1_OFF, ws + SB_OFF + 128, ws + Y1_OFF, 128, 6400);
    conv1x1_bn_kernel<<<dim3(1600), dim3(256), 0, stream>>>(f2, ws + WR2_OFF, ws + SB_OFF + 256, ws + Y2_OFF, 256, 1600);
    conv1x1_bn_kernel<<<dim3(400),  dim3(256), 0, stream>>>(f3, ws + WR3_OFF, ws + SB_OFF + 384, ws + Y3_OFF, 512, 400);

    fuse_kernel<<<dim3(1600), dim3(256), 0, stream>>>(f0, ws);

    offconv_mfma_kernel<<<dim3(1600), dim3(256), 0, stream>>>(off_b, ws);

    dcn_mfma_kernel<<<dim3(1600), dim3(256), 0, stream>>>(ws, out);
}

// Round 13
// 362.807 us; speedup vs baseline: 2.1578x; 1.1207x over previous
//
#include <hip/hip_runtime.h>
#include <math.h>

#define EPSB 1e-5f

constexpr int B_ = 4;
constexpr int C_ = 64;
constexpr int H_ = 160;
constexpr int W_ = 160;
constexpr int HW_ = H_ * W_;

// workspace layout (float offsets) — total 11,503,488 floats = 46.01 MB
constexpr size_t X_OFF   = 0;                                    // x NHWC: [b][p][64]
constexpr size_t Y1_OFF  = X_OFF  + (size_t)B_ * HW_ * 64;       // y1 NHWC @80x80
constexpr size_t Y2_OFF  = Y1_OFF + (size_t)B_ * 6400 * 64;      // y2 NHWC @40x40
constexpr size_t Y3_OFF  = Y2_OFF + (size_t)B_ * 1600 * 64;      // y3 NHWC @20x20
constexpr size_t OM_OFF  = Y3_OFF + (size_t)B_ * 400 * 64;       // om: [b][p][27] (sy,sx,mk)*9
constexpr size_t WR0_OFF = OM_OFF + (size_t)B_ * HW_ * 27;       // w0 fp32 [ci][o]: 4096
constexpr size_t WTB_OFF = WR0_OFF + 4096;                       // dcn_w bf16 [k][o][c pad72]: 41472 ush
constexpr size_t RWB_OFF = WTB_OFF + (9 * 64 * 72) / 2;          // off_w bf16 [tap][o pad32][ci]: 18432 ush
constexpr size_t SB_OFF  = RWB_OFF + (9 * 32 * 64) / 2;          // 5 BNs x (scale[64], bias[64])
// transposed conv1x1 weights OVERLAID at head of X region (die before fuse writes x).
constexpr size_t WR1_OFF = X_OFF + 0;       // w1 fp32 [ci][o]
constexpr size_t WR2_OFF = X_OFF + 8192;    // w2 fp32 [ci][o]
constexpr size_t WR3_OFF = X_OFF + 24576;   // w3 fp32 [ci][o]

typedef short bf16x8 __attribute__((ext_vector_type(8)));
typedef float f32x4 __attribute__((ext_vector_type(4)));

static __device__ __forceinline__ unsigned short f2bf(float f) {
    unsigned int u = __float_as_uint(f);
    u += 0x7fff + ((u >> 16) & 1);   // RNE
    return (unsigned short)(u >> 16);
}

__global__ __launch_bounds__(256) void prep_kernel(
    const float* __restrict__ g0, const float* __restrict__ b0, const float* __restrict__ m0, const float* __restrict__ v0,
    const float* __restrict__ g1, const float* __restrict__ b1, const float* __restrict__ m1, const float* __restrict__ v1,
    const float* __restrict__ g2, const float* __restrict__ b2, const float* __restrict__ m2, const float* __restrict__ v2,
    const float* __restrict__ g3, const float* __restrict__ b3, const float* __restrict__ m3, const float* __restrict__ v3,
    const float* __restrict__ gf, const float* __restrict__ bf, const float* __restrict__ mf, const float* __restrict__ vf,
    const float* __restrict__ w0, const float* __restrict__ w1, const float* __restrict__ w2, const float* __restrict__ w3,
    const float* __restrict__ dcn_w, const float* __restrict__ off_w,
    float* __restrict__ ws)
{
    int tid = blockIdx.x * 256 + threadIdx.x;
    if (tid < 320) {  // BN scale/bias fold
        int j = tid >> 6, c = tid & 63;
        const float *g, *b, *m, *v;
        switch (j) {
            case 0: g = g0; b = b0; m = m0; v = v0; break;
            case 1: g = g1; b = b1; m = m1; v = v1; break;
            case 2: g = g2; b = b2; m = m2; v = v2; break;
            case 3: g = g3; b = b3; m = m3; v = v3; break;
            default: g = gf; b = bf; m = mf; v = vf; break;
        }
        float sc = g[c] * rsqrtf(v[c] + EPSB);
        ws[SB_OFF + j * 128 + c]      = sc;
        ws[SB_OFF + j * 128 + 64 + c] = b[c] - m[c] * sc;
        return;
    }
    int t = tid - 320;
    if (t < 4096) {  // wr0[ci*64+o] = w0[o*64+ci]
        int ci = t >> 6, o = t & 63;
        ws[WR0_OFF + t] = w0[o * 64 + ci];
        return;
    }
    t -= 4096;
    if (t < 9 * 64 * 72) {  // wtb[k][o][c pad72] bf16 = dcn_w[o][c][k]
        int k = t / 4608, r = t % 4608, o = r / 72, c = r % 72;
        float v = (c < 64) ? dcn_w[o * 576 + c * 9 + k] : 0.f;
        ((unsigned short*)(ws + WTB_OFF))[t] = f2bf(v);
        return;
    }
    t -= 9 * 64 * 72;
    if (t < 9 * 32 * 64) {  // rwb[tap][o pad32][ci] bf16 = off_w[o][ci][tap]
        int tap = t >> 11, r = t & 2047, o = r >> 6, ci = r & 63;
        float v = (o < 27) ? off_w[o * 576 + ci * 9 + tap] : 0.f;
        ((unsigned short*)(ws + RWB_OFF))[t] = f2bf(v);
        return;
    }
    t -= 9 * 32 * 64;
    if (t < 8192) {  // wr1[ci*64+o] = w1[o*128+ci]
        int ci = t >> 6, o = t & 63;
        ws[WR1_OFF + t] = w1[o * 128 + ci];
        return;
    }
    t -= 8192;
    if (t < 16384) {  // wr2
        int ci = t >> 6, o = t & 63;
        ws[WR2_OFF + t] = w2[o * 256 + ci];
        return;
    }
    t -= 16384;
    if (t < 32768) {  // wr3
        int ci = t >> 6, o = t & 63;
        ws[WR3_OFF + t] = w3[o * 512 + ci];
        return;
    }
}

// wave = one (b,p); lanes = 64 output channels; weights [ci][o] -> coalesced. NHWC out. XCD-affine.
__global__ __launch_bounds__(256) void conv1x1_bn_kernel(
    const float* __restrict__ f, const float* __restrict__ wr,
    const float* __restrict__ sb, float* __restrict__ out, int Cin, int hw)
{
    int xcd = blockIdx.x & 7, slot = blockIdx.x >> 3;
    int b = xcd >> 1;
    int g = (xcd & 1) * (hw >> 3) + slot;
    int o = threadIdx.x & 63;
    int p = g * 4 + (threadIdx.x >> 6);
    p = __builtin_amdgcn_readfirstlane(p);
    b = __builtin_amdgcn_readfirstlane(b);
    const float* fb = f + (size_t)b * Cin * hw + p;
    float acc = 0.f;
#pragma unroll 8
    for (int ci = 0; ci < Cin; ++ci) acc = fmaf(fb[(size_t)ci * hw], wr[ci * 64 + o], acc);
    out[((size_t)b * hw + p) * 64 + o] = fmaf(acc, sb[o], sb[64 + o]);
}

// fuse v4: scalar (wave-uniform) weight loads + batched-in-flight global loads.
// phase-1 per-px fp32 conv+BN -> Ot (LDS); phase-2 chunk-major upsample+relu+store.
__global__ __launch_bounds__(256) void fuse_kernel(const float* __restrict__ f0, float* __restrict__ ws)
{
    __shared__ float Ot[64 * 68];    // [px][ch pad 68] 17.4 KB

    int tid = threadIdx.x;
    int blk = blockIdx.x;
    int xcd = blk & 7, slot = blk >> 3;
    int b = xcd >> 1;
    int t = (xcd & 1) * 200 + slot;
    int p0 = t * 64;
    int lane = tid & 63;
    int cb = __builtin_amdgcn_readfirstlane(tid >> 6);   // wave-uniform -> scalar weight addressing
    int p = p0 + lane;
    const float* wr0 = ws + WR0_OFF + cb * 16;
    const float* sb  = ws + SB_OFF;  // bn0

    // phase 1: conv1x1(f0)+bn; f0 loads batched x8, weights via scalar loads
    {
        float acc[16];
#pragma unroll
        for (int i = 0; i < 16; i++) acc[i] = 0.f;

        const float* f0b = f0 + (size_t)b * 64 * HW_ + p;
        for (int ci0 = 0; ci0 < 64; ci0 += 8) {
            float fv[8];
#pragma unroll
            for (int j = 0; j < 8; j++) fv[j] = f0b[(size_t)(ci0 + j) * HW_];
#pragma unroll
            for (int j = 0; j < 8; j++) {
                const float* wrow = wr0 + (ci0 + j) * 64;
#pragma unroll
                for (int i = 0; i < 16; i++) acc[i] = fmaf(fv[j], wrow[i], acc[i]);
            }
        }
        float* orow = Ot + lane * 68 + cb * 16;
#pragma unroll
        for (int i = 0; i < 16; i++) {
            int o = cb * 16 + i;
            orow[i] = fmaf(acc[i], sb[o], sb[64 + o]);
        }
    }
    __syncthreads();

    // phase 2: chunk-major upsample + relu + store; all 12 corner loads hoisted per px
    {
        int chunk = lane & 15, pxo = lane >> 4;
        float* xb = ws + X_OFF + ((size_t)b * HW_ + p0) * 64;
#pragma unroll
        for (int r = 0; r < 4; r++) {
            int gpx = cb * 16 + r * 4 + pxo;
            int gp = p0 + gpx;
            int h = gp / W_, w = gp % W_;

            // level 1 (x2 from 80x80)
            float fy1 = h * (79.f / 159.f); int i1 = (int)fy1; if (i1 > 78) i1 = 78; float ty1 = fy1 - i1;
            float fx1 = w * (79.f / 159.f); int j1 = (int)fx1; if (j1 > 78) j1 = 78; float tx1 = fx1 - j1;
            const float* y1 = ws + Y1_OFF + ((size_t)b * 6400 + (size_t)(i1 * 80 + j1)) * 64 + chunk * 4;
            // level 2 (x4 from 40x40)
            float fy2 = h * (39.f / 159.f); int i2 = (int)fy2; if (i2 > 38) i2 = 38; float ty2 = fy2 - i2;
            float fx2 = w * (39.f / 159.f); int j2 = (int)fx2; if (j2 > 38) j2 = 38; float tx2 = fx2 - j2;
            const float* y2 = ws + Y2_OFF + ((size_t)b * 1600 + (size_t)(i2 * 40 + j2)) * 64 + chunk * 4;
            // level 3 (x8 from 20x20)
            float fy3 = h * (19.f / 159.f); int i3 = (int)fy3; if (i3 > 18) i3 = 18; float ty3 = fy3 - i3;
            float fx3 = w * (19.f / 159.f); int j3 = (int)fx3; if (j3 > 18) j3 = 18; float tx3 = fx3 - j3;
            const float* y3 = ws + Y3_OFF + ((size_t)b * 400 + (size_t)(i3 * 20 + j3)) * 64 + chunk * 4;

            // hoist all 12 loads — issued back-to-back, >=12 in flight
            f32x4 A[12];
            A[0]  = *(const f32x4*)(y1);
            A[1]  = *(const f32x4*)(y1 + 64);
            A[2]  = *(const f32x4*)(y1 + 80 * 64);
            A[3]  = *(const f32x4*)(y1 + 81 * 64);
            A[4]  = *(const f32x4*)(y2);
            A[5]  = *(const f32x4*)(y2 + 64);
            A[6]  = *(const f32x4*)(y2 + 40 * 64);
            A[7]  = *(const f32x4*)(y2 + 41 * 64);
            A[8]  = *(const f32x4*)(y3);
            A[9]  = *(const f32x4*)(y3 + 64);
            A[10] = *(const f32x4*)(y3 + 20 * 64);
            A[11] = *(const f32x4*)(y3 + 21 * 64);

            f32x4 v = *(const f32x4*)(Ot + gpx * 68 + chunk * 4);

            float w00, w01, w10, w11;
            w00 = (1.f - ty1) * (1.f - tx1); w01 = (1.f - ty1) * tx1; w10 = ty1 * (1.f - tx1); w11 = ty1 * tx1;
#pragma unroll
            for (int j = 0; j < 4; j++)
                v[j] += A[0][j] * w00 + A[1][j] * w01 + A[2][j] * w10 + A[3][j] * w11;
            w00 = (1.f - ty2) * (1.f - tx2); w01 = (1.f - ty2) * tx2; w10 = ty2 * (1.f - tx2); w11 = ty2 * tx2;
#pragma unroll
            for (int j = 0; j < 4; j++)
                v[j] += A[4][j] * w00 + A[5][j] * w01 + A[6][j] * w10 + A[7][j] * w11;
            w00 = (1.f - ty3) * (1.f - tx3); w01 = (1.f - ty3) * tx3; w10 = ty3 * (1.f - tx3); w11 = ty3 * tx3;
#pragma unroll
            for (int j = 0; j < 4; j++)
                v[j] += A[8][j] * w00 + A[9][j] * w01 + A[10][j] * w10 + A[11][j] * w11;

#pragma unroll
            for (int j = 0; j < 4; j++) v[j] = fmaxf(v[j], 0.f);
            *(f32x4*)(xb + (size_t)gpx * 64 + chunk * 4) = v;
        }
    }
}

// offconv MFMA GEMM: chunk-major coalesced gather (IW-free, inline bounds calc),
// 2 taps per barrier window, B fragments direct from global. Writes om[b][p][27].
__global__ __launch_bounds__(256) void offconv_mfma_kernel(const float* __restrict__ off_b, float* __restrict__ ws)
{
    __shared__ __align__(16) unsigned short A_lds[2][64 * 72];   // tap-pair; reused as C float[64][28]

    int tid = threadIdx.x;
    int blk = blockIdx.x;
    int xcd = blk & 7, slot = blk >> 3;
    int b = xcd >> 1;
    int t = (xcd & 1) * 200 + slot;
    int p0 = t * 64;
    int lane = tid & 63, cb = tid >> 6;
    int px = lane;
    int p = p0 + px;
    int h = p / W_, w = p % W_;
    int mrow = lane & 15, quad = lane >> 4;
    int chunk = lane & 15, pxo = lane >> 4;   // gather mapping

    const unsigned short* rwb = (const unsigned short*)(ws + RWB_OFF);
    const float* xb = ws + X_OFF + (size_t)b * HW_ * 64;

    f32x4 acc2[2];
    acc2[0] = (f32x4){0.f, 0.f, 0.f, 0.f};
    acc2[1] = (f32x4){0.f, 0.f, 0.f, 0.f};

    for (int kk = 0; kk < 9; kk += 2) {
        __syncthreads();  // prev window's A reads done
#pragma unroll
        for (int u = 0; u < 2; u++) {
            int tap = kk + u;
            if (tap > 8) break;
            int dy = tap / 3 - 1, dx = tap % 3 - 1;
            int delta = dy * W_ + dx;
#pragma unroll
            for (int r = 0; r < 4; r++) {
                int gpx = cb * 16 + r * 4 + pxo;      // pixel this lane serves
                int gp = p0 + gpx;
                int gh = gp / W_, gw = gp % W_;
                int yy = gh + dy, xx = gw + dx;
                bool vld = (yy >= 0) && (yy < H_) && (xx >= 0) && (xx < W_);
                int ps = gp + delta;
                ps = min(max(ps, 0), HW_ - 1);
                f32x4 g = *(const f32x4*)(xb + (size_t)ps * 64 + chunk * 4);
                unsigned short pk[4];
#pragma unroll
                for (int j = 0; j < 4; j++) pk[j] = vld ? f2bf(g[j]) : (unsigned short)0;
                *(unsigned int*)(A_lds[u] + gpx * 72 + chunk * 4)     = ((unsigned int)pk[1] << 16) | pk[0];
                *(unsigned int*)(A_lds[u] + gpx * 72 + chunk * 4 + 2) = ((unsigned int)pk[3] << 16) | pk[2];
            }
        }
        __syncthreads();  // A visible

#pragma unroll
        for (int u = 0; u < 2; u++) {
            int tap = kk + u;
            if (tap > 8) break;
            const unsigned short* Ab = A_lds[u] + (cb * 16 + mrow) * 72;
#pragma unroll
            for (int ks = 0; ks < 2; ks++) {
                bf16x8 af = *(const bf16x8*)(Ab + ks * 32 + quad * 8);
#pragma unroll
                for (int nt = 0; nt < 2; nt++) {
                    bf16x8 bf_ = *(const bf16x8*)(rwb + tap * 2048 + (nt * 16 + mrow) * 64 + ks * 32 + quad * 8);
                    acc2[nt] = __builtin_amdgcn_mfma_f32_16x16x32_bf16(af, bf_, acc2[nt], 0, 0, 0);
                }
            }
        }
    }

    __syncthreads();
    float* Cl = (float*)A_lds;  // [64 px][28]
#pragma unroll
    for (int nt = 0; nt < 2; nt++) {
        int o = nt * 16 + mrow;
        if (o < 27) {
            int pr = cb * 16 + quad * 4;
#pragma unroll
            for (int r = 0; r < 4; r++) Cl[(pr + r) * 28 + o] = acc2[nt][r];
        }
    }
    __syncthreads();

    for (int k = cb; k < 9; k += 4) {
        float ady = Cl[px * 28 + 2 * k]     + off_b[2 * k];
        float adx = Cl[px * 28 + 2 * k + 1] + off_b[2 * k + 1];
        float am  = Cl[px * 28 + 18 + k]    + off_b[18 + k];
        float sy = (float)(h + k / 3 - 1) + ady;
        float sx = (float)(w + k % 3 - 1) + adx;
        float mk = 1.f / (1.f + __expf(-am));
        float* om = ws + OM_OFF + ((size_t)b * HW_ + p) * 27 + 3 * k;
        om[0] = sy; om[1] = sx; om[2] = mk;
    }
}

// dcn MFMA GEMM (R10-proven): chunk-major coalesced gather, OMs in LDS, inline (idx,wv).
__global__ __launch_bounds__(256) void dcn_mfma_kernel(const float* __restrict__ ws, float* __restrict__ out)
{
    __shared__ __align__(16) unsigned short A_lds[2][64 * 72];  // tap-pair; reused as C float[64][65]
    __shared__ float OMs[64 * 27];

    int tid = threadIdx.x;
    int blk = blockIdx.x;
    int xcd = blk & 7, slot = blk >> 3;
    int b = xcd >> 1;
    int t = (xcd & 1) * 200 + slot;
    int p0 = t * 64;
    int lane = tid & 63, cb = tid >> 6;
    int mrow = lane & 15, quad = lane >> 4;
    int chunk = lane & 15, pxo = lane >> 4;   // gather mapping

    const float* xb  = ws + X_OFF + (size_t)b * HW_ * 64;
    const unsigned short* wtb = (const unsigned short*)(ws + WTB_OFF);
    const float* sb  = ws + SB_OFF + 4 * 128;  // final bn

    // stage om for this block's 64 px
    {
        const float* omg = ws + OM_OFF + ((size_t)b * HW_ + p0) * 27;
        for (int i = tid; i < 64 * 27; i += 256) OMs[i] = omg[i];
    }

    f32x4 acc[4];
#pragma unroll
    for (int nt = 0; nt < 4; nt++) acc[nt] = (f32x4){0.f, 0.f, 0.f, 0.f};

    for (int kk = 0; kk < 9; kk += 2) {
        __syncthreads();  // prev window's A reads done; first iter: OMs staged
#pragma unroll
        for (int u = 0; u < 2; u++) {
            int k = kk + u;
            if (k > 8) break;
#pragma unroll
            for (int r = 0; r < 4; r++) {
                int gpx = cb * 16 + r * 4 + pxo;   // pixel this lane serves
                float sy = OMs[gpx * 27 + 3 * k];
                float sx = OMs[gpx * 27 + 3 * k + 1];
                float mk = OMs[gpx * 27 + 3 * k + 2];
                float y0f = floorf(sy), x0f = floorf(sx);
                int y0 = (int)y0f, x0 = (int)x0f;
                float ty = sy - y0f, tx = sx - x0f;
                f32x4 v = (f32x4){0.f, 0.f, 0.f, 0.f};
#pragma unroll
                for (int cr = 0; cr < 4; cr++) {
                    int dy = cr >> 1, dx = cr & 1;
                    int yy = y0 + dy, xx = x0 + dx;
                    float wy = dy ? ty : 1.f - ty;
                    float wx = dx ? tx : 1.f - tx;
                    bool vld = (yy >= 0) && (yy < H_) && (xx >= 0) && (xx < W_);
                    int yc = min(max(yy, 0), H_ - 1);
                    int xc = min(max(xx, 0), W_ - 1);
                    float wv = vld ? wy * wx * mk : 0.f;
                    f32x4 g = *(const f32x4*)(xb + (size_t)(yc * W_ + xc) * 64 + chunk * 4);
#pragma unroll
                    for (int j = 0; j < 4; j++) v[j] = fmaf(g[j], wv, v[j]);
                }
                unsigned short pk[4];
#pragma unroll
                for (int j = 0; j < 4; j++) pk[j] = f2bf(v[j]);
                *(unsigned int*)(A_lds[u] + gpx * 72 + chunk * 4)     = ((unsigned int)pk[1] << 16) | pk[0];
                *(unsigned int*)(A_lds[u] + gpx * 72 + chunk * 4 + 2) = ((unsigned int)pk[3] << 16) | pk[2];
            }
        }
        __syncthreads();  // A visible

#pragma unroll
        for (int u = 0; u < 2; u++) {
            int k = kk + u;
            if (k > 8) break;
            const unsigned short* Ab = A_lds[u] + (cb * 16 + mrow) * 72;
#pragma unroll
            for (int ks = 0; ks < 2; ks++) {
                bf16x8 af = *(const bf16x8*)(Ab + ks * 32 + quad * 8);
#pragma unroll
                for (int nt = 0; nt < 4; nt++) {
                    bf16x8 bf_ = *(const bf16x8*)(wtb + k * 4608 + (nt * 16 + mrow) * 72 + ks * 32 + quad * 8);
                    acc[nt] = __builtin_amdgcn_mfma_f32_16x16x32_bf16(af, bf_, acc[nt], 0, 0, 0);
                }
            }
        }
    }

    // epilogue: C frag -> LDS [o][px pad65] -> NCHW store
    __syncthreads();
    float* C_lds = (float*)A_lds;
#pragma unroll
    for (int nt = 0; nt < 4; nt++) {
        int o = nt * 16 + mrow;
        int pxb = cb * 16 + quad * 4;
#pragma unroll
        for (int r = 0; r < 4; r++) C_lds[o * 65 + pxb + r] = acc[nt][r];
    }
    __syncthreads();
#pragma unroll
    for (int i = 0; i < 16; i++) {
        int o = cb * 16 + i;
        float v = C_lds[o * 65 + lane];
        v = fmaf(v, sb[o], sb[64 + o]);
        out[((size_t)b * 64 + o) * HW_ + p0 + lane] = fmaxf(v, 0.f);
    }
}

extern "C" void kernel_launch(void* const* d_in, const int* in_sizes, int n_in,
                              void* d_out, int out_size, void* d_ws, size_t ws_size,
                              hipStream_t stream)
{
    const float* f0 = (const float*)d_in[0];
    const float* f1 = (const float*)d_in[1];
    const float* f2 = (const float*)d_in[2];
    const float* f3 = (const float*)d_in[3];
    const float* w0 = (const float*)d_in[4];
    const float* g0 = (const float*)d_in[5];
    const float* b0 = (const float*)d_in[6];
    const float* m0 = (const float*)d_in[7];
    const float* v0 = (const float*)d_in[8];
    const float* w1 = (const float*)d_in[9];
    const float* g1 = (const float*)d_in[10];
    const float* b1 = (const float*)d_in[11];
    const float* m1 = (const float*)d_in[12];
    const float* v1 = (const float*)d_in[13];
    const float* w2 = (const float*)d_in[14];
    const float* g2 = (const float*)d_in[15];
    const float* b2 = (const float*)d_in[16];
    const float* m2 = (const float*)d_in[17];
    const float* v2 = (const float*)d_in[18];
    const float* w3 = (const float*)d_in[19];
    const float* g3 = (const float*)d_in[20];
    const float* b3 = (const float*)d_in[21];
    const float* m3 = (const float*)d_in[22];
    const float* v3 = (const float*)d_in[23];
    const float* off_w = (const float*)d_in[24];
    const float* off_b = (const float*)d_in[25];
    const float* dcn_w = (const float*)d_in[26];
    const float* gf = (const float*)d_in[27];
    const float* bf = (const float*)d_in[28];
    const float* mf = (const float*)d_in[29];
    const float* vf = (const float*)d_in[30];

    float* ws  = (float*)d_ws;
    float* out = (float*)d_out;

    prep_kernel<<<dim3(476), dim3(256), 0, stream>>>(
        g0, b0, m0, v0, g1, b1, m1, v1, g2, b2, m2, v2, g3, b3, m3, v3,
        gf, bf, mf, vf, w0, w1, w2, w3, dcn_w, off_w, ws);

    conv1x1_bn_kernel<<<dim3(6400), dim3(256), 0, stream>>>(f1, ws + WR1_OFF, ws + SB_OFF + 128, ws + Y1_OFF, 128, 6400);
    conv1x1_bn_kernel<<<dim3(1600), dim3(256), 0, stream>>>(f2, ws + WR2_OFF, ws + SB_OFF + 256, ws + Y2_OFF, 256, 1600);
    conv1x1_bn_kernel<<<dim3(400),  dim3(256), 0, stream>>>(f3, ws + WR3_OFF, ws + SB_OFF + 384, ws + Y3_OFF, 512, 400);

    fuse_kernel<<<dim3(1600), dim3(256), 0, stream>>>(f0, ws);

    offconv_mfma_kernel<<<dim3(1600), dim3(256), 0, stream>>>(off_b, ws);

    dcn_mfma_kernel<<<dim3(1600), dim3(256), 0, stream>>>(ws, out);
}

// Round 14
// 353.837 us; speedup vs baseline: 2.2125x; 1.0254x over previous
//
#include <hip/hip_runtime.h>
#include <math.h>

#define EPSB 1e-5f

constexpr int B_ = 4;
constexpr int C_ = 64;
constexpr int H_ = 160;
constexpr int W_ = 160;
constexpr int HW_ = H_ * W_;

// workspace layout (float offsets) — total 11,503,488 floats = 46.01 MB
constexpr size_t X_OFF   = 0;                                    // x NHWC: [b][p][64]
constexpr size_t Y1_OFF  = X_OFF  + (size_t)B_ * HW_ * 64;       // y1 NHWC @80x80
constexpr size_t Y2_OFF  = Y1_OFF + (size_t)B_ * 6400 * 64;      // y2 NHWC @40x40
constexpr size_t Y3_OFF  = Y2_OFF + (size_t)B_ * 1600 * 64;      // y3 NHWC @20x20
constexpr size_t OM_OFF  = Y3_OFF + (size_t)B_ * 400 * 64;       // om: [b][p][27] (sy,sx,mk)*9
constexpr size_t WR0_OFF = OM_OFF + (size_t)B_ * HW_ * 27;       // w0 fp32 [ci][o]: 4096
constexpr size_t WTB_OFF = WR0_OFF + 4096;                       // dcn_w bf16 [k][o][c pad72]: 41472 ush
constexpr size_t RWB_OFF = WTB_OFF + (9 * 64 * 72) / 2;          // off_w bf16 [tap][o pad32][ci]: 18432 ush
constexpr size_t SB_OFF  = RWB_OFF + (9 * 32 * 64) / 2;          // 5 BNs x (scale[64], bias[64])
// transposed conv1x1 weights OVERLAID at head of X region (die before fuse writes x).
constexpr size_t WR1_OFF = X_OFF + 0;       // w1 fp32 [ci][o]
constexpr size_t WR2_OFF = X_OFF + 8192;    // w2 fp32 [ci][o]
constexpr size_t WR3_OFF = X_OFF + 24576;   // w3 fp32 [ci][o]

typedef short bf16x8 __attribute__((ext_vector_type(8)));
typedef float f32x4 __attribute__((ext_vector_type(4)));

static __device__ __forceinline__ unsigned short f2bf(float f) {
    unsigned int u = __float_as_uint(f);
    u += 0x7fff + ((u >> 16) & 1);   // RNE
    return (unsigned short)(u >> 16);
}

__global__ __launch_bounds__(256) void prep_kernel(
    const float* __restrict__ g0, const float* __restrict__ b0, const float* __restrict__ m0, const float* __restrict__ v0,
    const float* __restrict__ g1, const float* __restrict__ b1, const float* __restrict__ m1, const float* __restrict__ v1,
    const float* __restrict__ g2, const float* __restrict__ b2, const float* __restrict__ m2, const float* __restrict__ v2,
    const float* __restrict__ g3, const float* __restrict__ b3, const float* __restrict__ m3, const float* __restrict__ v3,
    const float* __restrict__ gf, const float* __restrict__ bf, const float* __restrict__ mf, const float* __restrict__ vf,
    const float* __restrict__ w0, const float* __restrict__ w1, const float* __restrict__ w2, const float* __restrict__ w3,
    const float* __restrict__ dcn_w, const float* __restrict__ off_w,
    float* __restrict__ ws)
{
    int tid = blockIdx.x * 256 + threadIdx.x;
    if (tid < 320) {  // BN scale/bias fold
        int j = tid >> 6, c = tid & 63;
        const float *g, *b, *m, *v;
        switch (j) {
            case 0: g = g0; b = b0; m = m0; v = v0; break;
            case 1: g = g1; b = b1; m = m1; v = v1; break;
            case 2: g = g2; b = b2; m = m2; v = v2; break;
            case 3: g = g3; b = b3; m = m3; v = v3; break;
            default: g = gf; b = bf; m = mf; v = vf; break;
        }
        float sc = g[c] * rsqrtf(v[c] + EPSB);
        ws[SB_OFF + j * 128 + c]      = sc;
        ws[SB_OFF + j * 128 + 64 + c] = b[c] - m[c] * sc;
        return;
    }
    int t = tid - 320;
    if (t < 4096) {  // wr0[ci*64+o] = w0[o*64+ci]
        int ci = t >> 6, o = t & 63;
        ws[WR0_OFF + t] = w0[o * 64 + ci];
        return;
    }
    t -= 4096;
    if (t < 9 * 64 * 72) {  // wtb[k][o][c pad72] bf16 = dcn_w[o][c][k]
        int k = t / 4608, r = t % 4608, o = r / 72, c = r % 72;
        float v = (c < 64) ? dcn_w[o * 576 + c * 9 + k] : 0.f;
        ((unsigned short*)(ws + WTB_OFF))[t] = f2bf(v);
        return;
    }
    t -= 9 * 64 * 72;
    if (t < 9 * 32 * 64) {  // rwb[tap][o pad32][ci] bf16 = off_w[o][ci][tap]
        int tap = t >> 11, r = t & 2047, o = r >> 6, ci = r & 63;
        float v = (o < 27) ? off_w[o * 576 + ci * 9 + tap] : 0.f;
        ((unsigned short*)(ws + RWB_OFF))[t] = f2bf(v);
        return;
    }
    t -= 9 * 32 * 64;
    if (t < 8192) {  // wr1[ci*64+o] = w1[o*128+ci]
        int ci = t >> 6, o = t & 63;
        ws[WR1_OFF + t] = w1[o * 128 + ci];
        return;
    }
    t -= 8192;
    if (t < 16384) {  // wr2
        int ci = t >> 6, o = t & 63;
        ws[WR2_OFF + t] = w2[o * 256 + ci];
        return;
    }
    t -= 16384;
    if (t < 32768) {  // wr3
        int ci = t >> 6, o = t & 63;
        ws[WR3_OFF + t] = w3[o * 512 + ci];
        return;
    }
}

// wave = one (b,p); lanes = 64 output channels; weights [ci][o] -> coalesced. NHWC out. XCD-affine.
__global__ __launch_bounds__(256) void conv1x1_bn_kernel(
    const float* __restrict__ f, const float* __restrict__ wr,
    const float* __restrict__ sb, float* __restrict__ out, int Cin, int hw)
{
    int xcd = blockIdx.x & 7, slot = blockIdx.x >> 3;
    int b = xcd >> 1;
    int g = (xcd & 1) * (hw >> 3) + slot;
    int o = threadIdx.x & 63;
    int p = g * 4 + (threadIdx.x >> 6);
    p = __builtin_amdgcn_readfirstlane(p);
    b = __builtin_amdgcn_readfirstlane(b);
    const float* fb = f + (size_t)b * Cin * hw + p;
    float acc = 0.f;
#pragma unroll 8
    for (int ci = 0; ci < Cin; ++ci) acc = fmaf(fb[(size_t)ci * hw], wr[ci * 64 + o], acc);
    out[((size_t)b * hw + p) * 64 + o] = fmaf(acc, sb[o], sb[64 + o]);
}

// fuse v4: scalar (wave-uniform) weight loads + batched-in-flight global loads.
// phase-1 per-px fp32 conv+BN -> Ot (LDS); phase-2 chunk-major upsample+relu+store.
__global__ __launch_bounds__(256) void fuse_kernel(const float* __restrict__ f0, float* __restrict__ ws)
{
    __shared__ float Ot[64 * 68];    // [px][ch pad 68] 17.4 KB

    int tid = threadIdx.x;
    int blk = blockIdx.x;
    int xcd = blk & 7, slot = blk >> 3;
    int b = xcd >> 1;
    int t = (xcd & 1) * 200 + slot;
    int p0 = t * 64;
    int lane = tid & 63;
    int cb = __builtin_amdgcn_readfirstlane(tid >> 6);   // wave-uniform -> scalar weight addressing
    int p = p0 + lane;
    const float* wr0 = ws + WR0_OFF + cb * 16;
    const float* sb  = ws + SB_OFF;  // bn0

    // phase 1: conv1x1(f0)+bn; f0 loads batched x8, weights via scalar loads
    {
        float acc[16];
#pragma unroll
        for (int i = 0; i < 16; i++) acc[i] = 0.f;

        const float* f0b = f0 + (size_t)b * 64 * HW_ + p;
        for (int ci0 = 0; ci0 < 64; ci0 += 8) {
            float fv[8];
#pragma unroll
            for (int j = 0; j < 8; j++) fv[j] = f0b[(size_t)(ci0 + j) * HW_];
#pragma unroll
            for (int j = 0; j < 8; j++) {
                const float* wrow = wr0 + (ci0 + j) * 64;
#pragma unroll
                for (int i = 0; i < 16; i++) acc[i] = fmaf(fv[j], wrow[i], acc[i]);
            }
        }
        float* orow = Ot + lane * 68 + cb * 16;
#pragma unroll
        for (int i = 0; i < 16; i++) {
            int o = cb * 16 + i;
            orow[i] = fmaf(acc[i], sb[o], sb[64 + o]);
        }
    }
    __syncthreads();

    // phase 2: chunk-major upsample + relu + store; all 12 corner loads hoisted per px
    {
        int chunk = lane & 15, pxo = lane >> 4;
        float* xb = ws + X_OFF + ((size_t)b * HW_ + p0) * 64;
#pragma unroll
        for (int r = 0; r < 4; r++) {
            int gpx = cb * 16 + r * 4 + pxo;
            int gp = p0 + gpx;
            int h = gp / W_, w = gp % W_;

            float fy1 = h * (79.f / 159.f); int i1 = (int)fy1; if (i1 > 78) i1 = 78; float ty1 = fy1 - i1;
            float fx1 = w * (79.f / 159.f); int j1 = (int)fx1; if (j1 > 78) j1 = 78; float tx1 = fx1 - j1;
            const float* y1 = ws + Y1_OFF + ((size_t)b * 6400 + (size_t)(i1 * 80 + j1)) * 64 + chunk * 4;
            float fy2 = h * (39.f / 159.f); int i2 = (int)fy2; if (i2 > 38) i2 = 38; float ty2 = fy2 - i2;
            float fx2 = w * (39.f / 159.f); int j2 = (int)fx2; if (j2 > 38) j2 = 38; float tx2 = fx2 - j2;
            const float* y2 = ws + Y2_OFF + ((size_t)b * 1600 + (size_t)(i2 * 40 + j2)) * 64 + chunk * 4;
            float fy3 = h * (19.f / 159.f); int i3 = (int)fy3; if (i3 > 18) i3 = 18; float ty3 = fy3 - i3;
            float fx3 = w * (19.f / 159.f); int j3 = (int)fx3; if (j3 > 18) j3 = 18; float tx3 = fx3 - j3;
            const float* y3 = ws + Y3_OFF + ((size_t)b * 400 + (size_t)(i3 * 20 + j3)) * 64 + chunk * 4;

            f32x4 A[12];
            A[0]  = *(const f32x4*)(y1);
            A[1]  = *(const f32x4*)(y1 + 64);
            A[2]  = *(const f32x4*)(y1 + 80 * 64);
            A[3]  = *(const f32x4*)(y1 + 81 * 64);
            A[4]  = *(const f32x4*)(y2);
            A[5]  = *(const f32x4*)(y2 + 64);
            A[6]  = *(const f32x4*)(y2 + 40 * 64);
            A[7]  = *(const f32x4*)(y2 + 41 * 64);
            A[8]  = *(const f32x4*)(y3);
            A[9]  = *(const f32x4*)(y3 + 64);
            A[10] = *(const f32x4*)(y3 + 20 * 64);
            A[11] = *(const f32x4*)(y3 + 21 * 64);

            f32x4 v = *(const f32x4*)(Ot + gpx * 68 + chunk * 4);

            float w00, w01, w10, w11;
            w00 = (1.f - ty1) * (1.f - tx1); w01 = (1.f - ty1) * tx1; w10 = ty1 * (1.f - tx1); w11 = ty1 * tx1;
#pragma unroll
            for (int j = 0; j < 4; j++)
                v[j] += A[0][j] * w00 + A[1][j] * w01 + A[2][j] * w10 + A[3][j] * w11;
            w00 = (1.f - ty2) * (1.f - tx2); w01 = (1.f - ty2) * tx2; w10 = ty2 * (1.f - tx2); w11 = ty2 * tx2;
#pragma unroll
            for (int j = 0; j < 4; j++)
                v[j] += A[4][j] * w00 + A[5][j] * w01 + A[6][j] * w10 + A[7][j] * w11;
            w00 = (1.f - ty3) * (1.f - tx3); w01 = (1.f - ty3) * tx3; w10 = ty3 * (1.f - tx3); w11 = ty3 * tx3;
#pragma unroll
            for (int j = 0; j < 4; j++)
                v[j] += A[8][j] * w00 + A[9][j] * w01 + A[10][j] * w10 + A[11][j] * w11;

#pragma unroll
            for (int j = 0; j < 4; j++) v[j] = fmaxf(v[j], 0.f);
            *(f32x4*)(xb + (size_t)gpx * 64 + chunk * 4) = v;
        }
    }
}

// offconv MFMA GEMM: chunk-major gather with all 4 loads hoisted per tap.
// 2 taps per barrier window, B fragments direct from global. Writes om[b][p][27].
__global__ __launch_bounds__(256) void offconv_mfma_kernel(const float* __restrict__ off_b, float* __restrict__ ws)
{
    __shared__ __align__(16) unsigned short A_lds[2][64 * 72];   // tap-pair; reused as C float[64][28]

    int tid = threadIdx.x;
    int blk = blockIdx.x;
    int xcd = blk & 7, slot = blk >> 3;
    int b = xcd >> 1;
    int t = (xcd & 1) * 200 + slot;
    int p0 = t * 64;
    int lane = tid & 63, cb = tid >> 6;
    int px = lane;
    int p = p0 + px;
    int h = p / W_, w = p % W_;
    int mrow = lane & 15, quad = lane >> 4;
    int chunk = lane & 15, pxo = lane >> 4;   // gather mapping

    const unsigned short* rwb = (const unsigned short*)(ws + RWB_OFF);
    const float* xb = ws + X_OFF + (size_t)b * HW_ * 64;

    f32x4 acc2[2];
    acc2[0] = (f32x4){0.f, 0.f, 0.f, 0.f};
    acc2[1] = (f32x4){0.f, 0.f, 0.f, 0.f};

    for (int kk = 0; kk < 9; kk += 2) {
        __syncthreads();  // prev window's A reads done
#pragma unroll
        for (int u = 0; u < 2; u++) {
            int tap = kk + u;
            if (tap > 8) break;
            int dy = tap / 3 - 1, dx = tap % 3 - 1;
            int delta = dy * W_ + dx;
            // metadata for all 4 pixels first
            int  pss[4];
            bool vlds[4];
#pragma unroll
            for (int r = 0; r < 4; r++) {
                int gpx = cb * 16 + r * 4 + pxo;
                int gp = p0 + gpx;
                int gh = gp / W_, gw = gp % W_;
                int yy = gh + dy, xx = gw + dx;
                vlds[r] = (yy >= 0) && (yy < H_) && (xx >= 0) && (xx < W_);
                int ps = gp + delta;
                pss[r] = min(max(ps, 0), HW_ - 1);
            }
            // all 4 loads in flight
            f32x4 g[4];
#pragma unroll
            for (int r = 0; r < 4; r++)
                g[r] = *(const f32x4*)(xb + (size_t)pss[r] * 64 + chunk * 4);
            // pack + LDS store
#pragma unroll
            for (int r = 0; r < 4; r++) {
                int gpx = cb * 16 + r * 4 + pxo;
                unsigned short pk[4];
#pragma unroll
                for (int j = 0; j < 4; j++) pk[j] = vlds[r] ? f2bf(g[r][j]) : (unsigned short)0;
                *(unsigned int*)(A_lds[u] + gpx * 72 + chunk * 4)     = ((unsigned int)pk[1] << 16) | pk[0];
                *(unsigned int*)(A_lds[u] + gpx * 72 + chunk * 4 + 2) = ((unsigned int)pk[3] << 16) | pk[2];
            }
        }
        __syncthreads();  // A visible

#pragma unroll
        for (int u = 0; u < 2; u++) {
            int tap = kk + u;
            if (tap > 8) break;
            const unsigned short* Ab = A_lds[u] + (cb * 16 + mrow) * 72;
#pragma unroll
            for (int ks = 0; ks < 2; ks++) {
                bf16x8 af = *(const bf16x8*)(Ab + ks * 32 + quad * 8);
#pragma unroll
                for (int nt = 0; nt < 2; nt++) {
                    bf16x8 bf_ = *(const bf16x8*)(rwb + tap * 2048 + (nt * 16 + mrow) * 64 + ks * 32 + quad * 8);
                    acc2[nt] = __builtin_amdgcn_mfma_f32_16x16x32_bf16(af, bf_, acc2[nt], 0, 0, 0);
                }
            }
        }
    }

    __syncthreads();
    float* Cl = (float*)A_lds;  // [64 px][28]
#pragma unroll
    for (int nt = 0; nt < 2; nt++) {
        int o = nt * 16 + mrow;
        if (o < 27) {
            int pr = cb * 16 + quad * 4;
#pragma unroll
            for (int r = 0; r < 4; r++) Cl[(pr + r) * 28 + o] = acc2[nt][r];
        }
    }
    __syncthreads();

    for (int k = cb; k < 9; k += 4) {
        float ady = Cl[px * 28 + 2 * k]     + off_b[2 * k];
        float adx = Cl[px * 28 + 2 * k + 1] + off_b[2 * k + 1];
        float am  = Cl[px * 28 + 18 + k]    + off_b[18 + k];
        float sy = (float)(h + k / 3 - 1) + ady;
        float sx = (float)(w + k % 3 - 1) + adx;
        float mk = 1.f / (1.f + __expf(-am));
        float* om = ws + OM_OFF + ((size_t)b * HW_ + p) * 27 + 3 * k;
        om[0] = sy; om[1] = sx; om[2] = mk;
    }
}

// dcn MFMA GEMM: chunk-major gather with all 16 loads hoisted per tap (latency hiding),
// OMs in LDS, inline (idx,wv). Math order bit-identical to R13.
__global__ __launch_bounds__(256) void dcn_mfma_kernel(const float* __restrict__ ws, float* __restrict__ out)
{
    __shared__ __align__(16) unsigned short A_lds[2][64 * 72];  // tap-pair; reused as C float[64][65]
    __shared__ float OMs[64 * 27];

    int tid = threadIdx.x;
    int blk = blockIdx.x;
    int xcd = blk & 7, slot = blk >> 3;
    int b = xcd >> 1;
    int t = (xcd & 1) * 200 + slot;
    int p0 = t * 64;
    int lane = tid & 63, cb = tid >> 6;
    int mrow = lane & 15, quad = lane >> 4;
    int chunk = lane & 15, pxo = lane >> 4;   // gather mapping

    const float* xb  = ws + X_OFF + (size_t)b * HW_ * 64;
    const unsigned short* wtb = (const unsigned short*)(ws + WTB_OFF);
    const float* sb  = ws + SB_OFF + 4 * 128;  // final bn

    // stage om for this block's 64 px
    {
        const float* omg = ws + OM_OFF + ((size_t)b * HW_ + p0) * 27;
        for (int i = tid; i < 64 * 27; i += 256) OMs[i] = omg[i];
    }

    f32x4 acc[4];
#pragma unroll
    for (int nt = 0; nt < 4; nt++) acc[nt] = (f32x4){0.f, 0.f, 0.f, 0.f};

    for (int kk = 0; kk < 9; kk += 2) {
        __syncthreads();  // prev window's A reads done; first iter: OMs staged
#pragma unroll
        for (int u = 0; u < 2; u++) {
            int k = kk + u;
            if (k > 8) break;
            // metadata for all 4 px x 4 corners
            int   idxs[4][4];
            float wvs[4][4];
#pragma unroll
            for (int r = 0; r < 4; r++) {
                int gpx = cb * 16 + r * 4 + pxo;
                float sy = OMs[gpx * 27 + 3 * k];
                float sx = OMs[gpx * 27 + 3 * k + 1];
                float mk = OMs[gpx * 27 + 3 * k + 2];
                float y0f = floorf(sy), x0f = floorf(sx);
                int y0 = (int)y0f, x0 = (int)x0f;
                float ty = sy - y0f, tx = sx - x0f;
#pragma unroll
                for (int cr = 0; cr < 4; cr++) {
                    int dy = cr >> 1, dx = cr & 1;
                    int yy = y0 + dy, xx = x0 + dx;
                    float wy = dy ? ty : 1.f - ty;
                    float wx = dx ? tx : 1.f - tx;
                    bool vld = (yy >= 0) && (yy < H_) && (xx >= 0) && (xx < W_);
                    int yc = min(max(yy, 0), H_ - 1);
                    int xc = min(max(xx, 0), W_ - 1);
                    idxs[r][cr] = yc * W_ + xc;
                    wvs[r][cr]  = vld ? wy * wx * mk : 0.f;
                }
            }
            // all 16 loads in flight
            f32x4 g[4][4];
#pragma unroll
            for (int r = 0; r < 4; r++)
#pragma unroll
                for (int cr = 0; cr < 4; cr++)
                    g[r][cr] = *(const f32x4*)(xb + (size_t)idxs[r][cr] * 64 + chunk * 4);
            // weight + pack + LDS store (same accumulation order as before)
#pragma unroll
            for (int r = 0; r < 4; r++) {
                int gpx = cb * 16 + r * 4 + pxo;
                f32x4 v = (f32x4){0.f, 0.f, 0.f, 0.f};
#pragma unroll
                for (int cr = 0; cr < 4; cr++) {
                    float wv = wvs[r][cr];
#pragma unroll
                    for (int j = 0; j < 4; j++) v[j] = fmaf(g[r][cr][j], wv, v[j]);
                }
                unsigned short pk[4];
#pragma unroll
                for (int j = 0; j < 4; j++) pk[j] = f2bf(v[j]);
                *(unsigned int*)(A_lds[u] + gpx * 72 + chunk * 4)     = ((unsigned int)pk[1] << 16) | pk[0];
                *(unsigned int*)(A_lds[u] + gpx * 72 + chunk * 4 + 2) = ((unsigned int)pk[3] << 16) | pk[2];
            }
        }
        __syncthreads();  // A visible

#pragma unroll
        for (int u = 0; u < 2; u++) {
            int k = kk + u;
            if (k > 8) break;
            const unsigned short* Ab = A_lds[u] + (cb * 16 + mrow) * 72;
#pragma unroll
            for (int ks = 0; ks < 2; ks++) {
                bf16x8 af = *(const bf16x8*)(Ab + ks * 32 + quad * 8);
#pragma unroll
                for (int nt = 0; nt < 4; nt++) {
                    bf16x8 bf_ = *(const bf16x8*)(wtb + k * 4608 + (nt * 16 + mrow) * 72 + ks * 32 + quad * 8);
                    acc[nt] = __builtin_amdgcn_mfma_f32_16x16x32_bf16(af, bf_, acc[nt], 0, 0, 0);
                }
            }
        }
    }

    // epilogue: C frag -> LDS [o][px pad65] -> NCHW store
    __syncthreads();
    float* C_lds = (float*)A_lds;
#pragma unroll
    for (int nt = 0; nt < 4; nt++) {
        int o = nt * 16 + mrow;
        int pxb = cb * 16 + quad * 4;
#pragma unroll
        for (int r = 0; r < 4; r++) C_lds[o * 65 + pxb + r] = acc[nt][r];
    }
    __syncthreads();
#pragma unroll
    for (int i = 0; i < 16; i++) {
        int o = cb * 16 + i;
        float v = C_lds[o * 65 + lane];
        v = fmaf(v, sb[o], sb[64 + o]);
        out[((size_t)b * 64 + o) * HW_ + p0 + lane] = fmaxf(v, 0.f);
    }
}

extern "C" void kernel_launch(void* const* d_in, const int* in_sizes, int n_in,
                              void* d_out, int out_size, void* d_ws, size_t ws_size,
                              hipStream_t stream)
{
    const float* f0 = (const float*)d_in[0];
    const float* f1 = (const float*)d_in[1];
    const float* f2 = (const float*)d_in[2];
    const float* f3 = (const float*)d_in[3];
    const float* w0 = (const float*)d_in[4];
    const float* g0 = (const float*)d_in[5];
    const float* b0 = (const float*)d_in[6];
    const float* m0 = (const float*)d_in[7];
    const float* v0 = (const float*)d_in[8];
    const float* w1 = (const float*)d_in[9];
    const float* g1 = (const float*)d_in[10];
    const float* b1 = (const float*)d_in[11];
    const float* m1 = (const float*)d_in[12];
    const float* v1 = (const float*)d_in[13];
    const float* w2 = (const float*)d_in[14];
    const float* g2 = (const float*)d_in[15];
    const float* b2 = (const float*)d_in[16];
    const float* m2 = (const float*)d_in[17];
    const float* v2 = (const float*)d_in[18];
    const float* w3 = (const float*)d_in[19];
    const float* g3 = (const float*)d_in[20];
    const float* b3 = (const float*)d_in[21];
    const float* m3 = (const float*)d_in[22];
    const float* v3 = (const float*)d_in[23];
    const float* off_w = (const float*)d_in[24];
    const float* off_b = (const float*)d_in[25];
    const float* dcn_w = (const float*)d_in[26];
    const float* gf = (const float*)d_in[27];
    const float* bf = (const float*)d_in[28];
    const float* mf = (const float*)d_in[29];
    const float* vf = (const float*)d_in[30];

    float* ws  = (float*)d_ws;
    float* out = (float*)d_out;

    prep_kernel<<<dim3(476), dim3(256), 0, stream>>>(
        g0, b0, m0, v0, g1, b1, m1, v1, g2, b2, m2, v2, g3, b3, m3, v3,
        gf, bf, mf, vf, w0, w1, w2, w3, dcn_w, off_w, ws);

    conv1x1_bn_kernel<<<dim3(6400), dim3(256), 0, stream>>>(f1, ws + WR1_OFF, ws + SB_OFF + 128, ws + Y1_OFF, 128, 6400);
    conv1x1_bn_kernel<<<dim3(1600), dim3(256), 0, stream>>>(f2, ws + WR2_OFF, ws + SB_OFF + 256, ws + Y2_OFF, 256, 1600);
    conv1x1_bn_kernel<<<dim3(400),  dim3(256), 0, stream>>>(f3, ws + WR3_OFF, ws + SB_OFF + 384, ws + Y3_OFF, 512, 400);

    fuse_kernel<<<dim3(1600), dim3(256), 0, stream>>>(f0, ws);

    offconv_mfma_kernel<<<dim3(1600), dim3(256), 0, stream>>>(off_b, ws);

    dcn_mfma_kernel<<<dim3(1600), dim3(256), 0, stream>>>(ws, out);
}

// Round 15
// 345.349 us; speedup vs baseline: 2.2669x; 1.0246x over previous
//
#include <hip/hip_runtime.h>
#include <math.h>

#define EPSB 1e-5f

constexpr int B_ = 4;
constexpr int C_ = 64;
constexpr int H_ = 160;
constexpr int W_ = 160;
constexpr int HW_ = H_ * W_;

// workspace layout (float offsets) — total 11,503,488 floats = 46.01 MB
constexpr size_t X_OFF   = 0;                                    // x NHWC: [b][p][64]
constexpr size_t Y1_OFF  = X_OFF  + (size_t)B_ * HW_ * 64;       // y1 NHWC @80x80
constexpr size_t Y2_OFF  = Y1_OFF + (size_t)B_ * 6400 * 64;      // y2 NHWC @40x40
constexpr size_t Y3_OFF  = Y2_OFF + (size_t)B_ * 1600 * 64;      // y3 NHWC @20x20
constexpr size_t OM_OFF  = Y3_OFF + (size_t)B_ * 400 * 64;       // om: [b][p][27] (sy,sx,mk)*9
constexpr size_t WR0_OFF = OM_OFF + (size_t)B_ * HW_ * 27;       // w0 fp32 [ci][o]: 4096
constexpr size_t WTB_OFF = WR0_OFF + 4096;                       // dcn_w bf16 [k][o][c pad72]: 41472 ush
constexpr size_t RWB_OFF = WTB_OFF + (9 * 64 * 72) / 2;          // off_w bf16 [tap][o pad32][ci]: 18432 ush
constexpr size_t SB_OFF  = RWB_OFF + (9 * 32 * 64) / 2;          // 5 BNs x (scale[64], bias[64])
// transposed conv1x1 weights OVERLAID at head of X region (die before fuse writes x).
constexpr size_t WR1_OFF = X_OFF + 0;       // w1 fp32 [ci][o]
constexpr size_t WR2_OFF = X_OFF + 8192;    // w2 fp32 [ci][o]
constexpr size_t WR3_OFF = X_OFF + 24576;   // w3 fp32 [ci][o]

typedef short bf16x8 __attribute__((ext_vector_type(8)));
typedef float f32x4 __attribute__((ext_vector_type(4)));

static __device__ __forceinline__ unsigned short f2bf(float f) {
    unsigned int u = __float_as_uint(f);
    u += 0x7fff + ((u >> 16) & 1);   // RNE
    return (unsigned short)(u >> 16);
}

__global__ __launch_bounds__(256) void prep_kernel(
    const float* __restrict__ g0, const float* __restrict__ b0, const float* __restrict__ m0, const float* __restrict__ v0,
    const float* __restrict__ g1, const float* __restrict__ b1, const float* __restrict__ m1, const float* __restrict__ v1,
    const float* __restrict__ g2, const float* __restrict__ b2, const float* __restrict__ m2, const float* __restrict__ v2,
    const float* __restrict__ g3, const float* __restrict__ b3, const float* __restrict__ m3, const float* __restrict__ v3,
    const float* __restrict__ gf, const float* __restrict__ bf, const float* __restrict__ mf, const float* __restrict__ vf,
    const float* __restrict__ w0, const float* __restrict__ w1, const float* __restrict__ w2, const float* __restrict__ w3,
    const float* __restrict__ dcn_w, const float* __restrict__ off_w,
    float* __restrict__ ws)
{
    int tid = blockIdx.x * 256 + threadIdx.x;
    if (tid < 320) {  // BN scale/bias fold
        int j = tid >> 6, c = tid & 63;
        const float *g, *b, *m, *v;
        switch (j) {
            case 0: g = g0; b = b0; m = m0; v = v0; break;
            case 1: g = g1; b = b1; m = m1; v = v1; break;
            case 2: g = g2; b = b2; m = m2; v = v2; break;
            case 3: g = g3; b = b3; m = m3; v = v3; break;
            default: g = gf; b = bf; m = mf; v = vf; break;
        }
        float sc = g[c] * rsqrtf(v[c] + EPSB);
        ws[SB_OFF + j * 128 + c]      = sc;
        ws[SB_OFF + j * 128 + 64 + c] = b[c] - m[c] * sc;
        return;
    }
    int t = tid - 320;
    if (t < 4096) {  // wr0[ci*64+o] = w0[o*64+ci]
        int ci = t >> 6, o = t & 63;
        ws[WR0_OFF + t] = w0[o * 64 + ci];
        return;
    }
    t -= 4096;
    if (t < 9 * 64 * 72) {  // wtb[k][o][c pad72] bf16 = dcn_w[o][c][k]
        int k = t / 4608, r = t % 4608, o = r / 72, c = r % 72;
        float v = (c < 64) ? dcn_w[o * 576 + c * 9 + k] : 0.f;
        ((unsigned short*)(ws + WTB_OFF))[t] = f2bf(v);
        return;
    }
    t -= 9 * 64 * 72;
    if (t < 9 * 32 * 64) {  // rwb[tap][o pad32][ci] bf16 = off_w[o][ci][tap]
        int tap = t >> 11, r = t & 2047, o = r >> 6, ci = r & 63;
        float v = (o < 27) ? off_w[o * 576 + ci * 9 + tap] : 0.f;
        ((unsigned short*)(ws + RWB_OFF))[t] = f2bf(v);
        return;
    }
    t -= 9 * 32 * 64;
    if (t < 8192) {  // wr1[ci*64+o] = w1[o*128+ci]
        int ci = t >> 6, o = t & 63;
        ws[WR1_OFF + t] = w1[o * 128 + ci];
        return;
    }
    t -= 8192;
    if (t < 16384) {  // wr2
        int ci = t >> 6, o = t & 63;
        ws[WR2_OFF + t] = w2[o * 256 + ci];
        return;
    }
    t -= 16384;
    if (t < 32768) {  // wr3
        int ci = t >> 6, o = t & 63;
        ws[WR3_OFF + t] = w3[o * 512 + ci];
        return;
    }
}

// wave = one (b,p); lanes = 64 output channels; weights [ci][o] -> coalesced. NHWC out. XCD-affine.
__global__ __launch_bounds__(256) void conv1x1_bn_kernel(
    const float* __restrict__ f, const float* __restrict__ wr,
    const float* __restrict__ sb, float* __restrict__ out, int Cin, int hw)
{
    int xcd = blockIdx.x & 7, slot = blockIdx.x >> 3;
    int b = xcd >> 1;
    int g = (xcd & 1) * (hw >> 3) + slot;
    int o = threadIdx.x & 63;
    int p = g * 4 + (threadIdx.x >> 6);
    p = __builtin_amdgcn_readfirstlane(p);
    b = __builtin_amdgcn_readfirstlane(b);
    const float* fb = f + (size_t)b * Cin * hw + p;
    float acc = 0.f;
#pragma unroll 8
    for (int ci = 0; ci < Cin; ++ci) acc = fmaf(fb[(size_t)ci * hw], wr[ci * 64 + o], acc);
    out[((size_t)b * hw + p) * 64 + o] = fmaf(acc, sb[o], sb[64 + o]);
}

// fuse v4: scalar (wave-uniform) weight loads + batched-in-flight global loads.
// phase-1 per-px fp32 conv+BN -> Ot (LDS); phase-2 chunk-major upsample+relu+store.
__global__ __launch_bounds__(256) void fuse_kernel(const float* __restrict__ f0, float* __restrict__ ws)
{
    __shared__ float Ot[64 * 68];    // [px][ch pad 68] 17.4 KB

    int tid = threadIdx.x;
    int blk = blockIdx.x;
    int xcd = blk & 7, slot = blk >> 3;
    int b = xcd >> 1;
    int t = (xcd & 1) * 200 + slot;
    int p0 = t * 64;
    int lane = tid & 63;
    int cb = __builtin_amdgcn_readfirstlane(tid >> 6);   // wave-uniform -> scalar weight addressing
    int p = p0 + lane;
    const float* wr0 = ws + WR0_OFF + cb * 16;
    const float* sb  = ws + SB_OFF;  // bn0

    // phase 1: conv1x1(f0)+bn; f0 loads batched x8, weights via scalar loads
    {
        float acc[16];
#pragma unroll
        for (int i = 0; i < 16; i++) acc[i] = 0.f;

        const float* f0b = f0 + (size_t)b * 64 * HW_ + p;
        for (int ci0 = 0; ci0 < 64; ci0 += 8) {
            float fv[8];
#pragma unroll
            for (int j = 0; j < 8; j++) fv[j] = f0b[(size_t)(ci0 + j) * HW_];
#pragma unroll
            for (int j = 0; j < 8; j++) {
                const float* wrow = wr0 + (ci0 + j) * 64;
#pragma unroll
                for (int i = 0; i < 16; i++) acc[i] = fmaf(fv[j], wrow[i], acc[i]);
            }
        }
        float* orow = Ot + lane * 68 + cb * 16;
#pragma unroll
        for (int i = 0; i < 16; i++) {
            int o = cb * 16 + i;
            orow[i] = fmaf(acc[i], sb[o], sb[64 + o]);
        }
    }
    __syncthreads();

    // phase 2: chunk-major upsample + relu + store; all 12 corner loads hoisted per px
    {
        int chunk = lane & 15, pxo = lane >> 4;
        float* xb = ws + X_OFF + ((size_t)b * HW_ + p0) * 64;
#pragma unroll
        for (int r = 0; r < 4; r++) {
            int gpx = cb * 16 + r * 4 + pxo;
            int gp = p0 + gpx;
            int h = gp / W_, w = gp % W_;

            float fy1 = h * (79.f / 159.f); int i1 = (int)fy1; if (i1 > 78) i1 = 78; float ty1 = fy1 - i1;
            float fx1 = w * (79.f / 159.f); int j1 = (int)fx1; if (j1 > 78) j1 = 78; float tx1 = fx1 - j1;
            const float* y1 = ws + Y1_OFF + ((size_t)b * 6400 + (size_t)(i1 * 80 + j1)) * 64 + chunk * 4;
            float fy2 = h * (39.f / 159.f); int i2 = (int)fy2; if (i2 > 38) i2 = 38; float ty2 = fy2 - i2;
            float fx2 = w * (39.f / 159.f); int j2 = (int)fx2; if (j2 > 38) j2 = 38; float tx2 = fx2 - j2;
            const float* y2 = ws + Y2_OFF + ((size_t)b * 1600 + (size_t)(i2 * 40 + j2)) * 64 + chunk * 4;
            float fy3 = h * (19.f / 159.f); int i3 = (int)fy3; if (i3 > 18) i3 = 18; float ty3 = fy3 - i3;
            float fx3 = w * (19.f / 159.f); int j3 = (int)fx3; if (j3 > 18) j3 = 18; float tx3 = fx3 - j3;
            const float* y3 = ws + Y3_OFF + ((size_t)b * 400 + (size_t)(i3 * 20 + j3)) * 64 + chunk * 4;

            f32x4 A[12];
            A[0]  = *(const f32x4*)(y1);
            A[1]  = *(const f32x4*)(y1 + 64);
            A[2]  = *(const f32x4*)(y1 + 80 * 64);
            A[3]  = *(const f32x4*)(y1 + 81 * 64);
            A[4]  = *(const f32x4*)(y2);
            A[5]  = *(const f32x4*)(y2 + 64);
            A[6]  = *(const f32x4*)(y2 + 40 * 64);
            A[7]  = *(const f32x4*)(y2 + 41 * 64);
            A[8]  = *(const f32x4*)(y3);
            A[9]  = *(const f32x4*)(y3 + 64);
            A[10] = *(const f32x4*)(y3 + 20 * 64);
            A[11] = *(const f32x4*)(y3 + 21 * 64);

            f32x4 v = *(const f32x4*)(Ot + gpx * 68 + chunk * 4);

            float w00, w01, w10, w11;
            w00 = (1.f - ty1) * (1.f - tx1); w01 = (1.f - ty1) * tx1; w10 = ty1 * (1.f - tx1); w11 = ty1 * tx1;
#pragma unroll
            for (int j = 0; j < 4; j++)
                v[j] += A[0][j] * w00 + A[1][j] * w01 + A[2][j] * w10 + A[3][j] * w11;
            w00 = (1.f - ty2) * (1.f - tx2); w01 = (1.f - ty2) * tx2; w10 = ty2 * (1.f - tx2); w11 = ty2 * tx2;
#pragma unroll
            for (int j = 0; j < 4; j++)
                v[j] += A[4][j] * w00 + A[5][j] * w01 + A[6][j] * w10 + A[7][j] * w11;
            w00 = (1.f - ty3) * (1.f - tx3); w01 = (1.f - ty3) * tx3; w10 = ty3 * (1.f - tx3); w11 = ty3 * tx3;
#pragma unroll
            for (int j = 0; j < 4; j++)
                v[j] += A[8][j] * w00 + A[9][j] * w01 + A[10][j] * w10 + A[11][j] * w11;

#pragma unroll
            for (int j = 0; j < 4; j++) v[j] = fmaxf(v[j], 0.f);
            *(f32x4*)(xb + (size_t)gpx * 64 + chunk * 4) = v;
        }
    }
}

// offconv MFMA GEMM: wave-self-contained A slices -> NO in-loop barriers.
// Chunk-major gather, 4 loads in flight per tap, B fragments direct from global.
__global__ __launch_bounds__(256, 3) void offconv_mfma_kernel(const float* __restrict__ off_b, float* __restrict__ ws)
{
    __shared__ __align__(16) unsigned short A_lds[2][64 * 72];   // tap-pair; reused as C float[64][28]

    int tid = threadIdx.x;
    int blk = blockIdx.x;
    int xcd = blk & 7, slot = blk >> 3;
    int b = xcd >> 1;
    int t = (xcd & 1) * 200 + slot;
    int p0 = t * 64;
    int lane = tid & 63, cb = tid >> 6;
    int px = lane;
    int p = p0 + px;
    int h = p / W_, w = p % W_;
    int mrow = lane & 15, quad = lane >> 4;
    int chunk = lane & 15, pxo = lane >> 4;   // gather mapping

    const unsigned short* rwb = (const unsigned short*)(ws + RWB_OFF);
    const float* xb = ws + X_OFF + (size_t)b * HW_ * 64;

    f32x4 acc2[2];
    acc2[0] = (f32x4){0.f, 0.f, 0.f, 0.f};
    acc2[1] = (f32x4){0.f, 0.f, 0.f, 0.f};

    for (int kk = 0; kk < 9; kk += 2) {
#pragma unroll
        for (int u = 0; u < 2; u++) {
            int tap = kk + u;
            if (tap > 8) break;
            int dy = tap / 3 - 1, dx = tap % 3 - 1;
            int delta = dy * W_ + dx;
            int  pss[4];
            bool vlds[4];
#pragma unroll
            for (int r = 0; r < 4; r++) {
                int gpx = cb * 16 + r * 4 + pxo;
                int gp = p0 + gpx;
                int gh = gp / W_, gw = gp % W_;
                int yy = gh + dy, xx = gw + dx;
                vlds[r] = (yy >= 0) && (yy < H_) && (xx >= 0) && (xx < W_);
                int ps = gp + delta;
                pss[r] = min(max(ps, 0), HW_ - 1);
            }
            f32x4 g[4];
#pragma unroll
            for (int r = 0; r < 4; r++)
                g[r] = *(const f32x4*)(xb + (size_t)pss[r] * 64 + chunk * 4);
#pragma unroll
            for (int r = 0; r < 4; r++) {
                int gpx = cb * 16 + r * 4 + pxo;
                unsigned short pk[4];
#pragma unroll
                for (int j = 0; j < 4; j++) pk[j] = vlds[r] ? f2bf(g[r][j]) : (unsigned short)0;
                *(unsigned int*)(A_lds[u] + gpx * 72 + chunk * 4)     = ((unsigned int)pk[1] << 16) | pk[0];
                *(unsigned int*)(A_lds[u] + gpx * 72 + chunk * 4 + 2) = ((unsigned int)pk[3] << 16) | pk[2];
            }
        }

#pragma unroll
        for (int u = 0; u < 2; u++) {
            int tap = kk + u;
            if (tap > 8) break;
            const unsigned short* Ab = A_lds[u] + (cb * 16 + mrow) * 72;
#pragma unroll
            for (int ks = 0; ks < 2; ks++) {
                bf16x8 af = *(const bf16x8*)(Ab + ks * 32 + quad * 8);
#pragma unroll
                for (int nt = 0; nt < 2; nt++) {
                    bf16x8 bf_ = *(const bf16x8*)(rwb + tap * 2048 + (nt * 16 + mrow) * 64 + ks * 32 + quad * 8);
                    acc2[nt] = __builtin_amdgcn_mfma_f32_16x16x32_bf16(af, bf_, acc2[nt], 0, 0, 0);
                }
            }
        }
    }

    __syncthreads();   // all waves done with A_lds (C overlay next)
    float* Cl = (float*)A_lds;  // [64 px][28]
#pragma unroll
    for (int nt = 0; nt < 2; nt++) {
        int o = nt * 16 + mrow;
        if (o < 27) {
            int pr = cb * 16 + quad * 4;
#pragma unroll
            for (int r = 0; r < 4; r++) Cl[(pr + r) * 28 + o] = acc2[nt][r];
        }
    }
    __syncthreads();

    for (int k = cb; k < 9; k += 4) {
        float ady = Cl[px * 28 + 2 * k]     + off_b[2 * k];
        float adx = Cl[px * 28 + 2 * k + 1] + off_b[2 * k + 1];
        float am  = Cl[px * 28 + 18 + k]    + off_b[18 + k];
        float sy = (float)(h + k / 3 - 1) + ady;
        float sx = (float)(w + k % 3 - 1) + adx;
        float mk = 1.f / (1.f + __expf(-am));
        float* om = ws + OM_OFF + ((size_t)b * HW_ + p) * 27 + 3 * k;
        om[0] = sy; om[1] = sx; om[2] = mk;
    }
}

// dcn MFMA GEMM: wave-self-contained A slices -> NO in-loop barriers.
// Chunk-major gather, 16 loads in flight per tap, OMs in LDS, inline (idx,wv).
__global__ __launch_bounds__(256, 3) void dcn_mfma_kernel(const float* __restrict__ ws, float* __restrict__ out)
{
    __shared__ __align__(16) unsigned short A_lds[2][64 * 72];  // tap-pair; reused as C float[64][65]
    __shared__ float OMs[64 * 27];

    int tid = threadIdx.x;
    int blk = blockIdx.x;
    int xcd = blk & 7, slot = blk >> 3;
    int b = xcd >> 1;
    int t = (xcd & 1) * 200 + slot;
    int p0 = t * 64;
    int lane = tid & 63, cb = tid >> 6;
    int mrow = lane & 15, quad = lane >> 4;
    int chunk = lane & 15, pxo = lane >> 4;   // gather mapping

    const float* xb  = ws + X_OFF + (size_t)b * HW_ * 64;
    const unsigned short* wtb = (const unsigned short*)(ws + WTB_OFF);
    const float* sb  = ws + SB_OFF + 4 * 128;  // final bn

    // stage om for this block's 64 px
    {
        const float* omg = ws + OM_OFF + ((size_t)b * HW_ + p0) * 27;
        for (int i = tid; i < 64 * 27; i += 256) OMs[i] = omg[i];
    }
    __syncthreads();   // OMs visible to all waves

    f32x4 acc[4];
#pragma unroll
    for (int nt = 0; nt < 4; nt++) acc[nt] = (f32x4){0.f, 0.f, 0.f, 0.f};

    for (int kk = 0; kk < 9; kk += 2) {
#pragma unroll
        for (int u = 0; u < 2; u++) {
            int k = kk + u;
            if (k > 8) break;
            int   idxs[4][4];
            float wvs[4][4];
#pragma unroll
            for (int r = 0; r < 4; r++) {
                int gpx = cb * 16 + r * 4 + pxo;
                float sy = OMs[gpx * 27 + 3 * k];
                float sx = OMs[gpx * 27 + 3 * k + 1];
                float mk = OMs[gpx * 27 + 3 * k + 2];
                float y0f = floorf(sy), x0f = floorf(sx);
                int y0 = (int)y0f, x0 = (int)x0f;
                float ty = sy - y0f, tx = sx - x0f;
#pragma unroll
                for (int cr = 0; cr < 4; cr++) {
                    int dy = cr >> 1, dx = cr & 1;
                    int yy = y0 + dy, xx = x0 + dx;
                    float wy = dy ? ty : 1.f - ty;
                    float wx = dx ? tx : 1.f - tx;
                    bool vld = (yy >= 0) && (yy < H_) && (xx >= 0) && (xx < W_);
                    int yc = min(max(yy, 0), H_ - 1);
                    int xc = min(max(xx, 0), W_ - 1);
                    idxs[r][cr] = yc * W_ + xc;
                    wvs[r][cr]  = vld ? wy * wx * mk : 0.f;
                }
            }
            f32x4 g[4][4];
#pragma unroll
            for (int r = 0; r < 4; r++)
#pragma unroll
                for (int cr = 0; cr < 4; cr++)
                    g[r][cr] = *(const f32x4*)(xb + (size_t)idxs[r][cr] * 64 + chunk * 4);
#pragma unroll
            for (int r = 0; r < 4; r++) {
                int gpx = cb * 16 + r * 4 + pxo;
                f32x4 v = (f32x4){0.f, 0.f, 0.f, 0.f};
#pragma unroll
                for (int cr = 0; cr < 4; cr++) {
                    float wv = wvs[r][cr];
#pragma unroll
                    for (int j = 0; j < 4; j++) v[j] = fmaf(g[r][cr][j], wv, v[j]);
                }
                unsigned short pk[4];
#pragma unroll
                for (int j = 0; j < 4; j++) pk[j] = f2bf(v[j]);
                *(unsigned int*)(A_lds[u] + gpx * 72 + chunk * 4)     = ((unsigned int)pk[1] << 16) | pk[0];
                *(unsigned int*)(A_lds[u] + gpx * 72 + chunk * 4 + 2) = ((unsigned int)pk[3] << 16) | pk[2];
            }
        }

#pragma unroll
        for (int u = 0; u < 2; u++) {
            int k = kk + u;
            if (k > 8) break;
            const unsigned short* Ab = A_lds[u] + (cb * 16 + mrow) * 72;
#pragma unroll
            for (int ks = 0; ks < 2; ks++) {
                bf16x8 af = *(const bf16x8*)(Ab + ks * 32 + quad * 8);
#pragma unroll
                for (int nt = 0; nt < 4; nt++) {
                    bf16x8 bf_ = *(const bf16x8*)(wtb + k * 4608 + (nt * 16 + mrow) * 72 + ks * 32 + quad * 8);
                    acc[nt] = __builtin_amdgcn_mfma_f32_16x16x32_bf16(af, bf_, acc[nt], 0, 0, 0);
                }
            }
        }
    }

    // epilogue: C frag -> LDS [o][px pad65] -> NCHW store
    __syncthreads();   // all waves done with A_lds (C overlay next)
    float* C_lds = (float*)A_lds;
#pragma unroll
    for (int nt = 0; nt < 4; nt++) {
        int o = nt * 16 + mrow;
        int pxb = cb * 16 + quad * 4;
#pragma unroll
        for (int r = 0; r < 4; r++) C_lds[o * 65 + pxb + r] = acc[nt][r];
    }
    __syncthreads();
#pragma unroll
    for (int i = 0; i < 16; i++) {
        int o = cb * 16 + i;
        float v = C_lds[o * 65 + lane];
        v = fmaf(v, sb[o], sb[64 + o]);
        out[((size_t)b * 64 + o) * HW_ + p0 + lane] = fmaxf(v, 0.f);
    }
}

extern "C" void kernel_launch(void* const* d_in, const int* in_sizes, int n_in,
                              void* d_out, int out_size, void* d_ws, size_t ws_size,
                              hipStream_t stream)
{
    const float* f0 = (const float*)d_in[0];
    const float* f1 = (const float*)d_in[1];
    const float* f2 = (const float*)d_in[2];
    const float* f3 = (const float*)d_in[3];
    const float* w0 = (const float*)d_in[4];
    const float* g0 = (const float*)d_in[5];
    const float* b0 = (const float*)d_in[6];
    const float* m0 = (const float*)d_in[7];
    const float* v0 = (const float*)d_in[8];
    const float* w1 = (const float*)d_in[9];
    const float* g1 = (const float*)d_in[10];
    const float* b1 = (const float*)d_in[11];
    const float* m1 = (const float*)d_in[12];
    const float* v1 = (const float*)d_in[13];
    const float* w2 = (const float*)d_in[14];
    const float* g2 = (const float*)d_in[15];
    const float* b2 = (const float*)d_in[16];
    const float* m2 = (const float*)d_in[17];
    const float* v2 = (const float*)d_in[18];
    const float* w3 = (const float*)d_in[19];
    const float* g3 = (const float*)d_in[20];
    const float* b3 = (const float*)d_in[21];
    const float* m3 = (const float*)d_in[22];
    const float* v3 = (const float*)d_in[23];
    const float* off_w = (const float*)d_in[24];
    const float* off_b = (const float*)d_in[25];
    const float* dcn_w = (const float*)d_in[26];
    const float* gf = (const float*)d_in[27];
    const float* bf = (const float*)d_in[28];
    const float* mf = (const float*)d_in[29];
    const float* vf = (const float*)d_in[30];

    float* ws  = (float*)d_ws;
    float* out = (float*)d_out;

    prep_kernel<<<dim3(476), dim3(256), 0, stream>>>(
        g0, b0, m0, v0, g1, b1, m1, v1, g2, b2, m2, v2, g3, b3, m3, v3,
        gf, bf, mf, vf, w0, w1, w2, w3, dcn_w, off_w, ws);

    conv1x1_bn_kernel<<<dim3(6400), dim3(256), 0, stream>>>(f1, ws + WR1_OFF, ws + SB_OFF + 128, ws + Y1_OFF, 128, 6400);
    conv1x1_bn_kernel<<<dim3(1600), dim3(256), 0, stream>>>(f2, ws + WR2_OFF, ws + SB_OFF + 256, ws + Y2_OFF, 256, 1600);
    conv1x1_bn_kernel<<<dim3(400),  dim3(256), 0, stream>>>(f3, ws + WR3_OFF, ws + SB_OFF + 384, ws + Y3_OFF, 512, 400);

    fuse_kernel<<<dim3(1600), dim3(256), 0, stream>>>(f0, ws);

    offconv_mfma_kernel<<<dim3(1600), dim3(256), 0, stream>>>(off_b, ws);

    dcn_mfma_kernel<<<dim3(1600), dim3(256), 0, stream>>>(ws, out);
}